// Round 1
// baseline (3922.987 us; speedup 1.0000x reference)
//
#include <hip/hip_runtime.h>
#include <hip/hip_bf16.h>
#include <cstddef>

// ---------------------------------------------------------------------------
// TriangularSelfAttentionBlock: f32 baseline (correctness-first)
// L=512, SEQ_D=1024, PAIR_D=128, H=32, HW=32, INNER=64
// ---------------------------------------------------------------------------

#define L 512
#define SEQ_D 1024
#define PAIR_D 128
#define NH 32
#define HW 32

__device__ inline float wred_sum(float v) {
#pragma unroll
  for (int off = 32; off; off >>= 1) v += __shfl_xor(v, off, 64);
  return v;
}
__device__ inline float wred_max(float v) {
#pragma unroll
  for (int off = 32; off; off >>= 1) v = fmaxf(v, __shfl_xor(v, off, 64));
  return v;
}
__device__ inline void f4a(const float4 v, float* f) {
  f[0] = v.x; f[1] = v.y; f[2] = v.z; f[3] = v.w;
}

// ---------------- LayerNorm over 1024-dim rows -----------------------------
__global__ __launch_bounds__(256) void ln1024_kernel(
    const float* __restrict__ in, const float* __restrict__ g,
    const float* __restrict__ b, float* __restrict__ out) {
  const int row = blockIdx.x;
  const int tid = threadIdx.x;
  float4 v = ((const float4*)(in + (size_t)row * SEQ_D))[tid];
  float s = v.x + v.y + v.z + v.w;
  float s2 = v.x * v.x + v.y * v.y + v.z * v.z + v.w * v.w;
  __shared__ float red[8];
  const int lane = tid & 63, wid = tid >> 6;
  s = wred_sum(s);
  s2 = wred_sum(s2);
  if (lane == 0) { red[wid] = s; red[4 + wid] = s2; }
  __syncthreads();
  s = red[0] + red[1] + red[2] + red[3];
  s2 = red[4] + red[5] + red[6] + red[7];
  const float mean = s * (1.0f / SEQ_D);
  const float var = s2 * (1.0f / SEQ_D) - mean * mean;
  const float rstd = rsqrtf(var + 1e-5f);
  float4 gv = ((const float4*)g)[tid];
  float4 bv = ((const float4*)b)[tid];
  float4 o;
  o.x = (v.x - mean) * rstd * gv.x + bv.x;
  o.y = (v.y - mean) * rstd * gv.y + bv.y;
  o.z = (v.z - mean) * rstd * gv.z + bv.z;
  o.w = (v.w - mean) * rstd * gv.w + bv.w;
  ((float4*)(out + (size_t)row * SEQ_D))[tid] = o;
}

// ---------------- Generic GEMM: C[M][N] = A[M][K] @ B[N][K]^T --------------
// 64x64 tile, BK=16, 256 threads, 4x4 microtile, transposed LDS (float4 reads)
template <bool BIAS, bool RELU, bool RES>
__global__ __launch_bounds__(256) void gemm_nt_kernel(
    const float* __restrict__ A, const float* __restrict__ B,
    const float* __restrict__ bias, const float* __restrict__ res,
    float* __restrict__ C, int M, int N, int K) {
  __shared__ float At[16][68];
  __shared__ float Bt[16][68];
  const int tid = threadIdx.x;
  const int ty = tid >> 4, tx = tid & 15;
  const int bm = blockIdx.y * 64, bn = blockIdx.x * 64;
  const int lr = tid >> 2, lc = (tid & 3) << 2;
  const float* Ap = A + (size_t)(bm + lr) * K + lc;
  const float* Bp = B + (size_t)(bn + lr) * K + lc;
  float acc[4][4] = {};
  for (int k0 = 0; k0 < K; k0 += 16) {
    float4 av = *(const float4*)(Ap + k0);
    float4 bv = *(const float4*)(Bp + k0);
    At[lc + 0][lr] = av.x; At[lc + 1][lr] = av.y;
    At[lc + 2][lr] = av.z; At[lc + 3][lr] = av.w;
    Bt[lc + 0][lr] = bv.x; Bt[lc + 1][lr] = bv.y;
    Bt[lc + 2][lr] = bv.z; Bt[lc + 3][lr] = bv.w;
    __syncthreads();
#pragma unroll
    for (int kk = 0; kk < 16; ++kk) {
      float a[4], bb[4];
      f4a(*(const float4*)&At[kk][ty << 2], a);
      f4a(*(const float4*)&Bt[kk][tx << 2], bb);
#pragma unroll
      for (int i = 0; i < 4; ++i)
#pragma unroll
        for (int j = 0; j < 4; ++j) acc[i][j] += a[i] * bb[j];
    }
    __syncthreads();
  }
#pragma unroll
  for (int i = 0; i < 4; ++i) {
    const int row = bm + (ty << 2) + i;
#pragma unroll
    for (int j = 0; j < 4; ++j) {
      const int col = bn + (tx << 2) + j;
      float v = acc[i][j];
      if (BIAS) v += bias[col];
      if (RELU) v = fmaxf(v, 0.0f);
      if (RES) v += res[(size_t)row * N + col];
      C[(size_t)row * N + col] = v;
    }
  }
}

// ---------------- PairToSequence: biasT[h][i][j] = LN(pair[i,j]) . W[h] ----
__global__ __launch_bounds__(256) void p2s_bias_kernel(
    const float* __restrict__ pair, const float* __restrict__ g,
    const float* __restrict__ b, const float* __restrict__ W,
    float* __restrict__ biasT) {
  __shared__ float xt[64][130];
  __shared__ float Ws[32][128];
  const int tid = threadIdx.x;
  const int lane = tid & 63, wid = tid >> 6;
  const int r0 = blockIdx.x * 64;  // flat (i,j) row base; i constant per block
  {
    const float4* W4 = (const float4*)W;
    float4* Ws4 = (float4*)&Ws[0][0];
#pragma unroll
    for (int u = 0; u < 4; ++u) Ws4[tid + u * 256] = W4[tid + u * 256];
  }
  const float g0 = g[lane], g1 = g[lane + 64];
  const float b0 = b[lane], b1 = b[lane + 64];
  for (int q = 0; q < 16; ++q) {
    const int r = wid * 16 + q;
    const float* xr = pair + (size_t)(r0 + r) * PAIR_D;
    const float x0 = xr[lane], x1 = xr[lane + 64];
    const float s = wred_sum(x0 + x1);
    const float s2 = wred_sum(x0 * x0 + x1 * x1);
    const float mean = s * (1.0f / PAIR_D);
    const float var = s2 * (1.0f / PAIR_D) - mean * mean;
    const float rstd = rsqrtf(var + 1e-5f);
    xt[r][lane] = (x0 - mean) * rstd * g0 + b0;
    xt[r][lane + 64] = (x1 - mean) * rstd * g1 + b1;
  }
  __syncthreads();
  const int rl = tid & 63, h0 = (tid >> 6) << 3;
  float acc[8] = {};
  for (int c = 0; c < 128; c += 4) {
    float xa[4];
#pragma unroll
    for (int u = 0; u < 4; ++u) xa[u] = xt[rl][c + u];
#pragma unroll
    for (int j = 0; j < 8; ++j) {
      float w[4];
      f4a(*(const float4*)&Ws[h0 + j][c], w);
      acc[j] += xa[0] * w[0] + xa[1] * w[1] + xa[2] * w[2] + xa[3] * w[3];
    }
  }
  const int i_idx = r0 >> 9, j0 = r0 & 511;
#pragma unroll
  for (int j = 0; j < 8; ++j)
    biasT[(size_t)(h0 + j) * (L * L) + (size_t)i_idx * L + (j0 + rl)] = acc[j];
}

// ---------------- scores: S[h][q][k] = scale*Q.K + biasT -------------------
__global__ __launch_bounds__(256) void scores_kernel(
    const float* __restrict__ t, const float* __restrict__ biasT,
    float* __restrict__ S) {
  const int h = blockIdx.z, q0 = blockIdx.y * 64, k0 = blockIdx.x * 64;
  __shared__ float Qs[64][33];
  __shared__ float Ks[64][33];
  const int tid = threadIdx.x;
#pragma unroll
  for (int u = 0; u < 2; ++u) {
    const int f4 = tid + u * 256;
    const int r = f4 >> 3, c4 = (f4 & 7) << 2;
    float4 qv = *(const float4*)(t + (size_t)(q0 + r) * 3072 + h * 96 + c4);
    Qs[r][c4 + 0] = qv.x; Qs[r][c4 + 1] = qv.y;
    Qs[r][c4 + 2] = qv.z; Qs[r][c4 + 3] = qv.w;
    float4 kv = *(const float4*)(t + (size_t)(k0 + r) * 3072 + h * 96 + 32 + c4);
    Ks[r][c4 + 0] = kv.x; Ks[r][c4 + 1] = kv.y;
    Ks[r][c4 + 2] = kv.z; Ks[r][c4 + 3] = kv.w;
  }
  __syncthreads();
  const int ty = tid >> 4, tx = tid & 15;
  float acc[4][4] = {};
  for (int c = 0; c < 32; ++c) {
    float a[4], bb[4];
#pragma unroll
    for (int i = 0; i < 4; ++i) a[i] = Qs[(ty << 2) + i][c];
#pragma unroll
    for (int j = 0; j < 4; ++j) bb[j] = Ks[tx + (j << 4)][c];
#pragma unroll
    for (int i = 0; i < 4; ++i)
#pragma unroll
      for (int j = 0; j < 4; ++j) acc[i][j] += a[i] * bb[j];
  }
  const float scale = 0.17677669529663689f;  // 32^-0.5
#pragma unroll
  for (int i = 0; i < 4; ++i) {
    const int q = q0 + (ty << 2) + i;
#pragma unroll
    for (int j = 0; j < 4; ++j) {
      const int k = k0 + tx + (j << 4);
      const size_t idx = ((size_t)h * L + q) * L + k;
      S[idx] = acc[i][j] * scale + biasT[idx];
    }
  }
}

// ---------------- softmax over last dim (512) ------------------------------
__global__ __launch_bounds__(256) void softmax_kernel(float* __restrict__ S) {
  float* x = S + (size_t)blockIdx.x * L;
  const int tid = threadIdx.x;
  float2 v = ((float2*)x)[tid];
  __shared__ float red[4];
  const int lane = tid & 63, wid = tid >> 6;
  float m = wred_max(fmaxf(v.x, v.y));
  if (lane == 0) red[wid] = m;
  __syncthreads();
  m = fmaxf(fmaxf(red[0], red[1]), fmaxf(red[2], red[3]));
  const float e0 = __expf(v.x - m), e1 = __expf(v.y - m);
  float s = wred_sum(e0 + e1);
  __syncthreads();
  if (lane == 0) red[wid] = s;
  __syncthreads();
  s = red[0] + red[1] + red[2] + red[3];
  const float inv = 1.0f / s;
  ((float2*)x)[tid] = make_float2(e0 * inv, e1 * inv);
}

// ---------------- PV: o[q][h*32+c] = sum_k S[h][q][k] * V[k][c] ------------
__global__ __launch_bounds__(256) void pv_kernel(
    const float* __restrict__ S, const float* __restrict__ t,
    float* __restrict__ o) {
  const int h = blockIdx.x, q0 = blockIdx.y * 64;
  __shared__ float Ss[64][68];
  __shared__ float Vs[64][33];
  const int tid = threadIdx.x;
  const int c = tid & 31, ty = tid >> 5;  // ty 0..7
  float acc[8] = {};
  for (int kt = 0; kt < L; kt += 64) {
#pragma unroll
    for (int u = 0; u < 4; ++u) {
      const int f4 = tid + u * 256;
      const int r = f4 >> 4, c4 = (f4 & 15) << 2;
      float4 sv = *(const float4*)(S + ((size_t)h * L + q0 + r) * L + kt + c4);
      Ss[r][c4 + 0] = sv.x; Ss[r][c4 + 1] = sv.y;
      Ss[r][c4 + 2] = sv.z; Ss[r][c4 + 3] = sv.w;
    }
#pragma unroll
    for (int u = 0; u < 2; ++u) {
      const int f4 = tid + u * 256;
      const int r = f4 >> 3, c4 = (f4 & 7) << 2;
      float4 vv = *(const float4*)(t + (size_t)(kt + r) * 3072 + h * 96 + 64 + c4);
      Vs[r][c4 + 0] = vv.x; Vs[r][c4 + 1] = vv.y;
      Vs[r][c4 + 2] = vv.z; Vs[r][c4 + 3] = vv.w;
    }
    __syncthreads();
    for (int kk = 0; kk < 64; kk += 4) {
      float vv[4];
#pragma unroll
      for (int u = 0; u < 4; ++u) vv[u] = Vs[kk + u][c];
#pragma unroll
      for (int i = 0; i < 8; ++i) {
        float s4[4];
        f4a(*(const float4*)&Ss[ty * 8 + i][kk], s4);
        acc[i] += s4[0] * vv[0] + s4[1] * vv[1] + s4[2] * vv[2] + s4[3] * vv[3];
      }
    }
    __syncthreads();
  }
#pragma unroll
  for (int i = 0; i < 8; ++i) {
    const int q = q0 + ty * 8 + i;
    o[(size_t)q * SEQ_D + h * HW + c] = acc[i];
  }
}

// ---------------- gate: o *= sigmoid(g) ------------------------------------
__global__ __launch_bounds__(256) void gate_kernel(float* __restrict__ o,
                                                   const float* __restrict__ g) {
  const int i = blockIdx.x * 256 + threadIdx.x;
  float4 ov = ((float4*)o)[i];
  float4 gv = ((const float4*)g)[i];
  ov.x *= 1.0f / (1.0f + __expf(-gv.x));
  ov.y *= 1.0f / (1.0f + __expf(-gv.y));
  ov.z *= 1.0f / (1.0f + __expf(-gv.z));
  ov.w *= 1.0f / (1.0f + __expf(-gv.w));
  ((float4*)o)[i] = ov;
}

// ---------------- SequenceToPair: p = pairwise + X @ Wspo^T + bspo ---------
// X[r][c<64] = qh[j][c]*kh[i][c] ; X[r][c>=64] = qh[j][c-64]-kh[i][c-64]
__global__ __launch_bounds__(256) void pair1_kernel(
    const float* __restrict__ sp, const float* __restrict__ Wspo,
    const float* __restrict__ bspo, const float* __restrict__ pairwise,
    float* __restrict__ pout) {
  __shared__ float xs[64][129];
  __shared__ float Ws[128][34];
  __shared__ float khs[64];
  const int tid = threadIdx.x;
  const int r0 = blockIdx.x * 64;
  const int i_idx = r0 >> 9, j0 = r0 & 511;
  if (tid < 64) khs[tid] = sp[(size_t)i_idx * 128 + 64 + tid];
  __syncthreads();
  for (int idx = tid; idx < 64 * 128; idx += 256) {
    const int r = idx >> 7, cc = idx & 127;
    const float q_ = sp[(size_t)(j0 + r) * 128 + (cc & 63)];
    const float k_ = khs[cc & 63];
    xs[r][cc] = (cc < 64) ? q_ * k_ : q_ - k_;
  }
  const int ty = tid >> 4, tx = tid & 15;
  float acc[4][8] = {};
  for (int cs = 0; cs < 128; cs += 32) {
    __syncthreads();
#pragma unroll
    for (int u = 0; u < 4; ++u) {
      const int f4 = tid + u * 256;
      const int n = f4 >> 3, c4 = (f4 & 7) << 2;
      float4 wv = *(const float4*)(Wspo + (size_t)n * 128 + cs + c4);
      Ws[n][c4 + 0] = wv.x; Ws[n][c4 + 1] = wv.y;
      Ws[n][c4 + 2] = wv.z; Ws[n][c4 + 3] = wv.w;
    }
    __syncthreads();
    for (int ci = 0; ci < 32; ++ci) {
      float xa[4];
#pragma unroll
      for (int ir = 0; ir < 4; ++ir) xa[ir] = xs[ty + (ir << 4)][cs + ci];
#pragma unroll
      for (int jm = 0; jm < 8; ++jm) {
        const float w = Ws[tx + (jm << 4)][ci];
#pragma unroll
        for (int ir = 0; ir < 4; ++ir) acc[ir][jm] += xa[ir] * w;
      }
    }
  }
#pragma unroll
  for (int ir = 0; ir < 4; ++ir) {
    const size_t rowg = (size_t)(r0 + ty + (ir << 4));
#pragma unroll
    for (int jm = 0; jm < 8; ++jm) {
      const int m = tx + (jm << 4);
      pout[rowg * 128 + m] = acc[ir][jm] + bspo[m] + pairwise[rowg * 128 + m];
    }
  }
}

// ---------------- pair MLP (fused, in-place on p) --------------------------
// p = p + relu(LN(p) @ Wp1^T + bp1) @ Wp2^T + bp2
__global__ __launch_bounds__(256) void pair2_kernel(
    float* __restrict__ p, const float* __restrict__ lng,
    const float* __restrict__ lnb, const float* __restrict__ Wp1,
    const float* __restrict__ bp1, const float* __restrict__ Wp2,
    const float* __restrict__ bp2) {
  __shared__ float ps[32][132];
  __shared__ float pn[32][132];
  __shared__ float Hc[32][132];
  __shared__ float Wst[128][36];
  const int tid = threadIdx.x;
  const size_t r0 = (size_t)blockIdx.x * 32;
  {
    const float4* src = (const float4*)(p + r0 * 128);
#pragma unroll
    for (int u = 0; u < 4; ++u) {
      const int f4 = tid + u * 256;
      const int r = f4 >> 5, c4 = (f4 & 31) << 2;
      *(float4*)&ps[r][c4] = src[f4];
    }
  }
  __syncthreads();
  {
    const int lane = tid & 63, wid = tid >> 6;
    const float gg0 = lng[lane], gg1 = lng[lane + 64];
    const float bb0 = lnb[lane], bb1 = lnb[lane + 64];
    for (int q = 0; q < 8; ++q) {
      const int r = wid * 8 + q;
      const float x0 = ps[r][lane], x1 = ps[r][lane + 64];
      const float s = wred_sum(x0 + x1);
      const float s2 = wred_sum(x0 * x0 + x1 * x1);
      const float mean = s * (1.0f / 128.0f);
      const float var = s2 * (1.0f / 128.0f) - mean * mean;
      const float rstd = rsqrtf(var + 1e-5f);
      pn[r][lane] = (x0 - mean) * rstd * gg0 + bb0;
      pn[r][lane + 64] = (x1 - mean) * rstd * gg1 + bb1;
    }
  }
  __syncthreads();
  const int ty = tid >> 4, tx = tid & 15;
  float out_acc[2][8] = {};
  for (int nc = 0; nc < 4; ++nc) {
    float hacc[2][8] = {};
    for (int cs = 0; cs < 4; ++cs) {
      __syncthreads();
#pragma unroll
      for (int u = 0; u < 4; ++u) {
        const int f4 = tid + u * 256;
        const int n = f4 >> 3, c4 = (f4 & 7) << 2;
        *(float4*)&Wst[n][c4] =
            *(const float4*)(Wp1 + (size_t)(nc * 128 + n) * 128 + cs * 32 + c4);
      }
      __syncthreads();
      for (int c4 = 0; c4 < 32; c4 += 4) {
        float a0[4], a1[4];
        f4a(*(const float4*)&pn[ty][cs * 32 + c4], a0);
        f4a(*(const float4*)&pn[ty + 16][cs * 32 + c4], a1);
#pragma unroll
        for (int j = 0; j < 8; ++j) {
          float w[4];
          f4a(*(const float4*)&Wst[tx + (j << 4)][c4], w);
          hacc[0][j] += a0[0] * w[0] + a0[1] * w[1] + a0[2] * w[2] + a0[3] * w[3];
          hacc[1][j] += a1[0] * w[0] + a1[1] * w[1] + a1[2] * w[2] + a1[3] * w[3];
        }
      }
    }
    __syncthreads();
#pragma unroll
    for (int i = 0; i < 2; ++i)
#pragma unroll
      for (int j = 0; j < 8; ++j) {
        const int n = tx + (j << 4);
        Hc[ty + (i << 4)][n] = fmaxf(hacc[i][j] + bp1[nc * 128 + n], 0.0f);
      }
    __syncthreads();
    for (int ns = 0; ns < 4; ++ns) {
      __syncthreads();
#pragma unroll
      for (int u = 0; u < 4; ++u) {
        const int f4 = tid + u * 256;
        const int m = f4 >> 3, c4 = (f4 & 7) << 2;
        *(float4*)&Wst[m][c4] =
            *(const float4*)(Wp2 + (size_t)m * 512 + nc * 128 + ns * 32 + c4);
      }
      __syncthreads();
      for (int n4 = 0; n4 < 32; n4 += 4) {
        float h0[4], h1[4];
        f4a(*(const float4*)&Hc[ty][ns * 32 + n4], h0);
        f4a(*(const float4*)&Hc[ty + 16][ns * 32 + n4], h1);
#pragma unroll
        for (int j = 0; j < 8; ++j) {
          float w[4];
          f4a(*(const float4*)&Wst[tx + (j << 4)][n4], w);
          out_acc[0][j] += h0[0] * w[0] + h0[1] * w[1] + h0[2] * w[2] + h0[3] * w[3];
          out_acc[1][j] += h1[0] * w[0] + h1[1] * w[1] + h1[2] * w[2] + h1[3] * w[3];
        }
      }
    }
  }
  __syncthreads();
#pragma unroll
  for (int i = 0; i < 2; ++i) {
    const int r = ty + (i << 4);
#pragma unroll
    for (int j = 0; j < 8; ++j) {
      const int m = tx + (j << 4);
      p[(r0 + r) * 128 + m] = ps[r][m] + out_acc[i][j] + bp2[m];
    }
  }
}

// ---------------------------------------------------------------------------
extern "C" void kernel_launch(void* const* d_in, const int* in_sizes, int n_in,
                              void* d_out, int out_size, void* d_ws,
                              size_t ws_size, hipStream_t stream) {
  (void)in_sizes; (void)n_in; (void)out_size; (void)ws_size;
  const float* seq      = (const float*)d_in[0];
  const float* pair     = (const float*)d_in[1];
  const float* ln_p2s_g = (const float*)d_in[2];
  const float* ln_p2s_b = (const float*)d_in[3];
  const float* W_p2s    = (const float*)d_in[4];
  const float* ln1_g    = (const float*)d_in[5];
  const float* ln1_b    = (const float*)d_in[6];
  const float* Wqkv     = (const float*)d_in[7];
  const float* Wo       = (const float*)d_in[8];
  const float* bo       = (const float*)d_in[9];
  const float* Wg       = (const float*)d_in[10];
  const float* bg       = (const float*)d_in[11];
  const float* ln_s_g   = (const float*)d_in[12];
  const float* ln_s_b   = (const float*)d_in[13];
  const float* Wm1      = (const float*)d_in[14];
  const float* bm1      = (const float*)d_in[15];
  const float* Wm2      = (const float*)d_in[16];
  const float* bm2      = (const float*)d_in[17];
  const float* ln_sp_g  = (const float*)d_in[18];
  const float* ln_sp_b  = (const float*)d_in[19];
  const float* Wsp      = (const float*)d_in[20];
  const float* bsp      = (const float*)d_in[21];
  const float* Wspo     = (const float*)d_in[22];
  const float* bspo     = (const float*)d_in[23];
  const float* ln_mp_g  = (const float*)d_in[24];
  const float* ln_mp_b  = (const float*)d_in[25];
  const float* Wp1      = (const float*)d_in[26];
  const float* bp1      = (const float*)d_in[27];
  const float* Wp2      = (const float*)d_in[28];
  const float* bp2      = (const float*)d_in[29];
  // d_in[30] = mask (all-true in this problem) -> masking is a no-op

  float* out_s = (float*)d_out;            // 512*1024
  float* out_p = out_s + 512 * 1024;       // 512*512*128

  float* ws  = (float*)d_ws;
  float* y   = ws;                  // 524288
  float* t   = y + 524288;          // 1572864 (qkv)
  float* g   = t + 1572864;         // 524288 (gate logits)
  float* o   = g + 524288;          // 524288 (attn out)
  float* s1  = o + 524288;          // 524288
  float* h1  = s1 + 524288;         // 2097152 (mlp hidden)
  float* spb = h1 + 2097152;        // 65536 (qh|kh)

  // scratch inside d_out's p-section (written only at the very end):
  float* biasT = out_p;             // 32*512*512
  float* S     = out_p + 8388608;   // 32*512*512

  // 1. y = LN(seq)
  ln1024_kernel<<<512, 256, 0, stream>>>(seq, ln1_g, ln1_b, y);
  // 2. qkv = y @ Wqkv^T
  gemm_nt_kernel<false, false, false><<<dim3(48, 8), 256, 0, stream>>>(
      y, Wqkv, nullptr, nullptr, t, 512, 3072, 1024);
  // 3. gate logits = y @ Wg^T + bg
  gemm_nt_kernel<true, false, false><<<dim3(16, 8), 256, 0, stream>>>(
      y, Wg, bg, nullptr, g, 512, 1024, 1024);
  // 4. pairwise bias (PairToSequence)
  p2s_bias_kernel<<<4096, 256, 0, stream>>>(pair, ln_p2s_g, ln_p2s_b, W_p2s, biasT);
  // 5. scores = scale*QK^T + bias
  scores_kernel<<<dim3(8, 8, 32), 256, 0, stream>>>(t, biasT, S);
  // 6. softmax
  softmax_kernel<<<16384, 256, 0, stream>>>(S);
  // 7. o = A @ V
  pv_kernel<<<dim3(32, 8), 256, 0, stream>>>(S, t, o);
  // 8. o *= sigmoid(g)
  gate_kernel<<<512, 256, 0, stream>>>(o, g);
  // 9. s1 = seq + o @ Wo^T + bo
  gemm_nt_kernel<true, false, true><<<dim3(16, 8), 256, 0, stream>>>(
      o, Wo, bo, seq, s1, 512, 1024, 1024);
  // 10. y = LN(s1)
  ln1024_kernel<<<512, 256, 0, stream>>>(s1, ln_s_g, ln_s_b, y);
  // 11. h1 = relu(y @ Wm1^T + bm1)
  gemm_nt_kernel<true, true, false><<<dim3(64, 8), 256, 0, stream>>>(
      y, Wm1, bm1, nullptr, h1, 512, 4096, 1024);
  // 12. s2 = s1 + h1 @ Wm2^T + bm2  -> d_out (sequence output)
  gemm_nt_kernel<true, false, true><<<dim3(16, 8), 256, 0, stream>>>(
      h1, Wm2, bm2, s1, out_s, 512, 1024, 4096);
  // 13. y = LN(s2)
  ln1024_kernel<<<512, 256, 0, stream>>>(out_s, ln_sp_g, ln_sp_b, y);
  // 14. sp = y @ Wsp^T + bsp
  gemm_nt_kernel<true, false, false><<<dim3(2, 8), 256, 0, stream>>>(
      y, Wsp, bsp, nullptr, spb, 512, 128, 1024);
  // 15. p = pairwise + X @ Wspo^T + bspo   (overwrites biasT/S scratch)
  pair1_kernel<<<4096, 256, 0, stream>>>(spb, Wspo, bspo, pair, out_p);
  // 16. p += relu(LN(p) @ Wp1^T + bp1) @ Wp2^T + bp2  (in-place)
  pair2_kernel<<<8192, 256, 0, stream>>>(out_p, ln_mp_g, ln_mp_b, Wp1, bp1, Wp2, bp2);
}

// Round 2
// 1074.477 us; speedup vs baseline: 3.6511x; 3.6511x over previous
//
#include <hip/hip_runtime.h>
#include <hip/hip_bf16.h>
#include <cstddef>

// ---------------------------------------------------------------------------
// TriangularSelfAttentionBlock: R1 — pair-MLP on bf16 MFMA, rest f32 baseline
// L=512, SEQ_D=1024, PAIR_D=128, H=32, HW=32, INNER=64
// ---------------------------------------------------------------------------

#define L 512
#define SEQ_D 1024
#define PAIR_D 128
#define NH 32
#define HW 32

typedef short bf16x8 __attribute__((ext_vector_type(8)));
typedef float f32x4 __attribute__((ext_vector_type(4)));

__device__ inline float wred_sum(float v) {
#pragma unroll
  for (int off = 32; off; off >>= 1) v += __shfl_xor(v, off, 64);
  return v;
}
__device__ inline float wred_max(float v) {
#pragma unroll
  for (int off = 32; off; off >>= 1) v = fmaxf(v, __shfl_xor(v, off, 64));
  return v;
}
__device__ inline void f4a(const float4 v, float* f) {
  f[0] = v.x; f[1] = v.y; f[2] = v.z; f[3] = v.w;
}
// f32 -> bf16 (RNE, finite inputs), packed pair
__device__ inline unsigned pk2(float a, float b) {
  unsigned ua = __float_as_uint(a), ub = __float_as_uint(b);
  ua = (ua + 0x7fffu + ((ua >> 16) & 1u)) >> 16;
  ub = (ub + 0x7fffu + ((ub >> 16) & 1u)) >> 16;
  return ua | (ub << 16);
}

// swizzled byte offset within a [row][256B] LDS tile (T2: spread 16B slots)
#define SWZ(row, kb) ((((row)) << 8) + ((kb) ^ (((row)&7) << 4)))

// ---------------- LayerNorm over 1024-dim rows -----------------------------
__global__ __launch_bounds__(256) void ln1024_kernel(
    const float* __restrict__ in, const float* __restrict__ g,
    const float* __restrict__ b, float* __restrict__ out) {
  const int row = blockIdx.x;
  const int tid = threadIdx.x;
  float4 v = ((const float4*)(in + (size_t)row * SEQ_D))[tid];
  float s = v.x + v.y + v.z + v.w;
  float s2 = v.x * v.x + v.y * v.y + v.z * v.z + v.w * v.w;
  __shared__ float red[8];
  const int lane = tid & 63, wid = tid >> 6;
  s = wred_sum(s);
  s2 = wred_sum(s2);
  if (lane == 0) { red[wid] = s; red[4 + wid] = s2; }
  __syncthreads();
  s = red[0] + red[1] + red[2] + red[3];
  s2 = red[4] + red[5] + red[6] + red[7];
  const float mean = s * (1.0f / SEQ_D);
  const float var = s2 * (1.0f / SEQ_D) - mean * mean;
  const float rstd = rsqrtf(var + 1e-5f);
  float4 gv = ((const float4*)g)[tid];
  float4 bv = ((const float4*)b)[tid];
  float4 o;
  o.x = (v.x - mean) * rstd * gv.x + bv.x;
  o.y = (v.y - mean) * rstd * gv.y + bv.y;
  o.z = (v.z - mean) * rstd * gv.z + bv.z;
  o.w = (v.w - mean) * rstd * gv.w + bv.w;
  ((float4*)(out + (size_t)row * SEQ_D))[tid] = o;
}

// ---------------- Generic GEMM: C[M][N] = A[M][K] @ B[N][K]^T --------------
template <bool BIAS, bool RELU, bool RES>
__global__ __launch_bounds__(256) void gemm_nt_kernel(
    const float* __restrict__ A, const float* __restrict__ B,
    const float* __restrict__ bias, const float* __restrict__ res,
    float* __restrict__ C, int M, int N, int K) {
  __shared__ float At[16][68];
  __shared__ float Bt[16][68];
  const int tid = threadIdx.x;
  const int ty = tid >> 4, tx = tid & 15;
  const int bm = blockIdx.y * 64, bn = blockIdx.x * 64;
  const int lr = tid >> 2, lc = (tid & 3) << 2;
  const float* Ap = A + (size_t)(bm + lr) * K + lc;
  const float* Bp = B + (size_t)(bn + lr) * K + lc;
  float acc[4][4] = {};
  for (int k0 = 0; k0 < K; k0 += 16) {
    float4 av = *(const float4*)(Ap + k0);
    float4 bv = *(const float4*)(Bp + k0);
    At[lc + 0][lr] = av.x; At[lc + 1][lr] = av.y;
    At[lc + 2][lr] = av.z; At[lc + 3][lr] = av.w;
    Bt[lc + 0][lr] = bv.x; Bt[lc + 1][lr] = bv.y;
    Bt[lc + 2][lr] = bv.z; Bt[lc + 3][lr] = bv.w;
    __syncthreads();
#pragma unroll
    for (int kk = 0; kk < 16; ++kk) {
      float a[4], bb[4];
      f4a(*(const float4*)&At[kk][ty << 2], a);
      f4a(*(const float4*)&Bt[kk][tx << 2], bb);
#pragma unroll
      for (int i = 0; i < 4; ++i)
#pragma unroll
        for (int j = 0; j < 4; ++j) acc[i][j] += a[i] * bb[j];
    }
    __syncthreads();
  }
#pragma unroll
  for (int i = 0; i < 4; ++i) {
    const int row = bm + (ty << 2) + i;
#pragma unroll
    for (int j = 0; j < 4; ++j) {
      const int col = bn + (tx << 2) + j;
      float v = acc[i][j];
      if (BIAS) v += bias[col];
      if (RELU) v = fmaxf(v, 0.0f);
      if (RES) v += res[(size_t)row * N + col];
      C[(size_t)row * N + col] = v;
    }
  }
}

// ---------------- PairToSequence: biasT[h][i][j] = LN(pair[i,j]) . W[h] ----
__global__ __launch_bounds__(256) void p2s_bias_kernel(
    const float* __restrict__ pair, const float* __restrict__ g,
    const float* __restrict__ b, const float* __restrict__ W,
    float* __restrict__ biasT) {
  __shared__ float xt[64][130];
  __shared__ float Ws[32][128];
  const int tid = threadIdx.x;
  const int lane = tid & 63, wid = tid >> 6;
  const int r0 = blockIdx.x * 64;
  {
    const float4* W4 = (const float4*)W;
    float4* Ws4 = (float4*)&Ws[0][0];
#pragma unroll
    for (int u = 0; u < 4; ++u) Ws4[tid + u * 256] = W4[tid + u * 256];
  }
  const float g0 = g[lane], g1 = g[lane + 64];
  const float b0 = b[lane], b1 = b[lane + 64];
  for (int q = 0; q < 16; ++q) {
    const int r = wid * 16 + q;
    const float* xr = pair + (size_t)(r0 + r) * PAIR_D;
    const float x0 = xr[lane], x1 = xr[lane + 64];
    const float s = wred_sum(x0 + x1);
    const float s2 = wred_sum(x0 * x0 + x1 * x1);
    const float mean = s * (1.0f / PAIR_D);
    const float var = s2 * (1.0f / PAIR_D) - mean * mean;
    const float rstd = rsqrtf(var + 1e-5f);
    xt[r][lane] = (x0 - mean) * rstd * g0 + b0;
    xt[r][lane + 64] = (x1 - mean) * rstd * g1 + b1;
  }
  __syncthreads();
  const int rl = tid & 63, h0 = (tid >> 6) << 3;
  float acc[8] = {};
  for (int c = 0; c < 128; c += 4) {
    float xa[4];
#pragma unroll
    for (int u = 0; u < 4; ++u) xa[u] = xt[rl][c + u];
#pragma unroll
    for (int j = 0; j < 8; ++j) {
      float w[4];
      f4a(*(const float4*)&Ws[h0 + j][c], w);
      acc[j] += xa[0] * w[0] + xa[1] * w[1] + xa[2] * w[2] + xa[3] * w[3];
    }
  }
  const int i_idx = r0 >> 9, j0 = r0 & 511;
#pragma unroll
  for (int j = 0; j < 8; ++j)
    biasT[(size_t)(h0 + j) * (L * L) + (size_t)i_idx * L + (j0 + rl)] = acc[j];
}

// ---------------- scores: S[h][q][k] = scale*Q.K + biasT -------------------
__global__ __launch_bounds__(256) void scores_kernel(
    const float* __restrict__ t, const float* __restrict__ biasT,
    float* __restrict__ S) {
  const int h = blockIdx.z, q0 = blockIdx.y * 64, k0 = blockIdx.x * 64;
  __shared__ float Qs[64][33];
  __shared__ float Ks[64][33];
  const int tid = threadIdx.x;
#pragma unroll
  for (int u = 0; u < 2; ++u) {
    const int f4 = tid + u * 256;
    const int r = f4 >> 3, c4 = (f4 & 7) << 2;
    float4 qv = *(const float4*)(t + (size_t)(q0 + r) * 3072 + h * 96 + c4);
    Qs[r][c4 + 0] = qv.x; Qs[r][c4 + 1] = qv.y;
    Qs[r][c4 + 2] = qv.z; Qs[r][c4 + 3] = qv.w;
    float4 kv = *(const float4*)(t + (size_t)(k0 + r) * 3072 + h * 96 + 32 + c4);
    Ks[r][c4 + 0] = kv.x; Ks[r][c4 + 1] = kv.y;
    Ks[r][c4 + 2] = kv.z; Ks[r][c4 + 3] = kv.w;
  }
  __syncthreads();
  const int ty = tid >> 4, tx = tid & 15;
  float acc[4][4] = {};
  for (int c = 0; c < 32; ++c) {
    float a[4], bb[4];
#pragma unroll
    for (int i = 0; i < 4; ++i) a[i] = Qs[(ty << 2) + i][c];
#pragma unroll
    for (int j = 0; j < 4; ++j) bb[j] = Ks[tx + (j << 4)][c];
#pragma unroll
    for (int i = 0; i < 4; ++i)
#pragma unroll
      for (int j = 0; j < 4; ++j) acc[i][j] += a[i] * bb[j];
  }
  const float scale = 0.17677669529663689f;
#pragma unroll
  for (int i = 0; i < 4; ++i) {
    const int q = q0 + (ty << 2) + i;
#pragma unroll
    for (int j = 0; j < 4; ++j) {
      const int k = k0 + tx + (j << 4);
      const size_t idx = ((size_t)h * L + q) * L + k;
      S[idx] = acc[i][j] * scale + biasT[idx];
    }
  }
}

// ---------------- softmax over last dim (512) ------------------------------
__global__ __launch_bounds__(256) void softmax_kernel(float* __restrict__ S) {
  float* x = S + (size_t)blockIdx.x * L;
  const int tid = threadIdx.x;
  float2 v = ((float2*)x)[tid];
  __shared__ float red[4];
  const int lane = tid & 63, wid = tid >> 6;
  float m = wred_max(fmaxf(v.x, v.y));
  if (lane == 0) red[wid] = m;
  __syncthreads();
  m = fmaxf(fmaxf(red[0], red[1]), fmaxf(red[2], red[3]));
  const float e0 = __expf(v.x - m), e1 = __expf(v.y - m);
  float s = wred_sum(e0 + e1);
  __syncthreads();
  if (lane == 0) red[wid] = s;
  __syncthreads();
  s = red[0] + red[1] + red[2] + red[3];
  const float inv = 1.0f / s;
  ((float2*)x)[tid] = make_float2(e0 * inv, e1 * inv);
}

// ---------------- PV: o[q][h*32+c] = sum_k S[h][q][k] * V[k][c] ------------
__global__ __launch_bounds__(256) void pv_kernel(
    const float* __restrict__ S, const float* __restrict__ t,
    float* __restrict__ o) {
  const int h = blockIdx.x, q0 = blockIdx.y * 64;
  __shared__ float Ss[64][68];
  __shared__ float Vs[64][33];
  const int tid = threadIdx.x;
  const int c = tid & 31, ty = tid >> 5;
  float acc[8] = {};
  for (int kt = 0; kt < L; kt += 64) {
#pragma unroll
    for (int u = 0; u < 4; ++u) {
      const int f4 = tid + u * 256;
      const int r = f4 >> 4, c4 = (f4 & 15) << 2;
      float4 sv = *(const float4*)(S + ((size_t)h * L + q0 + r) * L + kt + c4);
      Ss[r][c4 + 0] = sv.x; Ss[r][c4 + 1] = sv.y;
      Ss[r][c4 + 2] = sv.z; Ss[r][c4 + 3] = sv.w;
    }
#pragma unroll
    for (int u = 0; u < 2; ++u) {
      const int f4 = tid + u * 256;
      const int r = f4 >> 3, c4 = (f4 & 7) << 2;
      float4 vv = *(const float4*)(t + (size_t)(kt + r) * 3072 + h * 96 + 64 + c4);
      Vs[r][c4 + 0] = vv.x; Vs[r][c4 + 1] = vv.y;
      Vs[r][c4 + 2] = vv.z; Vs[r][c4 + 3] = vv.w;
    }
    __syncthreads();
    for (int kk = 0; kk < 64; kk += 4) {
      float vv[4];
#pragma unroll
      for (int u = 0; u < 4; ++u) vv[u] = Vs[kk + u][c];
#pragma unroll
      for (int i = 0; i < 8; ++i) {
        float s4[4];
        f4a(*(const float4*)&Ss[ty * 8 + i][kk], s4);
        acc[i] += s4[0] * vv[0] + s4[1] * vv[1] + s4[2] * vv[2] + s4[3] * vv[3];
      }
    }
    __syncthreads();
  }
#pragma unroll
  for (int i = 0; i < 8; ++i) {
    const int q = q0 + ty * 8 + i;
    o[(size_t)q * SEQ_D + h * HW + c] = acc[i];
  }
}

// ---------------- gate: o *= sigmoid(g) ------------------------------------
__global__ __launch_bounds__(256) void gate_kernel(float* __restrict__ o,
                                                   const float* __restrict__ g) {
  const int i = blockIdx.x * 256 + threadIdx.x;
  float4 ov = ((float4*)o)[i];
  float4 gv = ((const float4*)g)[i];
  ov.x *= 1.0f / (1.0f + __expf(-gv.x));
  ov.y *= 1.0f / (1.0f + __expf(-gv.y));
  ov.z *= 1.0f / (1.0f + __expf(-gv.z));
  ov.w *= 1.0f / (1.0f + __expf(-gv.w));
  ((float4*)o)[i] = ov;
}

// ---------------- SequenceToPair: p = pairwise + X @ Wspo^T + bspo ---------
__global__ __launch_bounds__(256) void pair1_kernel(
    const float* __restrict__ sp, const float* __restrict__ Wspo,
    const float* __restrict__ bspo, const float* __restrict__ pairwise,
    float* __restrict__ pout) {
  __shared__ float xs[64][129];
  __shared__ float Ws[128][34];
  __shared__ float khs[64];
  const int tid = threadIdx.x;
  const int r0 = blockIdx.x * 64;
  const int i_idx = r0 >> 9, j0 = r0 & 511;
  if (tid < 64) khs[tid] = sp[(size_t)i_idx * 128 + 64 + tid];
  __syncthreads();
  for (int idx = tid; idx < 64 * 128; idx += 256) {
    const int r = idx >> 7, cc = idx & 127;
    const float q_ = sp[(size_t)(j0 + r) * 128 + (cc & 63)];
    const float k_ = khs[cc & 63];
    xs[r][cc] = (cc < 64) ? q_ * k_ : q_ - k_;
  }
  const int ty = tid >> 4, tx = tid & 15;
  float acc[4][8] = {};
  for (int cs = 0; cs < 128; cs += 32) {
    __syncthreads();
#pragma unroll
    for (int u = 0; u < 4; ++u) {
      const int f4 = tid + u * 256;
      const int n = f4 >> 3, c4 = (f4 & 7) << 2;
      float4 wv = *(const float4*)(Wspo + (size_t)n * 128 + cs + c4);
      Ws[n][c4 + 0] = wv.x; Ws[n][c4 + 1] = wv.y;
      Ws[n][c4 + 2] = wv.z; Ws[n][c4 + 3] = wv.w;
    }
    __syncthreads();
    for (int ci = 0; ci < 32; ++ci) {
      float xa[4];
#pragma unroll
      for (int ir = 0; ir < 4; ++ir) xa[ir] = xs[ty + (ir << 4)][cs + ci];
#pragma unroll
      for (int jm = 0; jm < 8; ++jm) {
        const float w = Ws[tx + (jm << 4)][ci];
#pragma unroll
        for (int ir = 0; ir < 4; ++ir) acc[ir][jm] += xa[ir] * w;
      }
    }
  }
#pragma unroll
  for (int ir = 0; ir < 4; ++ir) {
    const size_t rowg = (size_t)(r0 + ty + (ir << 4));
#pragma unroll
    for (int jm = 0; jm < 8; ++jm) {
      const int m = tx + (jm << 4);
      pout[rowg * 128 + m] = acc[ir][jm] + bspo[m] + pairwise[rowg * 128 + m];
    }
  }
}

// ---------------- pair MLP via bf16 MFMA (in-place on p) -------------------
// p = p + relu(LN(p) @ Wp1^T + bp1) @ Wp2^T + bp2
// 128-row tile, 4 waves (2x2 of 64x64), mfma_f32_16x16x32_bf16.
// LDS: [0,32K) pn (bf16, swizzled) reused as H; [32K,64K) weight chunk.
__global__ __launch_bounds__(256, 2) void pair2_mfma_kernel(
    float* __restrict__ p, const float* __restrict__ lng,
    const float* __restrict__ lnb, const float* __restrict__ Wp1,
    const float* __restrict__ bp1, const float* __restrict__ Wp2,
    const float* __restrict__ bp2) {
  __shared__ __align__(16) char smem[65536];
  char* pnb = smem;            // pn (then H), 128 rows x 256B, swizzled
  char* wbuf = smem + 32768;   // weight chunk, 128 rows x 256B, swizzled

  const int tid = threadIdx.x;
  const int l = tid & 63, wid = tid >> 6;
  const int wr = wid >> 1, wc = wid & 1;     // wave grid 2x2
  const int lane16 = l & 15, g16 = l >> 4;   // frag coords
  const size_t r0 = (size_t)blockIdx.x * 128;

  // ---- LN(p) -> bf16 swizzled LDS ----
  {
    const int l32 = l & 31, half = l >> 5;
    const float4 gv = *(const float4*)(lng + l32 * 4);
    const float4 bv = *(const float4*)(lnb + l32 * 4);
    for (int it = 0; it < 16; ++it) {
      const int r = it * 8 + wid * 2 + half;
      const float4 v = *(const float4*)(p + (r0 + r) * 128 + l32 * 4);
      float s = v.x + v.y + v.z + v.w;
      float s2 = v.x * v.x + v.y * v.y + v.z * v.z + v.w * v.w;
#pragma unroll
      for (int off = 1; off < 32; off <<= 1) {
        s += __shfl_xor(s, off, 64);
        s2 += __shfl_xor(s2, off, 64);
      }
      const float mean = s * (1.0f / 128.0f);
      const float rstd = rsqrtf(s2 * (1.0f / 128.0f) - mean * mean + 1e-5f);
      const float n0 = (v.x - mean) * rstd * gv.x + bv.x;
      const float n1 = (v.y - mean) * rstd * gv.y + bv.y;
      const float n2 = (v.z - mean) * rstd * gv.z + bv.z;
      const float n3 = (v.w - mean) * rstd * gv.w + bv.w;
      uint2 pkd; pkd.x = pk2(n0, n1); pkd.y = pk2(n2, n3);
      *(uint2*)(pnb + SWZ(r, l32 * 8)) = pkd;
    }
  }
  __syncthreads();

  // ---- hoist A fragments (this wave's 64 rows x full K=128) to registers --
  bf16x8 Areg[4][4];
#pragma unroll
  for (int rb = 0; rb < 4; ++rb)
#pragma unroll
    for (int kk = 0; kk < 4; ++kk)
      Areg[rb][kk] =
          *(const bf16x8*)(pnb + SWZ(wr * 64 + rb * 16 + lane16, kk * 64 + g16 * 16));

  const f32x4 fzero = {0.f, 0.f, 0.f, 0.f};
  f32x4 acc2[4][4];
#pragma unroll
  for (int i = 0; i < 4; ++i)
#pragma unroll
    for (int j = 0; j < 4; ++j) acc2[i][j] = fzero;

  const int slot = tid & 15, rowg = tid >> 4;

  for (int nc = 0; nc < 4; ++nc) {
    __syncthreads();  // A-load / previous GEMM2 reads complete
    // ---- stage W1 chunk: Wp1[nc*128 + row][0:128] f32 -> bf16 swizzled ----
#pragma unroll
    for (int u = 0; u < 8; ++u) {
      const int row = rowg * 8 + u;
      const float4* src =
          (const float4*)(Wp1 + (size_t)(nc * 128 + row) * 128 + slot * 8);
      const float4 v0 = src[0], v1 = src[1];
      uint4 w;
      w.x = pk2(v0.x, v0.y); w.y = pk2(v0.z, v0.w);
      w.z = pk2(v1.x, v1.y); w.w = pk2(v1.z, v1.w);
      *(uint4*)(wbuf + SWZ(row, slot * 16)) = w;
    }
    __syncthreads();
    // ---- GEMM1: H^T = W1c @ pn^T, bias+relu, write H row-major ----
#pragma unroll
    for (int nb = 0; nb < 4; ++nb) {
      f32x4 hacc[4];
#pragma unroll
      for (int rb = 0; rb < 4; ++rb) hacc[rb] = fzero;
#pragma unroll
      for (int kk = 0; kk < 4; ++kk) {
        const bf16x8 wf = *(const bf16x8*)(
            wbuf + SWZ(wc * 64 + nb * 16 + lane16, kk * 64 + g16 * 16));
#pragma unroll
        for (int rb = 0; rb < 4; ++rb)
          hacc[rb] = __builtin_amdgcn_mfma_f32_16x16x32_bf16(
              wf, Areg[rb][kk], hacc[rb], 0, 0, 0);
      }
      const int nbase = nc * 128 + wc * 64 + nb * 16 + g16 * 4;
      float bi[4];
#pragma unroll
      for (int q = 0; q < 4; ++q) bi[q] = bp1[nbase + q];
#pragma unroll
      for (int rb = 0; rb < 4; ++rb) {
        const int row = wr * 64 + rb * 16 + lane16;
        const float v0 = fmaxf(hacc[rb][0] + bi[0], 0.f);
        const float v1 = fmaxf(hacc[rb][1] + bi[1], 0.f);
        const float v2 = fmaxf(hacc[rb][2] + bi[2], 0.f);
        const float v3 = fmaxf(hacc[rb][3] + bi[3], 0.f);
        uint2 pkd; pkd.x = pk2(v0, v1); pkd.y = pk2(v2, v3);
        *(uint2*)(pnb + SWZ(row, wc * 128 + nb * 32 + g16 * 8)) = pkd;
      }
    }
    __syncthreads();  // H ready; W1 reads done
    // ---- stage W2 chunk: Wp2[m][nc*128 : +128] f32 -> bf16 swizzled ----
#pragma unroll
    for (int u = 0; u < 8; ++u) {
      const int row = rowg * 8 + u;
      const float4* src =
          (const float4*)(Wp2 + (size_t)row * 512 + nc * 128 + slot * 8);
      const float4 v0 = src[0], v1 = src[1];
      uint4 w;
      w.x = pk2(v0.x, v0.y); w.y = pk2(v0.z, v0.w);
      w.z = pk2(v1.x, v1.y); w.w = pk2(v1.z, v1.w);
      *(uint4*)(wbuf + SWZ(row, slot * 16)) = w;
    }
    __syncthreads();
    // ---- GEMM2: out += H @ W2c^T ----
#pragma unroll
    for (int kk = 0; kk < 4; ++kk) {
      bf16x8 hf[4];
#pragma unroll
      for (int rb = 0; rb < 4; ++rb)
        hf[rb] = *(const bf16x8*)(
            pnb + SWZ(wr * 64 + rb * 16 + lane16, kk * 64 + g16 * 16));
#pragma unroll
      for (int mb = 0; mb < 4; ++mb) {
        const bf16x8 w2f = *(const bf16x8*)(
            wbuf + SWZ(wc * 64 + mb * 16 + lane16, kk * 64 + g16 * 16));
#pragma unroll
        for (int rb = 0; rb < 4; ++rb)
          acc2[rb][mb] = __builtin_amdgcn_mfma_f32_16x16x32_bf16(
              hf[rb], w2f, acc2[rb][mb], 0, 0, 0);
      }
    }
  }

  // ---- epilogue: p += acc + bp2 (residual read from global, in-place) ----
#pragma unroll
  for (int mb = 0; mb < 4; ++mb) {
    const int m = wc * 64 + mb * 16 + lane16;
    const float b2 = bp2[m];
#pragma unroll
    for (int rb = 0; rb < 4; ++rb) {
#pragma unroll
      for (int q = 0; q < 4; ++q) {
        const int row = wr * 64 + rb * 16 + g16 * 4 + q;
        const size_t gi = (r0 + row) * 128 + m;
        p[gi] = acc2[rb][mb][q] + b2 + p[gi];
      }
    }
  }
}

// ---------------------------------------------------------------------------
extern "C" void kernel_launch(void* const* d_in, const int* in_sizes, int n_in,
                              void* d_out, int out_size, void* d_ws,
                              size_t ws_size, hipStream_t stream) {
  (void)in_sizes; (void)n_in; (void)out_size; (void)ws_size;
  const float* seq      = (const float*)d_in[0];
  const float* pair     = (const float*)d_in[1];
  const float* ln_p2s_g = (const float*)d_in[2];
  const float* ln_p2s_b = (const float*)d_in[3];
  const float* W_p2s    = (const float*)d_in[4];
  const float* ln1_g    = (const float*)d_in[5];
  const float* ln1_b    = (const float*)d_in[6];
  const float* Wqkv     = (const float*)d_in[7];
  const float* Wo       = (const float*)d_in[8];
  const float* bo       = (const float*)d_in[9];
  const float* Wg       = (const float*)d_in[10];
  const float* bg       = (const float*)d_in[11];
  const float* ln_s_g   = (const float*)d_in[12];
  const float* ln_s_b   = (const float*)d_in[13];
  const float* Wm1      = (const float*)d_in[14];
  const float* bm1      = (const float*)d_in[15];
  const float* Wm2      = (const float*)d_in[16];
  const float* bm2      = (const float*)d_in[17];
  const float* ln_sp_g  = (const float*)d_in[18];
  const float* ln_sp_b  = (const float*)d_in[19];
  const float* Wsp      = (const float*)d_in[20];
  const float* bsp      = (const float*)d_in[21];
  const float* Wspo     = (const float*)d_in[22];
  const float* bspo     = (const float*)d_in[23];
  const float* ln_mp_g  = (const float*)d_in[24];
  const float* ln_mp_b  = (const float*)d_in[25];
  const float* Wp1      = (const float*)d_in[26];
  const float* bp1      = (const float*)d_in[27];
  const float* Wp2      = (const float*)d_in[28];
  const float* bp2      = (const float*)d_in[29];

  float* out_s = (float*)d_out;            // 512*1024
  float* out_p = out_s + 512 * 1024;       // 512*512*128

  float* ws  = (float*)d_ws;
  float* y   = ws;                  // 524288
  float* t   = y + 524288;          // 1572864 (qkv)
  float* g   = t + 1572864;         // 524288 (gate logits)
  float* o   = g + 524288;          // 524288 (attn out)
  float* s1  = o + 524288;          // 524288
  float* h1  = s1 + 524288;         // 2097152 (mlp hidden)
  float* spb = h1 + 2097152;        // 65536 (qh|kh)

  // scratch inside d_out's p-section (written only at the very end):
  float* biasT = out_p;             // 32*512*512
  float* S     = out_p + 8388608;   // 32*512*512

  ln1024_kernel<<<512, 256, 0, stream>>>(seq, ln1_g, ln1_b, y);
  gemm_nt_kernel<false, false, false><<<dim3(48, 8), 256, 0, stream>>>(
      y, Wqkv, nullptr, nullptr, t, 512, 3072, 1024);
  gemm_nt_kernel<true, false, false><<<dim3(16, 8), 256, 0, stream>>>(
      y, Wg, bg, nullptr, g, 512, 1024, 1024);
  p2s_bias_kernel<<<4096, 256, 0, stream>>>(pair, ln_p2s_g, ln_p2s_b, W_p2s, biasT);
  scores_kernel<<<dim3(8, 8, 32), 256, 0, stream>>>(t, biasT, S);
  softmax_kernel<<<16384, 256, 0, stream>>>(S);
  pv_kernel<<<dim3(32, 8), 256, 0, stream>>>(S, t, o);
  gate_kernel<<<512, 256, 0, stream>>>(o, g);
  gemm_nt_kernel<true, false, true><<<dim3(16, 8), 256, 0, stream>>>(
      o, Wo, bo, seq, s1, 512, 1024, 1024);
  ln1024_kernel<<<512, 256, 0, stream>>>(s1, ln_s_g, ln_s_b, y);
  gemm_nt_kernel<true, true, false><<<dim3(64, 8), 256, 0, stream>>>(
      y, Wm1, bm1, nullptr, h1, 512, 4096, 1024);
  gemm_nt_kernel<true, false, true><<<dim3(16, 8), 256, 0, stream>>>(
      h1, Wm2, bm2, s1, out_s, 512, 1024, 4096);
  ln1024_kernel<<<512, 256, 0, stream>>>(out_s, ln_sp_g, ln_sp_b, y);
  gemm_nt_kernel<true, false, false><<<dim3(2, 8), 256, 0, stream>>>(
      y, Wsp, bsp, nullptr, spb, 512, 128, 1024);
  pair1_kernel<<<4096, 256, 0, stream>>>(spb, Wspo, bspo, pair, out_p);
  pair2_mfma_kernel<<<2048, 256, 0, stream>>>(out_p, ln_mp_g, ln_mp_b, Wp1, bp1,
                                              Wp2, bp2);
}

// Round 3
// 712.522 us; speedup vs baseline: 5.5058x; 1.5080x over previous
//
#include <hip/hip_runtime.h>
#include <hip/hip_bf16.h>
#include <cstddef>

// ---------------------------------------------------------------------------
// TriangularSelfAttentionBlock R3: MFMA everywhere except attention inner path
// L=512, SEQ_D=1024, PAIR_D=128, H=32, HW=32, INNER=64
// ---------------------------------------------------------------------------

#define L 512
#define SEQ_D 1024
#define PAIR_D 128
#define NH 32
#define HW 32

typedef short bf16x8 __attribute__((ext_vector_type(8)));
typedef float f32x4 __attribute__((ext_vector_type(4)));
typedef unsigned short ushort_t;

__device__ inline float wred_sum(float v) {
#pragma unroll
  for (int off = 32; off; off >>= 1) v += __shfl_xor(v, off, 64);
  return v;
}
__device__ inline float wred_max(float v) {
#pragma unroll
  for (int off = 32; off; off >>= 1) v = fmaxf(v, __shfl_xor(v, off, 64));
  return v;
}
__device__ inline void f4a(const float4 v, float* f) {
  f[0] = v.x; f[1] = v.y; f[2] = v.z; f[3] = v.w;
}
// f32 -> bf16 (RNE), packed pair (a low, b high)
__device__ inline unsigned pk2(float a, float b) {
  unsigned ua = __float_as_uint(a), ub = __float_as_uint(b);
  ua = (ua + 0x7fffu + ((ua >> 16) & 1u)) >> 16;
  ub = (ub + 0x7fffu + ((ub >> 16) & 1u)) >> 16;
  return ua | (ub << 16);
}
__device__ inline float bfl(unsigned u) { return __uint_as_float(u << 16); }
__device__ inline float bfh(unsigned u) { return __uint_as_float(u & 0xffff0000u); }

// swizzled byte offset for [row][256B] LDS tiles
#define SWZ(row, kb) ((((row)) << 8) + ((kb) ^ (((row)&7) << 4)))
// swizzled byte offset for [row][128B] LDS tiles
#define SWZ64(row, kb) ((((row)) << 7) + ((kb) ^ (((row)&7) << 4)))

// ---------------- fused f32->bf16 weight conversion (9 tensors) ------------
__global__ __launch_bounds__(256) void cvt9_kernel(
    const float* __restrict__ s0, ushort_t* __restrict__ d0,   // Wqkv 1536 blk
    const float* __restrict__ s1, ushort_t* __restrict__ d1,   // Wg 512
    const float* __restrict__ s2, ushort_t* __restrict__ d2,   // Wo 512
    const float* __restrict__ s3, ushort_t* __restrict__ d3,   // Wm1 2048
    const float* __restrict__ s4, ushort_t* __restrict__ d4,   // Wm2 2048
    const float* __restrict__ s5, ushort_t* __restrict__ d5,   // Wsp 64
    const float* __restrict__ s6, ushort_t* __restrict__ d6,   // Wspo 8
    const float* __restrict__ s7, ushort_t* __restrict__ d7,   // Wp1 32
    const float* __restrict__ s8, ushort_t* __restrict__ d8) { // Wp2 32
  const int b = blockIdx.x;
  const float* s; ushort_t* d; int base;
  if (b < 1536)      { s = s0; d = d0; base = b; }
  else if (b < 2048) { s = s1; d = d1; base = b - 1536; }
  else if (b < 2560) { s = s2; d = d2; base = b - 2048; }
  else if (b < 4608) { s = s3; d = d3; base = b - 2560; }
  else if (b < 6656) { s = s4; d = d4; base = b - 4608; }
  else if (b < 6720) { s = s5; d = d5; base = b - 6656; }
  else if (b < 6728) { s = s6; d = d6; base = b - 6720; }
  else if (b < 6760) { s = s7; d = d7; base = b - 6728; }
  else               { s = s8; d = d8; base = b - 6760; }
  const int i = base * 256 + threadIdx.x;
  float4 a = ((const float4*)s)[2 * i], c = ((const float4*)s)[2 * i + 1];
  uint4 w;
  w.x = pk2(a.x, a.y); w.y = pk2(a.z, a.w);
  w.z = pk2(c.x, c.y); w.w = pk2(c.z, c.w);
  ((uint4*)d)[i] = w;
}

// ---------------- LayerNorm 1024 -> bf16 out -------------------------------
__global__ __launch_bounds__(256) void ln1024b_kernel(
    const float* __restrict__ in, const float* __restrict__ g,
    const float* __restrict__ b, ushort_t* __restrict__ out) {
  const int row = blockIdx.x;
  const int tid = threadIdx.x;
  float4 v = ((const float4*)(in + (size_t)row * SEQ_D))[tid];
  float s = v.x + v.y + v.z + v.w;
  float s2 = v.x * v.x + v.y * v.y + v.z * v.z + v.w * v.w;
  __shared__ float red[8];
  const int lane = tid & 63, wid = tid >> 6;
  s = wred_sum(s);
  s2 = wred_sum(s2);
  if (lane == 0) { red[wid] = s; red[4 + wid] = s2; }
  __syncthreads();
  s = red[0] + red[1] + red[2] + red[3];
  s2 = red[4] + red[5] + red[6] + red[7];
  const float mean = s * (1.0f / SEQ_D);
  const float var = s2 * (1.0f / SEQ_D) - mean * mean;
  const float rstd = rsqrtf(var + 1e-5f);
  float4 gv = ((const float4*)g)[tid];
  float4 bv = ((const float4*)b)[tid];
  const float o0 = (v.x - mean) * rstd * gv.x + bv.x;
  const float o1 = (v.y - mean) * rstd * gv.y + bv.y;
  const float o2 = (v.z - mean) * rstd * gv.z + bv.z;
  const float o3 = (v.w - mean) * rstd * gv.w + bv.w;
  uint2 pkd; pkd.x = pk2(o0, o1); pkd.y = pk2(o2, o3);
  ((uint2*)(out + (size_t)row * SEQ_D))[tid] = pkd;
}

// ---------------- MFMA GEMM: C[M][N] = A[M][K](bf16) @ B[N][K]^T(bf16) -----
// BM=64 BN=128 BK=64, 4 waves (2x2), wave tile 32x64, T-layout output.
template <int BIAS, int RELU, int RES, int OBF16>
__global__ __launch_bounds__(256, 2) void gemm_mfma_kernel(
    const ushort_t* __restrict__ A, const ushort_t* __restrict__ B,
    const float* __restrict__ bias, const float* __restrict__ res,
    float* __restrict__ C, ushort_t* __restrict__ Cb, int M, int N, int K) {
  __shared__ __align__(16) char smem[24576];
  char* Ab = smem;           // 64 rows x 128B (swizzled)
  char* Bb = smem + 8192;    // 128 rows x 128B (swizzled)
  const int tid = threadIdx.x;
  const int l = tid & 63, w = tid >> 6;
  const int wr = w >> 1, wc = w & 1;
  const int lane16 = l & 15, g16 = l >> 4;
  const int bm = blockIdx.y * 64, bn = blockIdx.x * 128;
  const f32x4 fz = {0.f, 0.f, 0.f, 0.f};
  f32x4 acc[4][2];
#pragma unroll
  for (int i = 0; i < 4; ++i)
#pragma unroll
    for (int j = 0; j < 2; ++j) acc[i][j] = fz;

  for (int k0 = 0; k0 < K; k0 += 64) {
    __syncthreads();
#pragma unroll
    for (int u = 0; u < 2; ++u) {
      const int slot = u * 256 + tid;
      const int row = slot >> 3, sl = slot & 7;
      bf16x8 v = *(const bf16x8*)(A + (size_t)(bm + row) * K + k0 + sl * 8);
      *(bf16x8*)(Ab + SWZ64(row, sl * 16)) = v;
    }
#pragma unroll
    for (int u = 0; u < 4; ++u) {
      const int slot = u * 256 + tid;
      const int row = slot >> 3, sl = slot & 7;
      bf16x8 v = *(const bf16x8*)(B + (size_t)(bn + row) * K + k0 + sl * 8);
      *(bf16x8*)(Bb + SWZ64(row, sl * 16)) = v;
    }
    __syncthreads();
#pragma unroll
    for (int kk = 0; kk < 2; ++kk) {
      const int kb = kk * 64 + g16 * 16;
      bf16x8 af[2], bf[4];
#pragma unroll
      for (int rb = 0; rb < 2; ++rb) {
        const int row = wr * 32 + rb * 16 + lane16;
        af[rb] = *(const bf16x8*)(Ab + SWZ64(row, kb));
      }
#pragma unroll
      for (int cb = 0; cb < 4; ++cb) {
        const int row = wc * 64 + cb * 16 + lane16;
        bf[cb] = *(const bf16x8*)(Bb + SWZ64(row, kb));
      }
#pragma unroll
      for (int cb = 0; cb < 4; ++cb)
#pragma unroll
        for (int rb = 0; rb < 2; ++rb)
          acc[cb][rb] = __builtin_amdgcn_mfma_f32_16x16x32_bf16(
              bf[cb], af[rb], acc[cb][rb], 0, 0, 0);
    }
  }
#pragma unroll
  for (int cb = 0; cb < 4; ++cb) {
    const int col0 = bn + wc * 64 + cb * 16 + g16 * 4;
    float4 bi = make_float4(0.f, 0.f, 0.f, 0.f);
    if (BIAS) bi = *(const float4*)(bias + col0);
#pragma unroll
    for (int rb = 0; rb < 2; ++rb) {
      const int row = bm + wr * 32 + rb * 16 + lane16;
      f32x4 v = acc[cb][rb];
      v[0] += bi.x; v[1] += bi.y; v[2] += bi.z; v[3] += bi.w;
      if (RELU) {
        v[0] = fmaxf(v[0], 0.f); v[1] = fmaxf(v[1], 0.f);
        v[2] = fmaxf(v[2], 0.f); v[3] = fmaxf(v[3], 0.f);
      }
      if (RES) {
        const float4 r4 = *(const float4*)(res + (size_t)row * N + col0);
        v[0] += r4.x; v[1] += r4.y; v[2] += r4.z; v[3] += r4.w;
      }
      if (OBF16) {
        uint2 pkd; pkd.x = pk2(v[0], v[1]); pkd.y = pk2(v[2], v[3]);
        *(uint2*)(Cb + (size_t)row * N + col0) = pkd;
      } else {
        float4 o4; o4.x = v[0]; o4.y = v[1]; o4.z = v[2]; o4.w = v[3];
        *(float4*)(C + (size_t)row * N + col0) = o4;
      }
    }
  }
}

// ---------------- PairToSequence: biasT[h][i][j] = LN(pair[i,j]) . W[h] ----
__global__ __launch_bounds__(256) void p2s_bias_kernel(
    const float* __restrict__ pair, const float* __restrict__ g,
    const float* __restrict__ b, const float* __restrict__ W,
    float* __restrict__ biasT) {
  __shared__ float xt[64][130];
  __shared__ float Ws[32][128];
  const int tid = threadIdx.x;
  const int lane = tid & 63, wid = tid >> 6;
  const int r0 = blockIdx.x * 64;
  {
    const float4* W4 = (const float4*)W;
    float4* Ws4 = (float4*)&Ws[0][0];
#pragma unroll
    for (int u = 0; u < 4; ++u) Ws4[tid + u * 256] = W4[tid + u * 256];
  }
  const float g0 = g[lane], g1 = g[lane + 64];
  const float b0 = b[lane], b1 = b[lane + 64];
  for (int q = 0; q < 16; ++q) {
    const int r = wid * 16 + q;
    const float* xr = pair + (size_t)(r0 + r) * PAIR_D;
    const float x0 = xr[lane], x1 = xr[lane + 64];
    const float s = wred_sum(x0 + x1);
    const float s2 = wred_sum(x0 * x0 + x1 * x1);
    const float mean = s * (1.0f / PAIR_D);
    const float var = s2 * (1.0f / PAIR_D) - mean * mean;
    const float rstd = rsqrtf(var + 1e-5f);
    xt[r][lane] = (x0 - mean) * rstd * g0 + b0;
    xt[r][lane + 64] = (x1 - mean) * rstd * g1 + b1;
  }
  __syncthreads();
  const int rl = tid & 63, h0 = (tid >> 6) << 3;
  float acc[8] = {};
  for (int c = 0; c < 128; c += 4) {
    float xa[4];
#pragma unroll
    for (int u = 0; u < 4; ++u) xa[u] = xt[rl][c + u];
#pragma unroll
    for (int j = 0; j < 8; ++j) {
      float wv[4];
      f4a(*(const float4*)&Ws[h0 + j][c], wv);
      acc[j] += xa[0] * wv[0] + xa[1] * wv[1] + xa[2] * wv[2] + xa[3] * wv[3];
    }
  }
  const int i_idx = r0 >> 9, j0 = r0 & 511;
#pragma unroll
  for (int j = 0; j < 8; ++j)
    biasT[(size_t)(h0 + j) * (L * L) + (size_t)i_idx * L + (j0 + rl)] = acc[j];
}

// ---------------- scores: S[h][q][k] = scale*Q.K + biasT -------------------
__global__ __launch_bounds__(256) void scores_kernel(
    const float* __restrict__ t, const float* __restrict__ biasT,
    float* __restrict__ S) {
  const int h = blockIdx.z, q0 = blockIdx.y * 64, k0 = blockIdx.x * 64;
  __shared__ float Qs[64][33];
  __shared__ float Ks[64][33];
  const int tid = threadIdx.x;
#pragma unroll
  for (int u = 0; u < 2; ++u) {
    const int f4 = tid + u * 256;
    const int r = f4 >> 3, c4 = (f4 & 7) << 2;
    float4 qv = *(const float4*)(t + (size_t)(q0 + r) * 3072 + h * 96 + c4);
    Qs[r][c4 + 0] = qv.x; Qs[r][c4 + 1] = qv.y;
    Qs[r][c4 + 2] = qv.z; Qs[r][c4 + 3] = qv.w;
    float4 kv = *(const float4*)(t + (size_t)(k0 + r) * 3072 + h * 96 + 32 + c4);
    Ks[r][c4 + 0] = kv.x; Ks[r][c4 + 1] = kv.y;
    Ks[r][c4 + 2] = kv.z; Ks[r][c4 + 3] = kv.w;
  }
  __syncthreads();
  const int ty = tid >> 4, tx = tid & 15;
  float acc[4][4] = {};
  for (int c = 0; c < 32; ++c) {
    float a[4], bb[4];
#pragma unroll
    for (int i = 0; i < 4; ++i) a[i] = Qs[(ty << 2) + i][c];
#pragma unroll
    for (int j = 0; j < 4; ++j) bb[j] = Ks[tx + (j << 4)][c];
#pragma unroll
    for (int i = 0; i < 4; ++i)
#pragma unroll
      for (int j = 0; j < 4; ++j) acc[i][j] += a[i] * bb[j];
  }
  const float scale = 0.17677669529663689f;
#pragma unroll
  for (int i = 0; i < 4; ++i) {
    const int q = q0 + (ty << 2) + i;
#pragma unroll
    for (int j = 0; j < 4; ++j) {
      const int k = k0 + tx + (j << 4);
      const size_t idx = ((size_t)h * L + q) * L + k;
      S[idx] = acc[i][j] * scale + biasT[idx];
    }
  }
}

// ---------------- softmax over last dim (512) ------------------------------
__global__ __launch_bounds__(256) void softmax_kernel(float* __restrict__ S) {
  float* x = S + (size_t)blockIdx.x * L;
  const int tid = threadIdx.x;
  float2 v = ((float2*)x)[tid];
  __shared__ float red[4];
  const int lane = tid & 63, wid = tid >> 6;
  float m = wred_max(fmaxf(v.x, v.y));
  if (lane == 0) red[wid] = m;
  __syncthreads();
  m = fmaxf(fmaxf(red[0], red[1]), fmaxf(red[2], red[3]));
  const float e0 = __expf(v.x - m), e1 = __expf(v.y - m);
  float s = wred_sum(e0 + e1);
  __syncthreads();
  if (lane == 0) red[wid] = s;
  __syncthreads();
  s = red[0] + red[1] + red[2] + red[3];
  const float inv = 1.0f / s;
  ((float2*)x)[tid] = make_float2(e0 * inv, e1 * inv);
}

// ---------------- PV: o[q][h*32+c] = sum_k S[h][q][k] * V[k][c] ------------
__global__ __launch_bounds__(256) void pv_kernel(
    const float* __restrict__ S, const float* __restrict__ t,
    float* __restrict__ o) {
  const int h = blockIdx.x, q0 = blockIdx.y * 64;
  __shared__ float Ss[64][68];
  __shared__ float Vs[64][33];
  const int tid = threadIdx.x;
  const int c = tid & 31, ty = tid >> 5;
  float acc[8] = {};
  for (int kt = 0; kt < L; kt += 64) {
#pragma unroll
    for (int u = 0; u < 4; ++u) {
      const int f4 = tid + u * 256;
      const int r = f4 >> 4, c4 = (f4 & 15) << 2;
      float4 sv = *(const float4*)(S + ((size_t)h * L + q0 + r) * L + kt + c4);
      Ss[r][c4 + 0] = sv.x; Ss[r][c4 + 1] = sv.y;
      Ss[r][c4 + 2] = sv.z; Ss[r][c4 + 3] = sv.w;
    }
#pragma unroll
    for (int u = 0; u < 2; ++u) {
      const int f4 = tid + u * 256;
      const int r = f4 >> 3, c4 = (f4 & 7) << 2;
      float4 vv = *(const float4*)(t + (size_t)(kt + r) * 3072 + h * 96 + 64 + c4);
      Vs[r][c4 + 0] = vv.x; Vs[r][c4 + 1] = vv.y;
      Vs[r][c4 + 2] = vv.z; Vs[r][c4 + 3] = vv.w;
    }
    __syncthreads();
    for (int kk = 0; kk < 64; kk += 4) {
      float vv[4];
#pragma unroll
      for (int u = 0; u < 4; ++u) vv[u] = Vs[kk + u][c];
#pragma unroll
      for (int i = 0; i < 8; ++i) {
        float s4[4];
        f4a(*(const float4*)&Ss[ty * 8 + i][kk], s4);
        acc[i] += s4[0] * vv[0] + s4[1] * vv[1] + s4[2] * vv[2] + s4[3] * vv[3];
      }
    }
    __syncthreads();
  }
#pragma unroll
  for (int i = 0; i < 8; ++i) {
    const int q = q0 + ty * 8 + i;
    o[(size_t)q * SEQ_D + h * HW + c] = acc[i];
  }
}

// ---------------- gate: ob = bf16(o * sigmoid(g)) --------------------------
__global__ __launch_bounds__(256) void gate_b_kernel(
    const float* __restrict__ o, const float* __restrict__ g,
    ushort_t* __restrict__ ob) {
  const int i = blockIdx.x * 256 + threadIdx.x;
  float4 ov = ((const float4*)o)[i];
  float4 gv = ((const float4*)g)[i];
  ov.x *= 1.0f / (1.0f + __expf(-gv.x));
  ov.y *= 1.0f / (1.0f + __expf(-gv.y));
  ov.z *= 1.0f / (1.0f + __expf(-gv.z));
  ov.w *= 1.0f / (1.0f + __expf(-gv.w));
  uint2 pkd; pkd.x = pk2(ov.x, ov.y); pkd.y = pk2(ov.z, ov.w);
  ((uint2*)ob)[i] = pkd;
}

// ---------------- fused SequenceToPair + pair MLP --------------------------
// p = P + relu(LN(P) @ Wp1^T + bp1) @ Wp2^T + bp2,
// where P = pairwise + X @ Wspo^T + bspo, X = [qh*kh | qh-kh].
// 128-row tile, 4 waves (2x2 of 64x64), all GEMMs T-layout (lane16 = p-row).
__global__ __launch_bounds__(256, 2) void pairfuse_kernel(
    const float* __restrict__ spb, const ushort_t* __restrict__ Wspob,
    const float* __restrict__ bspo, const float* __restrict__ pairw,
    const float* __restrict__ lng, const float* __restrict__ lnb,
    const ushort_t* __restrict__ Wp1b, const float* __restrict__ bp1,
    const ushort_t* __restrict__ Wp2b, const float* __restrict__ bp2,
    float* __restrict__ pout) {
  __shared__ __align__(16) char smem[65536];
  __shared__ float khs[64];
  char* buf0 = smem;           // X -> pn -> H   (128 x 256B swizzled)
  char* buf1 = smem + 32768;   // Wspo -> ptile -> W1/W2 chunks

  const int tid = threadIdx.x;
  const int l = tid & 63, w = tid >> 6;
  const int wr = w >> 1, wc = w & 1;
  const int lane16 = l & 15, g16 = l >> 4;
  const size_t r0 = (size_t)blockIdx.x * 128;
  const int i_idx = (int)(r0 >> 9), j0 = (int)(r0 & 511);

  const f32x4 fz = {0.f, 0.f, 0.f, 0.f};
  f32x4 acc[4][4];
#pragma unroll
  for (int i = 0; i < 4; ++i)
#pragma unroll
    for (int j = 0; j < 4; ++j) acc[i][j] = fz;

  // ---- stage kh(i) + Wspo ----
  if (tid < 16) *(float4*)(khs + tid * 4) =
      *(const float4*)(spb + (size_t)i_idx * 128 + 64 + tid * 4);
#pragma unroll
  for (int u = 0; u < 8; ++u) {
    const int slot = u * 256 + tid;
    const int row = slot >> 4, sl = slot & 15;
    bf16x8 v = *(const bf16x8*)(Wspob + (size_t)row * 128 + sl * 8);
    *(bf16x8*)(buf1 + SWZ(row, sl * 16)) = v;
  }
  __syncthreads();

  // ---- build X (bf16, swizzled) in buf0 ----
  {
    const int r = tid >> 1, half = tid & 1;
    const float* qrow = spb + (size_t)(j0 + r) * 128;
#pragma unroll
    for (int s8 = 0; s8 < 8; ++s8) {
      const int c = s8 * 8;
      float4 q0 = *(const float4*)(qrow + c);
      float4 q1 = *(const float4*)(qrow + c + 4);
      float4 k0 = *(const float4*)(khs + c);
      float4 k1 = *(const float4*)(khs + c + 4);
      float v0, v1, v2, v3, v4, v5, v6, v7;
      if (half == 0) {
        v0 = q0.x * k0.x; v1 = q0.y * k0.y; v2 = q0.z * k0.z; v3 = q0.w * k0.w;
        v4 = q1.x * k1.x; v5 = q1.y * k1.y; v6 = q1.z * k1.z; v7 = q1.w * k1.w;
      } else {
        v0 = q0.x - k0.x; v1 = q0.y - k0.y; v2 = q0.z - k0.z; v3 = q0.w - k0.w;
        v4 = q1.x - k1.x; v5 = q1.y - k1.y; v6 = q1.z - k1.z; v7 = q1.w - k1.w;
      }
      uint4 wv;
      wv.x = pk2(v0, v1); wv.y = pk2(v2, v3);
      wv.z = pk2(v4, v5); wv.w = pk2(v6, v7);
      *(uint4*)(buf0 + SWZ(r, (half * 8 + s8) * 16)) = wv;
    }
  }
  __syncthreads();

  // ---- GEMM0: acc = X @ Wspo^T ----
#pragma unroll
  for (int kk = 0; kk < 4; ++kk) {
    const int kb = kk * 64 + g16 * 16;
    bf16x8 xf[4], wf[4];
#pragma unroll
    for (int rb = 0; rb < 4; ++rb)
      xf[rb] = *(const bf16x8*)(buf0 + SWZ(wr * 64 + rb * 16 + lane16, kb));
#pragma unroll
    for (int cb = 0; cb < 4; ++cb)
      wf[cb] = *(const bf16x8*)(buf1 + SWZ(wc * 64 + cb * 16 + lane16, kb));
#pragma unroll
    for (int cb = 0; cb < 4; ++cb)
#pragma unroll
      for (int rb = 0; rb < 4; ++rb)
        acc[cb][rb] = __builtin_amdgcn_mfma_f32_16x16x32_bf16(
            wf[cb], xf[rb], acc[cb][rb], 0, 0, 0);
  }
  __syncthreads();

  // ---- P = acc + bspo + pairwise; keep packed bf16; write bf16 to buf1 ----
  uint2 ptk[4][4];
#pragma unroll
  for (int cb = 0; cb < 4; ++cb) {
    const int col0 = wc * 64 + cb * 16 + g16 * 4;
    const float4 bs = *(const float4*)(bspo + col0);
#pragma unroll
    for (int rb = 0; rb < 4; ++rb) {
      const int row = wr * 64 + rb * 16 + lane16;
      const float4 pw = *(const float4*)(pairw + (r0 + row) * 128 + col0);
      f32x4 v = acc[cb][rb];
      const float p0 = v[0] + bs.x + pw.x;
      const float p1 = v[1] + bs.y + pw.y;
      const float p2 = v[2] + bs.z + pw.z;
      const float p3 = v[3] + bs.w + pw.w;
      uint2 pkd; pkd.x = pk2(p0, p1); pkd.y = pk2(p2, p3);
      ptk[cb][rb] = pkd;
      *(uint2*)(buf1 + SWZ(row, col0 * 2)) = pkd;
      acc[cb][rb] = fz;
    }
  }
  __syncthreads();

  // ---- LN(P) -> pn bf16 swizzled in buf0 ----
  {
    const int l32 = tid & 31, rg = tid >> 5;
    const float4 gv = *(const float4*)(lng + l32 * 4);
    const float4 bv = *(const float4*)(lnb + l32 * 4);
#pragma unroll
    for (int it = 0; it < 16; ++it) {
      const int r = it * 8 + rg;
      uint2 d = *(const uint2*)(buf1 + SWZ(r, l32 * 8));
      const float x0 = bfl(d.x), x1 = bfh(d.x), x2 = bfl(d.y), x3 = bfh(d.y);
      float s = x0 + x1 + x2 + x3;
      float s2 = x0 * x0 + x1 * x1 + x2 * x2 + x3 * x3;
#pragma unroll
      for (int off = 1; off < 32; off <<= 1) {
        s += __shfl_xor(s, off, 64);
        s2 += __shfl_xor(s2, off, 64);
      }
      const float mean = s * (1.0f / 128.0f);
      const float rstd = rsqrtf(s2 * (1.0f / 128.0f) - mean * mean + 1e-5f);
      const float n0 = (x0 - mean) * rstd * gv.x + bv.x;
      const float n1 = (x1 - mean) * rstd * gv.y + bv.y;
      const float n2 = (x2 - mean) * rstd * gv.z + bv.z;
      const float n3 = (x3 - mean) * rstd * gv.w + bv.w;
      uint2 pkd; pkd.x = pk2(n0, n1); pkd.y = pk2(n2, n3);
      *(uint2*)(buf0 + SWZ(r, l32 * 8)) = pkd;
    }
  }
  __syncthreads();

  // ---- hoist pn fragments (wave's 64 rows x K=128) ----
  bf16x8 Areg[4][4];
#pragma unroll
  for (int rb = 0; rb < 4; ++rb)
#pragma unroll
    for (int kk = 0; kk < 4; ++kk)
      Areg[rb][kk] = *(const bf16x8*)(
          buf0 + SWZ(wr * 64 + rb * 16 + lane16, kk * 64 + g16 * 16));

  // ---- MLP: 4 chunks of 128 hidden ----
  for (int nc = 0; nc < 4; ++nc) {
    // stage W1 chunk
#pragma unroll
    for (int u = 0; u < 8; ++u) {
      const int slot = u * 256 + tid;
      const int row = slot >> 4, sl = slot & 15;
      bf16x8 v = *(const bf16x8*)(Wp1b + (size_t)(nc * 128 + row) * 128 + sl * 8);
      *(bf16x8*)(buf1 + SWZ(row, sl * 16)) = v;
    }
    __syncthreads();
    // GEMM1: H = pn @ W1c^T (T-layout), relu+bias, write H to buf0
#pragma unroll
    for (int cb = 0; cb < 4; ++cb) {
      f32x4 hacc[4];
#pragma unroll
      for (int rb = 0; rb < 4; ++rb) hacc[rb] = fz;
#pragma unroll
      for (int kk = 0; kk < 4; ++kk) {
        const bf16x8 w1f = *(const bf16x8*)(
            buf1 + SWZ(wc * 64 + cb * 16 + lane16, kk * 64 + g16 * 16));
#pragma unroll
        for (int rb = 0; rb < 4; ++rb)
          hacc[rb] = __builtin_amdgcn_mfma_f32_16x16x32_bf16(
              w1f, Areg[rb][kk], hacc[rb], 0, 0, 0);
      }
      const int hcol = nc * 128 + wc * 64 + cb * 16 + g16 * 4;
      const float4 bi = *(const float4*)(bp1 + hcol);
#pragma unroll
      for (int rb = 0; rb < 4; ++rb) {
        const int row = wr * 64 + rb * 16 + lane16;
        const float h0 = fmaxf(hacc[rb][0] + bi.x, 0.f);
        const float h1 = fmaxf(hacc[rb][1] + bi.y, 0.f);
        const float h2 = fmaxf(hacc[rb][2] + bi.z, 0.f);
        const float h3 = fmaxf(hacc[rb][3] + bi.w, 0.f);
        uint2 pkd; pkd.x = pk2(h0, h1); pkd.y = pk2(h2, h3);
        *(uint2*)(buf0 + SWZ(row, wc * 128 + cb * 32 + g16 * 8)) = pkd;
      }
    }
    __syncthreads();
    // stage W2 chunk
#pragma unroll
    for (int u = 0; u < 8; ++u) {
      const int slot = u * 256 + tid;
      const int row = slot >> 4, sl = slot & 15;
      bf16x8 v = *(const bf16x8*)(Wp2b + (size_t)row * 512 + nc * 128 + sl * 8);
      *(bf16x8*)(buf1 + SWZ(row, sl * 16)) = v;
    }
    __syncthreads();
    // GEMM2: acc += H @ W2c^T (T-layout)
#pragma unroll
    for (int kk = 0; kk < 4; ++kk) {
      const int kb = kk * 64 + g16 * 16;
      bf16x8 hf[4], w2f[4];
#pragma unroll
      for (int rb = 0; rb < 4; ++rb)
        hf[rb] = *(const bf16x8*)(buf0 + SWZ(wr * 64 + rb * 16 + lane16, kb));
#pragma unroll
      for (int cb = 0; cb < 4; ++cb)
        w2f[cb] = *(const bf16x8*)(buf1 + SWZ(wc * 64 + cb * 16 + lane16, kb));
#pragma unroll
      for (int cb = 0; cb < 4; ++cb)
#pragma unroll
        for (int rb = 0; rb < 4; ++rb)
          acc[cb][rb] = __builtin_amdgcn_mfma_f32_16x16x32_bf16(
              w2f[cb], hf[rb], acc[cb][rb], 0, 0, 0);
    }
    __syncthreads();
  }

  // ---- epilogue: p = acc + bp2 + P ----
#pragma unroll
  for (int cb = 0; cb < 4; ++cb) {
    const int col0 = wc * 64 + cb * 16 + g16 * 4;
    const float4 b2 = *(const float4*)(bp2 + col0);
#pragma unroll
    for (int rb = 0; rb < 4; ++rb) {
      const int row = wr * 64 + rb * 16 + lane16;
      const uint2 pkd = ptk[cb][rb];
      float4 o4;
      o4.x = acc[cb][rb][0] + b2.x + bfl(pkd.x);
      o4.y = acc[cb][rb][1] + b2.y + bfh(pkd.x);
      o4.z = acc[cb][rb][2] + b2.z + bfl(pkd.y);
      o4.w = acc[cb][rb][3] + b2.w + bfh(pkd.y);
      *(float4*)(pout + (r0 + row) * 128 + col0) = o4;
    }
  }
}

// ---------------------------------------------------------------------------
extern "C" void kernel_launch(void* const* d_in, const int* in_sizes, int n_in,
                              void* d_out, int out_size, void* d_ws,
                              size_t ws_size, hipStream_t stream) {
  (void)in_sizes; (void)n_in; (void)out_size; (void)ws_size;
  const float* seq      = (const float*)d_in[0];
  const float* pair     = (const float*)d_in[1];
  const float* ln_p2s_g = (const float*)d_in[2];
  const float* ln_p2s_b = (const float*)d_in[3];
  const float* W_p2s    = (const float*)d_in[4];
  const float* ln1_g    = (const float*)d_in[5];
  const float* ln1_b    = (const float*)d_in[6];
  const float* Wqkv     = (const float*)d_in[7];
  const float* Wo       = (const float*)d_in[8];
  const float* bo       = (const float*)d_in[9];
  const float* Wg       = (const float*)d_in[10];
  const float* bg       = (const float*)d_in[11];
  const float* ln_s_g   = (const float*)d_in[12];
  const float* ln_s_b   = (const float*)d_in[13];
  const float* Wm1      = (const float*)d_in[14];
  const float* bm1      = (const float*)d_in[15];
  const float* Wm2      = (const float*)d_in[16];
  const float* bm2      = (const float*)d_in[17];
  const float* ln_sp_g  = (const float*)d_in[18];
  const float* ln_sp_b  = (const float*)d_in[19];
  const float* Wsp      = (const float*)d_in[20];
  const float* bsp      = (const float*)d_in[21];
  const float* Wspo     = (const float*)d_in[22];
  const float* bspo     = (const float*)d_in[23];
  const float* ln_mp_g  = (const float*)d_in[24];
  const float* ln_mp_b  = (const float*)d_in[25];
  const float* Wp1      = (const float*)d_in[26];
  const float* bp1      = (const float*)d_in[27];
  const float* Wp2      = (const float*)d_in[28];
  const float* bp2      = (const float*)d_in[29];

  float* out_s = (float*)d_out;            // 512*1024
  float* out_p = out_s + 512 * 1024;       // 512*512*128

  // ---- workspace layout (floats) ----
  float* ws = (float*)d_ws;
  ushort_t* y_b  = (ushort_t*)ws;                    // 524288 bf16 -> 262144 fl
  float* t   = ws + 262144;                          // 1572864
  float* g   = t + 1572864;                          // 524288
  float* o   = g + 524288;                           // 524288
  float* s1  = o + 524288;                           // 524288
  ushort_t* ob  = (ushort_t*)(s1 + 524288);          // 524288 bf16 -> 262144
  ushort_t* h1b = (ushort_t*)(s1 + 524288 + 262144); // 2097152 bf16 -> 1048576
  float* spb = s1 + 524288 + 262144 + 1048576;       // 65536
  ushort_t* wspo_b = (ushort_t*)(spb + 65536);       // 16384 bf16 -> 8192
  ushort_t* wp1_b  = (ushort_t*)(spb + 65536 + 8192);    // 65536 bf16 -> 32768
  ushort_t* wp2_b  = (ushort_t*)(spb + 65536 + 40960);   // 65536 bf16 -> 32768

  // ---- d_out p-section scratch (overwritten only by final pairfuse) ----
  float* biasT = out_p;                    // 8388608 fl
  float* S     = out_p + 8388608;          // 8388608 fl
  ushort_t* wq_b  = (ushort_t*)(out_p + 16777216);   // 3145728 bf16
  ushort_t* wg_b  = wq_b + 3145728;
  ushort_t* wo_b  = wg_b + 1048576;
  ushort_t* wm1_b = wo_b + 1048576;
  ushort_t* wm2_b = wm1_b + 4194304;
  ushort_t* wsp_b = wm2_b + 4194304;       // 131072

  // 0. weight conversions (one fused kernel)
  cvt9_kernel<<<6792, 256, 0, stream>>>(Wqkv, wq_b, Wg, wg_b, Wo, wo_b,
                                        Wm1, wm1_b, Wm2, wm2_b, Wsp, wsp_b,
                                        Wspo, wspo_b, Wp1, wp1_b, Wp2, wp2_b);
  // 1. y = LN(seq) (bf16)
  ln1024b_kernel<<<512, 256, 0, stream>>>(seq, ln1_g, ln1_b, y_b);
  // 2. qkv = y @ Wqkv^T
  gemm_mfma_kernel<0, 0, 0, 0><<<dim3(24, 8), 256, 0, stream>>>(
      y_b, wq_b, nullptr, nullptr, t, nullptr, 512, 3072, 1024);
  // 3. gate logits
  gemm_mfma_kernel<1, 0, 0, 0><<<dim3(8, 8), 256, 0, stream>>>(
      y_b, wg_b, bg, nullptr, g, nullptr, 512, 1024, 1024);
  // 4. pairwise bias
  p2s_bias_kernel<<<4096, 256, 0, stream>>>(pair, ln_p2s_g, ln_p2s_b, W_p2s, biasT);
  // 5-7. scores, softmax, PV
  scores_kernel<<<dim3(8, 8, 32), 256, 0, stream>>>(t, biasT, S);
  softmax_kernel<<<16384, 256, 0, stream>>>(S);
  pv_kernel<<<dim3(32, 8), 256, 0, stream>>>(S, t, o);
  // 8. gate -> bf16
  gate_b_kernel<<<512, 256, 0, stream>>>(o, g, ob);
  // 9. s1 = seq + o @ Wo^T + bo
  gemm_mfma_kernel<1, 0, 1, 0><<<dim3(8, 8), 256, 0, stream>>>(
      ob, wo_b, bo, seq, s1, nullptr, 512, 1024, 1024);
  // 10. y = LN(s1)
  ln1024b_kernel<<<512, 256, 0, stream>>>(s1, ln_s_g, ln_s_b, y_b);
  // 11. h1 = relu(y @ Wm1^T + bm1) (bf16 out)
  gemm_mfma_kernel<1, 1, 0, 1><<<dim3(32, 8), 256, 0, stream>>>(
      y_b, wm1_b, bm1, nullptr, nullptr, h1b, 512, 4096, 1024);
  // 12. s2 = s1 + h1 @ Wm2^T + bm2 -> out_s
  gemm_mfma_kernel<1, 0, 1, 0><<<dim3(8, 8), 256, 0, stream>>>(
      h1b, wm2_b, bm2, s1, out_s, nullptr, 512, 1024, 4096);
  // 13. y = LN(s2)
  ln1024b_kernel<<<512, 256, 0, stream>>>(out_s, ln_sp_g, ln_sp_b, y_b);
  // 14. sp = y @ Wsp^T + bsp
  gemm_mfma_kernel<1, 0, 0, 0><<<dim3(1, 8), 256, 0, stream>>>(
      y_b, wsp_b, bsp, nullptr, spb, nullptr, 512, 128, 1024);
  // 15. fused SequenceToPair + pair MLP -> out_p
  pairfuse_kernel<<<2048, 256, 0, stream>>>(spb, wspo_b, bspo, pair,
                                            ln_mp_g, ln_mp_b, wp1_b, bp1,
                                            wp2_b, bp2, out_p);
}

// Round 6
// 594.849 us; speedup vs baseline: 6.5949x; 1.1978x over previous
//
#include <hip/hip_runtime.h>
#include <hip/hip_bf16.h>
#include <cstddef>

// ---------------------------------------------------------------------------
// TriangularSelfAttentionBlock R4: full MFMA + fused flash attention
// L=512, SEQ_D=1024, PAIR_D=128, H=32, HW=32, INNER=64
// ---------------------------------------------------------------------------

#define L 512
#define SEQ_D 1024
#define PAIR_D 128
#define NH 32
#define HW 32

typedef short bf16x8 __attribute__((ext_vector_type(8)));
typedef float f32x4 __attribute__((ext_vector_type(4)));
typedef unsigned short ushort_t;

__device__ inline float wred_sum(float v) {
#pragma unroll
  for (int off = 32; off; off >>= 1) v += __shfl_xor(v, off, 64);
  return v;
}
// f32 -> bf16 (RNE), packed pair (a low, b high)
__device__ inline unsigned pk2(float a, float b) {
  unsigned ua = __float_as_uint(a), ub = __float_as_uint(b);
  ua = (ua + 0x7fffu + ((ua >> 16) & 1u)) >> 16;
  ub = (ub + 0x7fffu + ((ub >> 16) & 1u)) >> 16;
  return ua | (ub << 16);
}
__device__ inline float bfl(unsigned u) { return __uint_as_float(u << 16); }
__device__ inline float bfh(unsigned u) { return __uint_as_float(u & 0xffff0000u); }

// swizzled byte offset for [row][256B] LDS tiles
#define SWZ(row, kb) ((((row)) << 8) + ((kb) ^ (((row)&7) << 4)))
// swizzled byte offset for [row][128B] LDS tiles
#define SWZ64(row, kb) ((((row)) << 7) + ((kb) ^ (((row)&7) << 4)))
// swizzled byte offset for [row][512B] LDS tiles (f32 out tile)
#define SWZP(row, cb) ((((row)) << 9) + ((cb) ^ (((row)&7) << 4)))

// ---------------- fused f32->bf16 weight conversion (9 tensors) ------------
__global__ __launch_bounds__(256) void cvt9_kernel(
    const float* __restrict__ s0, ushort_t* __restrict__ d0,
    const float* __restrict__ s1, ushort_t* __restrict__ d1,
    const float* __restrict__ s2, ushort_t* __restrict__ d2,
    const float* __restrict__ s3, ushort_t* __restrict__ d3,
    const float* __restrict__ s4, ushort_t* __restrict__ d4,
    const float* __restrict__ s5, ushort_t* __restrict__ d5,
    const float* __restrict__ s6, ushort_t* __restrict__ d6,
    const float* __restrict__ s7, ushort_t* __restrict__ d7,
    const float* __restrict__ s8, ushort_t* __restrict__ d8) {
  const int b = blockIdx.x;
  const float* s; ushort_t* d; int base;
  if (b < 1536)      { s = s0; d = d0; base = b; }
  else if (b < 2048) { s = s1; d = d1; base = b - 1536; }
  else if (b < 2560) { s = s2; d = d2; base = b - 2048; }
  else if (b < 4608) { s = s3; d = d3; base = b - 2560; }
  else if (b < 6656) { s = s4; d = d4; base = b - 4608; }
  else if (b < 6720) { s = s5; d = d5; base = b - 6656; }
  else if (b < 6728) { s = s6; d = d6; base = b - 6720; }
  else if (b < 6760) { s = s7; d = d7; base = b - 6728; }
  else               { s = s8; d = d8; base = b - 6760; }
  const int i = base * 256 + threadIdx.x;
  float4 a = ((const float4*)s)[2 * i], c = ((const float4*)s)[2 * i + 1];
  uint4 w;
  w.x = pk2(a.x, a.y); w.y = pk2(a.z, a.w);
  w.z = pk2(c.x, c.y); w.w = pk2(c.z, c.w);
  ((uint4*)d)[i] = w;
}

// ---------------- LayerNorm 1024 -> bf16 out -------------------------------
__global__ __launch_bounds__(256) void ln1024b_kernel(
    const float* __restrict__ in, const float* __restrict__ g,
    const float* __restrict__ b, ushort_t* __restrict__ out) {
  const int row = blockIdx.x;
  const int tid = threadIdx.x;
  float4 v = ((const float4*)(in + (size_t)row * SEQ_D))[tid];
  float s = v.x + v.y + v.z + v.w;
  float s2 = v.x * v.x + v.y * v.y + v.z * v.z + v.w * v.w;
  __shared__ float red[8];
  const int lane = tid & 63, wid = tid >> 6;
  s = wred_sum(s);
  s2 = wred_sum(s2);
  if (lane == 0) { red[wid] = s; red[4 + wid] = s2; }
  __syncthreads();
  s = red[0] + red[1] + red[2] + red[3];
  s2 = red[4] + red[5] + red[6] + red[7];
  const float mean = s * (1.0f / SEQ_D);
  const float var = s2 * (1.0f / SEQ_D) - mean * mean;
  const float rstd = rsqrtf(var + 1e-5f);
  float4 gv = ((const float4*)g)[tid];
  float4 bv = ((const float4*)b)[tid];
  const float o0 = (v.x - mean) * rstd * gv.x + bv.x;
  const float o1 = (v.y - mean) * rstd * gv.y + bv.y;
  const float o2 = (v.z - mean) * rstd * gv.z + bv.z;
  const float o3 = (v.w - mean) * rstd * gv.w + bv.w;
  uint2 pkd; pkd.x = pk2(o0, o1); pkd.y = pk2(o2, o3);
  ((uint2*)(out + (size_t)row * SEQ_D))[tid] = pkd;
}

// ---------------- MFMA GEMM: C[M][N] = A[M][K](bf16) @ B[N][K]^T(bf16) -----
template <int BIAS, int RELU, int RES, int OBF16>
__global__ __launch_bounds__(256, 2) void gemm_mfma_kernel(
    const ushort_t* __restrict__ A, const ushort_t* __restrict__ B,
    const float* __restrict__ bias, const float* __restrict__ res,
    float* __restrict__ C, ushort_t* __restrict__ Cb, int M, int N, int K) {
  __shared__ __align__(16) char smem[24576];
  char* Ab = smem;
  char* Bb = smem + 8192;
  const int tid = threadIdx.x;
  const int l = tid & 63, w = tid >> 6;
  const int wr = w >> 1, wc = w & 1;
  const int lane16 = l & 15, g16 = l >> 4;
  const int bm = blockIdx.y * 64, bn = blockIdx.x * 128;
  const f32x4 fz = {0.f, 0.f, 0.f, 0.f};
  f32x4 acc[4][2];
#pragma unroll
  for (int i = 0; i < 4; ++i)
#pragma unroll
    for (int j = 0; j < 2; ++j) acc[i][j] = fz;

  for (int k0 = 0; k0 < K; k0 += 64) {
    __syncthreads();
#pragma unroll
    for (int u = 0; u < 2; ++u) {
      const int slot = u * 256 + tid;
      const int row = slot >> 3, sl = slot & 7;
      bf16x8 v = *(const bf16x8*)(A + (size_t)(bm + row) * K + k0 + sl * 8);
      *(bf16x8*)(Ab + SWZ64(row, sl * 16)) = v;
    }
#pragma unroll
    for (int u = 0; u < 4; ++u) {
      const int slot = u * 256 + tid;
      const int row = slot >> 3, sl = slot & 7;
      bf16x8 v = *(const bf16x8*)(B + (size_t)(bn + row) * K + k0 + sl * 8);
      *(bf16x8*)(Bb + SWZ64(row, sl * 16)) = v;
    }
    __syncthreads();
#pragma unroll
    for (int kk = 0; kk < 2; ++kk) {
      const int kb = kk * 64 + g16 * 16;
      bf16x8 af[2], bf[4];
#pragma unroll
      for (int rb = 0; rb < 2; ++rb) {
        const int row = wr * 32 + rb * 16 + lane16;
        af[rb] = *(const bf16x8*)(Ab + SWZ64(row, kb));
      }
#pragma unroll
      for (int cb = 0; cb < 4; ++cb) {
        const int row = wc * 64 + cb * 16 + lane16;
        bf[cb] = *(const bf16x8*)(Bb + SWZ64(row, kb));
      }
#pragma unroll
      for (int cb = 0; cb < 4; ++cb)
#pragma unroll
        for (int rb = 0; rb < 2; ++rb)
          acc[cb][rb] = __builtin_amdgcn_mfma_f32_16x16x32_bf16(
              bf[cb], af[rb], acc[cb][rb], 0, 0, 0);
    }
  }
#pragma unroll
  for (int cb = 0; cb < 4; ++cb) {
    const int col0 = bn + wc * 64 + cb * 16 + g16 * 4;
    float4 bi = make_float4(0.f, 0.f, 0.f, 0.f);
    if (BIAS) bi = *(const float4*)(bias + col0);
#pragma unroll
    for (int rb = 0; rb < 2; ++rb) {
      const int row = bm + wr * 32 + rb * 16 + lane16;
      f32x4 v = acc[cb][rb];
      v[0] += bi.x; v[1] += bi.y; v[2] += bi.z; v[3] += bi.w;
      if (RELU) {
        v[0] = fmaxf(v[0], 0.f); v[1] = fmaxf(v[1], 0.f);
        v[2] = fmaxf(v[2], 0.f); v[3] = fmaxf(v[3], 0.f);
      }
      if (RES) {
        const float4 r4 = *(const float4*)(res + (size_t)row * N + col0);
        v[0] += r4.x; v[1] += r4.y; v[2] += r4.z; v[3] += r4.w;
      }
      if (OBF16) {
        uint2 pkd; pkd.x = pk2(v[0], v[1]); pkd.y = pk2(v[2], v[3]);
        *(uint2*)(Cb + (size_t)row * N + col0) = pkd;
      } else {
        float4 o4; o4.x = v[0]; o4.y = v[1]; o4.z = v[2]; o4.w = v[3];
        *(float4*)(C + (size_t)row * N + col0) = o4;
      }
    }
  }
}

// ---------------- PairToSequence via MFMA ----------------------------------
// biasT[h][i][j] = LN(pair[i,j]) . W[h]; 128 pair-rows per block, 4 waves.
__global__ __launch_bounds__(256) void p2s_mfma_kernel(
    const float* __restrict__ pair, const float* __restrict__ g,
    const float* __restrict__ b, const float* __restrict__ W,
    float* __restrict__ biasT) {
  __shared__ __align__(16) char pnb[32768];  // 128 rows x 256B swizzled
  __shared__ __align__(16) char wls[8192];   // 32 rows x 256B swizzled
  const int tid = threadIdx.x;
  const int l = tid & 63, w = tid >> 6;
  const int lane16 = l & 15, g16 = l >> 4;
  const size_t r0 = (size_t)blockIdx.x * 128;
  const int i_idx = (int)(r0 >> 9), j0 = (int)(r0 & 511);
  // stage W (32x128 f32 -> bf16 swizzled)
#pragma unroll
  for (int u = 0; u < 2; ++u) {
    const int slot = u * 256 + tid;
    const int row = slot >> 4, sl = slot & 15;
    const float4 v0 = *(const float4*)(W + (size_t)row * 128 + sl * 8);
    const float4 v1 = *(const float4*)(W + (size_t)row * 128 + sl * 8 + 4);
    uint4 wv; wv.x = pk2(v0.x, v0.y); wv.y = pk2(v0.z, v0.w);
    wv.z = pk2(v1.x, v1.y); wv.w = pk2(v1.z, v1.w);
    *(uint4*)(wls + SWZ(row, sl * 16)) = wv;
  }
  // LN rows -> pn bf16 swizzled
  {
    const int l32 = tid & 31, rg = tid >> 5;
    const float4 gv = *(const float4*)(g + l32 * 4);
    const float4 bv = *(const float4*)(b + l32 * 4);
#pragma unroll
    for (int it = 0; it < 16; ++it) {
      const int r = it * 8 + rg;
      const float4 v = *(const float4*)(pair + (r0 + r) * 128 + l32 * 4);
      float s = v.x + v.y + v.z + v.w;
      float s2 = v.x * v.x + v.y * v.y + v.z * v.z + v.w * v.w;
#pragma unroll
      for (int off = 1; off < 32; off <<= 1) {
        s += __shfl_xor(s, off, 64);
        s2 += __shfl_xor(s2, off, 64);
      }
      const float mean = s * (1.0f / 128.0f);
      const float rstd = rsqrtf(s2 * (1.0f / 128.0f) - mean * mean + 1e-5f);
      const float n0 = (v.x - mean) * rstd * gv.x + bv.x;
      const float n1 = (v.y - mean) * rstd * gv.y + bv.y;
      const float n2 = (v.z - mean) * rstd * gv.z + bv.z;
      const float n3 = (v.w - mean) * rstd * gv.w + bv.w;
      uint2 pkd; pkd.x = pk2(n0, n1); pkd.y = pk2(n2, n3);
      *(uint2*)(pnb + SWZ(r, l32 * 8)) = pkd;
    }
  }
  __syncthreads();
  const f32x4 fz = {0.f, 0.f, 0.f, 0.f};
  f32x4 a2[2][2];
#pragma unroll
  for (int i = 0; i < 2; ++i)
#pragma unroll
    for (int j = 0; j < 2; ++j) a2[i][j] = fz;
#pragma unroll
  for (int kk = 0; kk < 4; ++kk) {
    bf16x8 wf[2], pf[2];
#pragma unroll
    for (int hb = 0; hb < 2; ++hb)
      wf[hb] = *(const bf16x8*)(wls + SWZ(hb * 16 + lane16, kk * 64 + g16 * 16));
#pragma unroll
    for (int rb = 0; rb < 2; ++rb)
      pf[rb] = *(const bf16x8*)(pnb + SWZ(w * 32 + rb * 16 + lane16, kk * 64 + g16 * 16));
#pragma unroll
    for (int hb = 0; hb < 2; ++hb)
#pragma unroll
      for (int rb = 0; rb < 2; ++rb)
        a2[hb][rb] = __builtin_amdgcn_mfma_f32_16x16x32_bf16(
            wf[hb], pf[rb], a2[hb][rb], 0, 0, 0);
  }
#pragma unroll
  for (int hb = 0; hb < 2; ++hb)
#pragma unroll
    for (int rb = 0; rb < 2; ++rb) {
      const int j = j0 + w * 32 + rb * 16 + lane16;
#pragma unroll
      for (int qq = 0; qq < 4; ++qq) {
        const int hh = hb * 16 + g16 * 4 + qq;
        biasT[((size_t)hh * 512 + i_idx) * 512 + j] = a2[hb][rb][qq];
      }
    }
}

// ---------------- fused attention: softmax(scale*QK^T + bias) @ V ----------
// grid (8 q-tiles, 32 heads), 4 waves x 16 q-rows. Online softmax, MFMA.
__global__ __launch_bounds__(256) void attn_kernel(
    const ushort_t* __restrict__ tb, const float* __restrict__ biasT,
    float* __restrict__ o) {
  __shared__ __align__(16) ushort_t Vt[32][80];  // V^T tile, padded
  const int tid = threadIdx.x;
  const int l = tid & 63, wq = tid >> 6;
  const int lane16 = l & 15, g16 = l >> 4;
  const int h = blockIdx.y;
  const int q = blockIdx.x * 64 + wq * 16 + lane16;
  const float scale = 0.17677669529663689f;
  const bf16x8 qf = *(const bf16x8*)(tb + (size_t)q * 3072 + h * 96 + g16 * 8);
  const float* brow = biasT + ((size_t)h * 512 + q) * 512;
  float m = -3e38f, lsum = 0.f;
  const f32x4 fz = {0.f, 0.f, 0.f, 0.f};
  f32x4 accp[2] = {fz, fz};
  for (int kt = 0; kt < 512; kt += 64) {
    // stage V^T
    {
      const int kr = tid >> 2, cc = tid & 3;
      bf16x8 vv = *(const bf16x8*)(tb + (size_t)(kt + kr) * 3072 + h * 96 + 64 + cc * 8);
#pragma unroll
      for (int u = 0; u < 8; ++u) Vt[cc * 8 + u][kr] = (ushort_t)vv[u];
    }
    __syncthreads();
    // S = scale*QK^T + bias  (lane holds S[k=kb*16+g16*4+qq][q=lane16])
    f32x4 st[4];
#pragma unroll
    for (int kb = 0; kb < 4; ++kb) {
      const bf16x8 kf = *(const bf16x8*)(
          tb + (size_t)(kt + kb * 16 + lane16) * 3072 + h * 96 + 32 + g16 * 8);
      st[kb] = __builtin_amdgcn_mfma_f32_16x16x32_bf16(kf, qf, fz, 0, 0, 0);
      const float4 bv = *(const float4*)(brow + kt + kb * 16 + g16 * 4);
      st[kb][0] = st[kb][0] * scale + bv.x;
      st[kb][1] = st[kb][1] * scale + bv.y;
      st[kb][2] = st[kb][2] * scale + bv.z;
      st[kb][3] = st[kb][3] * scale + bv.w;
    }
    // online softmax (per q-row: reduce over the k direction = g16 groups)
    float tm = st[0][0];
#pragma unroll
    for (int kb = 0; kb < 4; ++kb)
#pragma unroll
      for (int qq = 0; qq < 4; ++qq) tm = fmaxf(tm, st[kb][qq]);
    tm = fmaxf(tm, __shfl_xor(tm, 16, 64));
    tm = fmaxf(tm, __shfl_xor(tm, 32, 64));
    const float mn = fmaxf(m, tm);
    const float corr = __expf(m - mn);
    m = mn;
    lsum *= corr;
#pragma unroll
    for (int ct = 0; ct < 2; ++ct) {
      accp[ct][0] *= corr; accp[ct][1] *= corr;
      accp[ct][2] *= corr; accp[ct][3] *= corr;
    }
#pragma unroll
    for (int kb = 0; kb < 4; ++kb)
#pragma unroll
      for (int qq = 0; qq < 4; ++qq) {
        const float e = __expf(st[kb][qq] - mn);
        st[kb][qq] = e;
        lsum += e;
      }
    // redistribute P to B-operand layout (lane: P[q=lane16][k=kk*32+g16*8+j])
    const int src0 = lane16 + ((l & 16) << 1);
    const int src1 = src0 + 16;
    const bool hi = (l & 32) != 0;
#pragma unroll
    for (int kk = 0; kk < 2; ++kk) {
      float lo4[4], hi4[4];
#pragma unroll
      for (int qq = 0; qq < 4; ++qq) {
        const float a0 = __shfl(st[kk * 2][qq], src0, 64);
        const float a1 = __shfl(st[kk * 2][qq], src1, 64);
        const float b0 = __shfl(st[kk * 2 + 1][qq], src0, 64);
        const float b1 = __shfl(st[kk * 2 + 1][qq], src1, 64);
        lo4[qq] = hi ? b0 : a0;
        hi4[qq] = hi ? b1 : a1;
      }
      uint4 pu;
      pu.x = pk2(lo4[0], lo4[1]); pu.y = pk2(lo4[2], lo4[3]);
      pu.z = pk2(hi4[0], hi4[1]); pu.w = pk2(hi4[2], hi4[3]);
      bf16x8 pf;
      __builtin_memcpy(&pf, &pu, 16);
#pragma unroll
      for (int ct = 0; ct < 2; ++ct) {
        const bf16x8 vf = *(const bf16x8*)&Vt[ct * 16 + lane16][kk * 32 + g16 * 8];
        accp[ct] = __builtin_amdgcn_mfma_f32_16x16x32_bf16(vf, pf, accp[ct], 0, 0, 0);
      }
    }
    __syncthreads();
  }
  lsum += __shfl_xor(lsum, 16, 64);
  lsum += __shfl_xor(lsum, 32, 64);
  const float inv = 1.0f / lsum;
#pragma unroll
  for (int ct = 0; ct < 2; ++ct) {
    float4 o4;
    o4.x = accp[ct][0] * inv; o4.y = accp[ct][1] * inv;
    o4.z = accp[ct][2] * inv; o4.w = accp[ct][3] * inv;
    *(float4*)(o + (size_t)q * SEQ_D + h * 32 + ct * 16 + g16 * 4) = o4;
  }
}

// ---------------- gate: ob = bf16(o * sigmoid(g)) --------------------------
__global__ __launch_bounds__(256) void gate_b_kernel(
    const float* __restrict__ o, const float* __restrict__ g,
    ushort_t* __restrict__ ob) {
  const int i = blockIdx.x * 256 + threadIdx.x;
  float4 ov = ((const float4*)o)[i];
  float4 gv = ((const float4*)g)[i];
  ov.x *= 1.0f / (1.0f + __expf(-gv.x));
  ov.y *= 1.0f / (1.0f + __expf(-gv.y));
  ov.z *= 1.0f / (1.0f + __expf(-gv.z));
  ov.w *= 1.0f / (1.0f + __expf(-gv.w));
  uint2 pkd; pkd.x = pk2(ov.x, ov.y); pkd.y = pk2(ov.z, ov.w);
  ((uint2*)ob)[i] = pkd;
}

// ---------------- fused SequenceToPair + pair MLP (v2) ---------------------
__global__ __launch_bounds__(256, 2) void pairfuse_kernel(
    const float* __restrict__ spb, const ushort_t* __restrict__ Wspob,
    const float* __restrict__ bspo, const float* __restrict__ pairw,
    const float* __restrict__ lng, const float* __restrict__ lnb,
    const ushort_t* __restrict__ Wp1b, const float* __restrict__ bp1,
    const ushort_t* __restrict__ Wp2b, const float* __restrict__ bp2,
    float* __restrict__ pout) {
  __shared__ __align__(16) char smem[65536];
  char* buf0 = smem;           // pair tile -> pn -> H
  char* buf1 = smem + 32768;   // Wspo -> P tile -> W1/W2 chunks
  const int tid = threadIdx.x;
  const int l = tid & 63, w = tid >> 6;
  const int wr = w >> 1, wc = w & 1;
  const int lane16 = l & 15, g16 = l >> 4;
  const size_t r0 = (size_t)blockIdx.x * 128;
  const int i_idx = (int)(r0 >> 9), j0 = (int)(r0 & 511);

  // ---- stage Wspo -> buf1 ; pair tile (bf16) -> buf0 (coalesced) ----
#pragma unroll
  for (int u = 0; u < 8; ++u) {
    const int slot = u * 256 + tid;
    const int row = slot >> 4, sl = slot & 15;
    bf16x8 v = *(const bf16x8*)(Wspob + (size_t)row * 128 + sl * 8);
    *(bf16x8*)(buf1 + SWZ(row, sl * 16)) = v;
  }
#pragma unroll
  for (int u = 0; u < 8; ++u) {
    const int slot = u * 256 + tid;
    const int row = slot >> 4, sl = slot & 15;
    const float4 v0 = *(const float4*)(pairw + (r0 + row) * 128 + sl * 8);
    const float4 v1 = *(const float4*)(pairw + (r0 + row) * 128 + sl * 8 + 4);
    uint4 pv; pv.x = pk2(v0.x, v0.y); pv.y = pk2(v0.z, v0.w);
    pv.z = pk2(v1.x, v1.y); pv.w = pk2(v1.z, v1.w);
    *(uint4*)(buf0 + SWZ(row, sl * 16)) = pv;
  }

  // ---- build X fragments in registers ----
  // X[r][c<64] = qh[j0+r][c]*kh[i][c] ; X[r][c>=64] = qh - kh
  bf16x8 xf[4][4];
  {
    const float* khp = spb + (size_t)i_idx * 128 + 64;
    const float4 kha0 = *(const float4*)(khp + g16 * 8);
    const float4 kha1 = *(const float4*)(khp + g16 * 8 + 4);
    const float4 khb0 = *(const float4*)(khp + 32 + g16 * 8);
    const float4 khb1 = *(const float4*)(khp + 32 + g16 * 8 + 4);
#pragma unroll
    for (int rb = 0; rb < 4; ++rb) {
      const float* qp = spb + (size_t)(j0 + wr * 64 + rb * 16 + lane16) * 128;
      const float4 qa0 = *(const float4*)(qp + g16 * 8);
      const float4 qa1 = *(const float4*)(qp + g16 * 8 + 4);
      const float4 qb0 = *(const float4*)(qp + 32 + g16 * 8);
      const float4 qb1 = *(const float4*)(qp + 32 + g16 * 8 + 4);
      uint4 u;
      u.x = pk2(qa0.x * kha0.x, qa0.y * kha0.y);
      u.y = pk2(qa0.z * kha0.z, qa0.w * kha0.w);
      u.z = pk2(qa1.x * kha1.x, qa1.y * kha1.y);
      u.w = pk2(qa1.z * kha1.z, qa1.w * kha1.w);
      __builtin_memcpy(&xf[rb][0], &u, 16);
      u.x = pk2(qb0.x * khb0.x, qb0.y * khb0.y);
      u.y = pk2(qb0.z * khb0.z, qb0.w * khb0.w);
      u.z = pk2(qb1.x * khb1.x, qb1.y * khb1.y);
      u.w = pk2(qb1.z * khb1.z, qb1.w * khb1.w);
      __builtin_memcpy(&xf[rb][1], &u, 16);
      u.x = pk2(qa0.x - kha0.x, qa0.y - kha0.y);
      u.y = pk2(qa0.z - kha0.z, qa0.w - kha0.w);
      u.z = pk2(qa1.x - kha1.x, qa1.y - kha1.y);
      u.w = pk2(qa1.z - kha1.z, qa1.w - kha1.w);
      __builtin_memcpy(&xf[rb][2], &u, 16);
      u.x = pk2(qb0.x - khb0.x, qb0.y - khb0.y);
      u.y = pk2(qb0.z - khb0.z, qb0.w - khb0.w);
      u.z = pk2(qb1.x - khb1.x, qb1.y - khb1.y);
      u.w = pk2(qb1.z - khb1.z, qb1.w - khb1.w);
      __builtin_memcpy(&xf[rb][3], &u, 16);
    }
  }
  __syncthreads();

  const f32x4 fz = {0.f, 0.f, 0.f, 0.f};
  f32x4 acc[4][4];
#pragma unroll
  for (int i = 0; i < 4; ++i)
#pragma unroll
    for (int j = 0; j < 4; ++j) acc[i][j] = fz;

  // ---- GEMM0: acc = X @ Wspo^T ----
#pragma unroll
  for (int kk = 0; kk < 4; ++kk) {
    const int kb = kk * 64 + g16 * 16;
    bf16x8 wf[4];
#pragma unroll
    for (int cb = 0; cb < 4; ++cb)
      wf[cb] = *(const bf16x8*)(buf1 + SWZ(wc * 64 + cb * 16 + lane16, kb));
#pragma unroll
    for (int cb = 0; cb < 4; ++cb)
#pragma unroll
      for (int rb = 0; rb < 4; ++rb)
        acc[cb][rb] = __builtin_amdgcn_mfma_f32_16x16x32_bf16(
            wf[cb], xf[rb][kk], acc[cb][rb], 0, 0, 0);
  }
  __syncthreads();

  // ---- P = acc + bspo + pair(bf16 from buf0); P bf16 -> buf1; keep ptk ----
  uint2 ptk[4][4];
#pragma unroll
  for (int cb = 0; cb < 4; ++cb) {
    const int col0 = wc * 64 + cb * 16 + g16 * 4;
    const float4 bs = *(const float4*)(bspo + col0);
#pragma unroll
    for (int rb = 0; rb < 4; ++rb) {
      const int row = wr * 64 + rb * 16 + lane16;
      const uint2 pw2 = *(const uint2*)(buf0 + SWZ(row, col0 * 2));
      const float p0 = acc[cb][rb][0] + bs.x + bfl(pw2.x);
      const float p1 = acc[cb][rb][1] + bs.y + bfh(pw2.x);
      const float p2 = acc[cb][rb][2] + bs.z + bfl(pw2.y);
      const float p3 = acc[cb][rb][3] + bs.w + bfh(pw2.y);
      uint2 pkd; pkd.x = pk2(p0, p1); pkd.y = pk2(p2, p3);
      ptk[cb][rb] = pkd;
      *(uint2*)(buf1 + SWZ(row, col0 * 2)) = pkd;
      acc[cb][rb] = fz;
    }
  }
  __syncthreads();

  // ---- LN(P) -> pn bf16 in buf0 ----
  {
    const int l32 = tid & 31, rg = tid >> 5;
    const float4 gv = *(const float4*)(lng + l32 * 4);
    const float4 bv = *(const float4*)(lnb + l32 * 4);
#pragma unroll
    for (int it = 0; it < 16; ++it) {
      const int r = it * 8 + rg;
      uint2 d = *(const uint2*)(buf1 + SWZ(r, l32 * 8));
      const float x0 = bfl(d.x), x1 = bfh(d.x), x2 = bfl(d.y), x3 = bfh(d.y);
      float s = x0 + x1 + x2 + x3;
      float s2 = x0 * x0 + x1 * x1 + x2 * x2 + x3 * x3;
#pragma unroll
      for (int off = 1; off < 32; off <<= 1) {
        s += __shfl_xor(s, off, 64);
        s2 += __shfl_xor(s2, off, 64);
      }
      const float mean = s * (1.0f / 128.0f);
      const float rstd = rsqrtf(s2 * (1.0f / 128.0f) - mean * mean + 1e-5f);
      const float n0 = (x0 - mean) * rstd * gv.x + bv.x;
      const float n1 = (x1 - mean) * rstd * gv.y + bv.y;
      const float n2 = (x2 - mean) * rstd * gv.z + bv.z;
      const float n3 = (x3 - mean) * rstd * gv.w + bv.w;
      uint2 pkd; pkd.x = pk2(n0, n1); pkd.y = pk2(n2, n3);
      *(uint2*)(buf0 + SWZ(r, l32 * 8)) = pkd;
    }
  }
  __syncthreads();

  // ---- hoist pn fragments ----
  bf16x8 Areg[4][4];
#pragma unroll
  for (int rb = 0; rb < 4; ++rb)
#pragma unroll
    for (int kk = 0; kk < 4; ++kk)
      Areg[rb][kk] = *(const bf16x8*)(
          buf0 + SWZ(wr * 64 + rb * 16 + lane16, kk * 64 + g16 * 16));

  // ---- MLP: 4 chunks of 128 hidden ----
  for (int nc = 0; nc < 4; ++nc) {
#pragma unroll
    for (int u = 0; u < 8; ++u) {
      const int slot = u * 256 + tid;
      const int row = slot >> 4, sl = slot & 15;
      bf16x8 v = *(const bf16x8*)(Wp1b + (size_t)(nc * 128 + row) * 128 + sl * 8);
      *(bf16x8*)(buf1 + SWZ(row, sl * 16)) = v;
    }
    __syncthreads();
#pragma unroll
    for (int cb = 0; cb < 4; ++cb) {
      f32x4 hacc[4];
#pragma unroll
      for (int rb = 0; rb < 4; ++rb) hacc[rb] = fz;
#pragma unroll
      for (int kk = 0; kk < 4; ++kk) {
        const bf16x8 w1f = *(const bf16x8*)(
            buf1 + SWZ(wc * 64 + cb * 16 + lane16, kk * 64 + g16 * 16));
#pragma unroll
        for (int rb = 0; rb < 4; ++rb)
          hacc[rb] = __builtin_amdgcn_mfma_f32_16x16x32_bf16(
              w1f, Areg[rb][kk], hacc[rb], 0, 0, 0);
      }
      const int hcol = nc * 128 + wc * 64 + cb * 16 + g16 * 4;
      const float4 bi = *(const float4*)(bp1 + hcol);
#pragma unroll
      for (int rb = 0; rb < 4; ++rb) {
        const int row = wr * 64 + rb * 16 + lane16;
        const float h0 = fmaxf(hacc[rb][0] + bi.x, 0.f);
        const float h1 = fmaxf(hacc[rb][1] + bi.y, 0.f);
        const float h2 = fmaxf(hacc[rb][2] + bi.z, 0.f);
        const float h3 = fmaxf(hacc[rb][3] + bi.w, 0.f);
        uint2 pkd; pkd.x = pk2(h0, h1); pkd.y = pk2(h2, h3);
        *(uint2*)(buf0 + SWZ(row, wc * 128 + cb * 32 + g16 * 8)) = pkd;
      }
    }
    __syncthreads();
#pragma unroll
    for (int u = 0; u < 8; ++u) {
      const int slot = u * 256 + tid;
      const int row = slot >> 4, sl = slot & 15;
      bf16x8 v = *(const bf16x8*)(Wp2b + (size_t)row * 512 + nc * 128 + sl * 8);
      *(bf16x8*)(buf1 + SWZ(row, sl * 16)) = v;
    }
    __syncthreads();
#pragma unroll
    for (int kk = 0; kk < 4; ++kk) {
      const int kb = kk * 64 + g16 * 16;
      bf16x8 hf[4], w2f[4];
#pragma unroll
      for (int rb = 0; rb < 4; ++rb)
        hf[rb] = *(const bf16x8*)(buf0 + SWZ(wr * 64 + rb * 16 + lane16, kb));
#pragma unroll
      for (int cb = 0; cb < 4; ++cb)
        w2f[cb] = *(const bf16x8*)(buf1 + SWZ(wc * 64 + cb * 16 + lane16, kb));
#pragma unroll
      for (int cb = 0; cb < 4; ++cb)
#pragma unroll
        for (int rb = 0; rb < 4; ++rb)
          acc[cb][rb] = __builtin_amdgcn_mfma_f32_16x16x32_bf16(
              w2f[cb], hf[rb], acc[cb][rb], 0, 0, 0);
    }
    __syncthreads();
  }

  // ---- epilogue: out tile -> smem (swizzled) -> coalesced store ----
#pragma unroll
  for (int cb = 0; cb < 4; ++cb) {
    const int col0 = wc * 64 + cb * 16 + g16 * 4;
    const float4 b2 = *(const float4*)(bp2 + col0);
#pragma unroll
    for (int rb = 0; rb < 4; ++rb) {
      const int row = wr * 64 + rb * 16 + lane16;
      const uint2 pkd = ptk[cb][rb];
      float4 o4;
      o4.x = acc[cb][rb][0] + b2.x + bfl(pkd.x);
      o4.y = acc[cb][rb][1] + b2.y + bfh(pkd.x);
      o4.z = acc[cb][rb][2] + b2.z + bfl(pkd.y);
      o4.w = acc[cb][rb][3] + b2.w + bfh(pkd.y);
      *(float4*)(smem + SWZP(row, col0 * 4)) = o4;
    }
  }
  __syncthreads();
#pragma unroll
  for (int pass = 0; pass < 16; ++pass) {
    const int idx = pass * 256 + tid;
    const int row = idx >> 5, colb = (idx & 31) * 16;
    const float4 v = *(const float4*)(smem + SWZP(row, colb));
    *(float4*)(pout + r0 * 128 + (size_t)idx * 4) = v;
  }
}

// ---------------------------------------------------------------------------
extern "C" void kernel_launch(void* const* d_in, const int* in_sizes, int n_in,
                              void* d_out, int out_size, void* d_ws,
                              size_t ws_size, hipStream_t stream) {
  (void)in_sizes; (void)n_in; (void)out_size; (void)ws_size;
  const float* seq      = (const float*)d_in[0];
  const float* pair     = (const float*)d_in[1];
  const float* ln_p2s_g = (const float*)d_in[2];
  const float* ln_p2s_b = (const float*)d_in[3];
  const float* W_p2s    = (const float*)d_in[4];
  const float* ln1_g    = (const float*)d_in[5];
  const float* ln1_b    = (const float*)d_in[6];
  const float* Wqkv     = (const float*)d_in[7];
  const float* Wo       = (const float*)d_in[8];
  const float* bo       = (const float*)d_in[9];
  const float* Wg       = (const float*)d_in[10];
  const float* bg       = (const float*)d_in[11];
  const float* ln_s_g   = (const float*)d_in[12];
  const float* ln_s_b   = (const float*)d_in[13];
  const float* Wm1      = (const float*)d_in[14];
  const float* bm1      = (const float*)d_in[15];
  const float* Wm2      = (const float*)d_in[16];
  const float* bm2      = (const float*)d_in[17];
  const float* ln_sp_g  = (const float*)d_in[18];
  const float* ln_sp_b  = (const float*)d_in[19];
  const float* Wsp      = (const float*)d_in[20];
  const float* bsp      = (const float*)d_in[21];
  const float* Wspo     = (const float*)d_in[22];
  const float* bspo     = (const float*)d_in[23];
  const float* ln_mp_g  = (const float*)d_in[24];
  const float* ln_mp_b  = (const float*)d_in[25];
  const float* Wp1      = (const float*)d_in[26];
  const float* bp1      = (const float*)d_in[27];
  const float* Wp2      = (const float*)d_in[28];
  const float* bp2      = (const float*)d_in[29];

  float* out_s = (float*)d_out;            // 512*1024
  float* out_p = out_s + 512 * 1024;       // 512*512*128

  // ---- workspace layout (float offsets) ----
  float* ws = (float*)d_ws;
  ushort_t* y_b = (ushort_t*)ws;                       // 524288 ush
  ushort_t* t_b = (ushort_t*)(ws + 262144);            // 1572864 ush
  float* g   = ws + 1048576;                           // 524288 f
  float* o   = g + 524288;                             // 524288 f
  float* s1  = o + 524288;                             // 524288 f
  ushort_t* ob  = (ushort_t*)(s1 + 524288);            // 524288 ush
  ushort_t* h1b = (ushort_t*)(s1 + 524288 + 262144);   // 2097152 ush
  float* spb = s1 + 524288 + 262144 + 1048576;         // 65536 f
  ushort_t* wspo_b = (ushort_t*)(spb + 65536);         // 16384 ush
  ushort_t* wp1_b  = (ushort_t*)(spb + 65536 + 8192);  // 65536 ush
  ushort_t* wp2_b  = (ushort_t*)(spb + 65536 + 40960); // 65536 ush

  // ---- d_out p-section scratch (consumed before pairfuse writes) ----
  float* biasT = out_p;                                // 8388608 f
  ushort_t* wq_b  = (ushort_t*)(out_p + 8388608);      // 3145728 ush
  ushort_t* wg_b  = wq_b + 3145728;                    // 1048576
  ushort_t* wo_b  = wg_b + 1048576;                    // 1048576
  ushort_t* wm1_b = wo_b + 1048576;                    // 4194304
  ushort_t* wm2_b = wm1_b + 4194304;                   // 4194304
  ushort_t* wsp_b = wm2_b + 4194304;                   // 131072

  cvt9_kernel<<<6792, 256, 0, stream>>>(Wqkv, wq_b, Wg, wg_b, Wo, wo_b,
                                        Wm1, wm1_b, Wm2, wm2_b, Wsp, wsp_b,
                                        Wspo, wspo_b, Wp1, wp1_b, Wp2, wp2_b);
  ln1024b_kernel<<<512, 256, 0, stream>>>(seq, ln1_g, ln1_b, y_b);
  gemm_mfma_kernel<0, 0, 0, 1><<<dim3(24, 8), 256, 0, stream>>>(
      y_b, wq_b, nullptr, nullptr, nullptr, t_b, 512, 3072, 1024);
  gemm_mfma_kernel<1, 0, 0, 0><<<dim3(8, 8), 256, 0, stream>>>(
      y_b, wg_b, bg, nullptr, g, nullptr, 512, 1024, 1024);
  p2s_mfma_kernel<<<2048, 256, 0, stream>>>(pair, ln_p2s_g, ln_p2s_b, W_p2s,
                                            biasT);
  attn_kernel<<<dim3(8, 32), 256, 0, stream>>>(t_b, biasT, o);
  gate_b_kernel<<<512, 256, 0, stream>>>(o, g, ob);
  gemm_mfma_kernel<1, 0, 1, 0><<<dim3(8, 8), 256, 0, stream>>>(
      ob, wo_b, bo, seq, s1, nullptr, 512, 1024, 1024);
  ln1024b_kernel<<<512, 256, 0, stream>>>(s1, ln_s_g, ln_s_b, y_b);
  gemm_mfma_kernel<1, 1, 0, 1><<<dim3(32, 8), 256, 0, stream>>>(
      y_b, wm1_b, bm1, nullptr, nullptr, h1b, 512, 4096, 1024);
  gemm_mfma_kernel<1, 0, 1, 0><<<dim3(8, 8), 256, 0, stream>>>(
      h1b, wm2_b, bm2, s1, out_s, nullptr, 512, 1024, 4096);
  ln1024b_kernel<<<512, 256, 0, stream>>>(out_s, ln_sp_g, ln_sp_b, y_b);
  gemm_mfma_kernel<1, 0, 0, 0><<<dim3(1, 8), 256, 0, stream>>>(
      y_b, wsp_b, bsp, nullptr, spb, nullptr, 512, 128, 1024);
  pairfuse_kernel<<<2048, 256, 0, stream>>>(spb, wspo_b, bspo, pair,
                                            ln_mp_g, ln_mp_b, wp1_b, bp1,
                                            wp2_b, bp2, out_p);
}

// Round 7
// 552.821 us; speedup vs baseline: 7.0963x; 1.0760x over previous
//
#include <hip/hip_runtime.h>
#include <hip/hip_bf16.h>
#include <cstddef>

// ---------------------------------------------------------------------------
// TriangularSelfAttentionBlock R6: pairfuse64 (wave-owns-rows, in-reg butterfly)
// L=512, SEQ_D=1024, PAIR_D=128, H=32, HW=32, INNER=64
// ---------------------------------------------------------------------------

#define L 512
#define SEQ_D 1024
#define PAIR_D 128
#define NH 32
#define HW 32

typedef short bf16x8 __attribute__((ext_vector_type(8)));
typedef float f32x4 __attribute__((ext_vector_type(4)));
typedef unsigned short ushort_t;

__device__ inline float wred_sum(float v) {
#pragma unroll
  for (int off = 32; off; off >>= 1) v += __shfl_xor(v, off, 64);
  return v;
}
// f32 -> bf16 (RNE), packed pair (a low, b high)
__device__ inline unsigned pk2(float a, float b) {
  unsigned ua = __float_as_uint(a), ub = __float_as_uint(b);
  ua = (ua + 0x7fffu + ((ua >> 16) & 1u)) >> 16;
  ub = (ub + 0x7fffu + ((ub >> 16) & 1u)) >> 16;
  return ua | (ub << 16);
}
__device__ inline float bfl(unsigned u) { return __uint_as_float(u << 16); }
__device__ inline float bfh(unsigned u) { return __uint_as_float(u & 0xffff0000u); }

// swizzled byte offset for [row][256B] LDS tiles
#define SWZ(row, kb) ((((row)) << 8) + ((kb) ^ (((row)&7) << 4)))
// swizzled byte offset for [row][128B] LDS tiles
#define SWZ64(row, kb) ((((row)) << 7) + ((kb) ^ (((row)&7) << 4)))

// ---------------- fused f32->bf16 weight conversion (9 tensors) ------------
__global__ __launch_bounds__(256) void cvt9_kernel(
    const float* __restrict__ s0, ushort_t* __restrict__ d0,
    const float* __restrict__ s1, ushort_t* __restrict__ d1,
    const float* __restrict__ s2, ushort_t* __restrict__ d2,
    const float* __restrict__ s3, ushort_t* __restrict__ d3,
    const float* __restrict__ s4, ushort_t* __restrict__ d4,
    const float* __restrict__ s5, ushort_t* __restrict__ d5,
    const float* __restrict__ s6, ushort_t* __restrict__ d6,
    const float* __restrict__ s7, ushort_t* __restrict__ d7,
    const float* __restrict__ s8, ushort_t* __restrict__ d8) {
  const int b = blockIdx.x;
  const float* s; ushort_t* d; int base;
  if (b < 1536)      { s = s0; d = d0; base = b; }
  else if (b < 2048) { s = s1; d = d1; base = b - 1536; }
  else if (b < 2560) { s = s2; d = d2; base = b - 2048; }
  else if (b < 4608) { s = s3; d = d3; base = b - 2560; }
  else if (b < 6656) { s = s4; d = d4; base = b - 4608; }
  else if (b < 6720) { s = s5; d = d5; base = b - 6656; }
  else if (b < 6728) { s = s6; d = d6; base = b - 6720; }
  else if (b < 6760) { s = s7; d = d7; base = b - 6728; }
  else               { s = s8; d = d8; base = b - 6760; }
  const int i = base * 256 + threadIdx.x;
  float4 a = ((const float4*)s)[2 * i], c = ((const float4*)s)[2 * i + 1];
  uint4 w;
  w.x = pk2(a.x, a.y); w.y = pk2(a.z, a.w);
  w.z = pk2(c.x, c.y); w.w = pk2(c.z, c.w);
  ((uint4*)d)[i] = w;
}

// ---------------- LayerNorm 1024 -> bf16 out -------------------------------
__global__ __launch_bounds__(256) void ln1024b_kernel(
    const float* __restrict__ in, const float* __restrict__ g,
    const float* __restrict__ b, ushort_t* __restrict__ out) {
  const int row = blockIdx.x;
  const int tid = threadIdx.x;
  float4 v = ((const float4*)(in + (size_t)row * SEQ_D))[tid];
  float s = v.x + v.y + v.z + v.w;
  float s2 = v.x * v.x + v.y * v.y + v.z * v.z + v.w * v.w;
  __shared__ float red[8];
  const int lane = tid & 63, wid = tid >> 6;
  s = wred_sum(s);
  s2 = wred_sum(s2);
  if (lane == 0) { red[wid] = s; red[4 + wid] = s2; }
  __syncthreads();
  s = red[0] + red[1] + red[2] + red[3];
  s2 = red[4] + red[5] + red[6] + red[7];
  const float mean = s * (1.0f / SEQ_D);
  const float var = s2 * (1.0f / SEQ_D) - mean * mean;
  const float rstd = rsqrtf(var + 1e-5f);
  float4 gv = ((const float4*)g)[tid];
  float4 bv = ((const float4*)b)[tid];
  const float o0 = (v.x - mean) * rstd * gv.x + bv.x;
  const float o1 = (v.y - mean) * rstd * gv.y + bv.y;
  const float o2 = (v.z - mean) * rstd * gv.z + bv.z;
  const float o3 = (v.w - mean) * rstd * gv.w + bv.w;
  uint2 pkd; pkd.x = pk2(o0, o1); pkd.y = pk2(o2, o3);
  ((uint2*)(out + (size_t)row * SEQ_D))[tid] = pkd;
}

// ---------------- MFMA GEMM: C[M][N] = A[M][K](bf16) @ B[N][K]^T(bf16) -----
template <int BIAS, int RELU, int RES, int OBF16>
__global__ __launch_bounds__(256, 2) void gemm_mfma_kernel(
    const ushort_t* __restrict__ A, const ushort_t* __restrict__ B,
    const float* __restrict__ bias, const float* __restrict__ res,
    float* __restrict__ C, ushort_t* __restrict__ Cb, int M, int N, int K) {
  __shared__ __align__(16) char smem[24576];
  char* Ab = smem;
  char* Bb = smem + 8192;
  const int tid = threadIdx.x;
  const int l = tid & 63, w = tid >> 6;
  const int wr = w >> 1, wc = w & 1;
  const int lane16 = l & 15, g16 = l >> 4;
  const int bm = blockIdx.y * 64, bn = blockIdx.x * 128;
  const f32x4 fz = {0.f, 0.f, 0.f, 0.f};
  f32x4 acc[4][2];
#pragma unroll
  for (int i = 0; i < 4; ++i)
#pragma unroll
    for (int j = 0; j < 2; ++j) acc[i][j] = fz;

  for (int k0 = 0; k0 < K; k0 += 64) {
    __syncthreads();
#pragma unroll
    for (int u = 0; u < 2; ++u) {
      const int slot = u * 256 + tid;
      const int row = slot >> 3, sl = slot & 7;
      bf16x8 v = *(const bf16x8*)(A + (size_t)(bm + row) * K + k0 + sl * 8);
      *(bf16x8*)(Ab + SWZ64(row, sl * 16)) = v;
    }
#pragma unroll
    for (int u = 0; u < 4; ++u) {
      const int slot = u * 256 + tid;
      const int row = slot >> 3, sl = slot & 7;
      bf16x8 v = *(const bf16x8*)(B + (size_t)(bn + row) * K + k0 + sl * 8);
      *(bf16x8*)(Bb + SWZ64(row, sl * 16)) = v;
    }
    __syncthreads();
#pragma unroll
    for (int kk = 0; kk < 2; ++kk) {
      const int kb = kk * 64 + g16 * 16;
      bf16x8 af[2], bf[4];
#pragma unroll
      for (int rb = 0; rb < 2; ++rb) {
        const int row = wr * 32 + rb * 16 + lane16;
        af[rb] = *(const bf16x8*)(Ab + SWZ64(row, kb));
      }
#pragma unroll
      for (int cb = 0; cb < 4; ++cb) {
        const int row = wc * 64 + cb * 16 + lane16;
        bf[cb] = *(const bf16x8*)(Bb + SWZ64(row, kb));
      }
#pragma unroll
      for (int cb = 0; cb < 4; ++cb)
#pragma unroll
        for (int rb = 0; rb < 2; ++rb)
          acc[cb][rb] = __builtin_amdgcn_mfma_f32_16x16x32_bf16(
              bf[cb], af[rb], acc[cb][rb], 0, 0, 0);
    }
  }
#pragma unroll
  for (int cb = 0; cb < 4; ++cb) {
    const int col0 = bn + wc * 64 + cb * 16 + g16 * 4;
    float4 bi = make_float4(0.f, 0.f, 0.f, 0.f);
    if (BIAS) bi = *(const float4*)(bias + col0);
#pragma unroll
    for (int rb = 0; rb < 2; ++rb) {
      const int row = bm + wr * 32 + rb * 16 + lane16;
      f32x4 v = acc[cb][rb];
      v[0] += bi.x; v[1] += bi.y; v[2] += bi.z; v[3] += bi.w;
      if (RELU) {
        v[0] = fmaxf(v[0], 0.f); v[1] = fmaxf(v[1], 0.f);
        v[2] = fmaxf(v[2], 0.f); v[3] = fmaxf(v[3], 0.f);
      }
      if (RES) {
        const float4 r4 = *(const float4*)(res + (size_t)row * N + col0);
        v[0] += r4.x; v[1] += r4.y; v[2] += r4.z; v[3] += r4.w;
      }
      if (OBF16) {
        uint2 pkd; pkd.x = pk2(v[0], v[1]); pkd.y = pk2(v[2], v[3]);
        *(uint2*)(Cb + (size_t)row * N + col0) = pkd;
      } else {
        float4 o4; o4.x = v[0]; o4.y = v[1]; o4.z = v[2]; o4.w = v[3];
        *(float4*)(C + (size_t)row * N + col0) = o4;
      }
    }
  }
}

// ---------------- PairToSequence via MFMA ----------------------------------
__global__ __launch_bounds__(256) void p2s_mfma_kernel(
    const float* __restrict__ pair, const float* __restrict__ g,
    const float* __restrict__ b, const float* __restrict__ W,
    float* __restrict__ biasT) {
  __shared__ __align__(16) char pnb[32768];
  __shared__ __align__(16) char wls[8192];
  const int tid = threadIdx.x;
  const int l = tid & 63, w = tid >> 6;
  const int lane16 = l & 15, g16 = l >> 4;
  const size_t r0 = (size_t)blockIdx.x * 128;
  const int i_idx = (int)(r0 >> 9), j0 = (int)(r0 & 511);
#pragma unroll
  for (int u = 0; u < 2; ++u) {
    const int slot = u * 256 + tid;
    const int row = slot >> 4, sl = slot & 15;
    const float4 v0 = *(const float4*)(W + (size_t)row * 128 + sl * 8);
    const float4 v1 = *(const float4*)(W + (size_t)row * 128 + sl * 8 + 4);
    uint4 wv; wv.x = pk2(v0.x, v0.y); wv.y = pk2(v0.z, v0.w);
    wv.z = pk2(v1.x, v1.y); wv.w = pk2(v1.z, v1.w);
    *(uint4*)(wls + SWZ(row, sl * 16)) = wv;
  }
  {
    const int l32 = tid & 31, rg = tid >> 5;
    const float4 gv = *(const float4*)(g + l32 * 4);
    const float4 bv = *(const float4*)(b + l32 * 4);
#pragma unroll
    for (int it = 0; it < 16; ++it) {
      const int r = it * 8 + rg;
      const float4 v = *(const float4*)(pair + (r0 + r) * 128 + l32 * 4);
      float s = v.x + v.y + v.z + v.w;
      float s2 = v.x * v.x + v.y * v.y + v.z * v.z + v.w * v.w;
#pragma unroll
      for (int off = 1; off < 32; off <<= 1) {
        s += __shfl_xor(s, off, 64);
        s2 += __shfl_xor(s2, off, 64);
      }
      const float mean = s * (1.0f / 128.0f);
      const float rstd = rsqrtf(s2 * (1.0f / 128.0f) - mean * mean + 1e-5f);
      const float n0 = (v.x - mean) * rstd * gv.x + bv.x;
      const float n1 = (v.y - mean) * rstd * gv.y + bv.y;
      const float n2 = (v.z - mean) * rstd * gv.z + bv.z;
      const float n3 = (v.w - mean) * rstd * gv.w + bv.w;
      uint2 pkd; pkd.x = pk2(n0, n1); pkd.y = pk2(n2, n3);
      *(uint2*)(pnb + SWZ(r, l32 * 8)) = pkd;
    }
  }
  __syncthreads();
  const f32x4 fz = {0.f, 0.f, 0.f, 0.f};
  f32x4 a2[2][2];
#pragma unroll
  for (int i = 0; i < 2; ++i)
#pragma unroll
    for (int j = 0; j < 2; ++j) a2[i][j] = fz;
#pragma unroll
  for (int kk = 0; kk < 4; ++kk) {
    bf16x8 wf[2], pf[2];
#pragma unroll
    for (int hb = 0; hb < 2; ++hb)
      wf[hb] = *(const bf16x8*)(wls + SWZ(hb * 16 + lane16, kk * 64 + g16 * 16));
#pragma unroll
    for (int rb = 0; rb < 2; ++rb)
      pf[rb] = *(const bf16x8*)(pnb + SWZ(w * 32 + rb * 16 + lane16, kk * 64 + g16 * 16));
#pragma unroll
    for (int hb = 0; hb < 2; ++hb)
#pragma unroll
      for (int rb = 0; rb < 2; ++rb)
        a2[hb][rb] = __builtin_amdgcn_mfma_f32_16x16x32_bf16(
            wf[hb], pf[rb], a2[hb][rb], 0, 0, 0);
  }
#pragma unroll
  for (int hb = 0; hb < 2; ++hb)
#pragma unroll
    for (int rb = 0; rb < 2; ++rb) {
      const int j = j0 + w * 32 + rb * 16 + lane16;
#pragma unroll
      for (int qq = 0; qq < 4; ++qq) {
        const int hh = hb * 16 + g16 * 4 + qq;
        biasT[((size_t)hh * 512 + i_idx) * 512 + j] = a2[hb][rb][qq];
      }
    }
}

// ---------------- fused attention: softmax(scale*QK^T + bias) @ V ----------
__global__ __launch_bounds__(256) void attn_kernel(
    const ushort_t* __restrict__ tb, const float* __restrict__ biasT,
    float* __restrict__ o) {
  __shared__ __align__(16) ushort_t Vt[32][80];
  const int tid = threadIdx.x;
  const int l = tid & 63, wq = tid >> 6;
  const int lane16 = l & 15, g16 = l >> 4;
  const int h = blockIdx.y;
  const int q = blockIdx.x * 64 + wq * 16 + lane16;
  const float scale = 0.17677669529663689f;
  const bf16x8 qf = *(const bf16x8*)(tb + (size_t)q * 3072 + h * 96 + g16 * 8);
  const float* brow = biasT + ((size_t)h * 512 + q) * 512;
  float m = -3e38f, lsum = 0.f;
  const f32x4 fz = {0.f, 0.f, 0.f, 0.f};
  f32x4 accp[2] = {fz, fz};
  for (int kt = 0; kt < 512; kt += 64) {
    {
      const int kr = tid >> 2, cc = tid & 3;
      bf16x8 vv = *(const bf16x8*)(tb + (size_t)(kt + kr) * 3072 + h * 96 + 64 + cc * 8);
#pragma unroll
      for (int u = 0; u < 8; ++u) Vt[cc * 8 + u][kr] = (ushort_t)vv[u];
    }
    __syncthreads();
    f32x4 st[4];
#pragma unroll
    for (int kb = 0; kb < 4; ++kb) {
      const bf16x8 kf = *(const bf16x8*)(
          tb + (size_t)(kt + kb * 16 + lane16) * 3072 + h * 96 + 32 + g16 * 8);
      st[kb] = __builtin_amdgcn_mfma_f32_16x16x32_bf16(kf, qf, fz, 0, 0, 0);
      const float4 bv = *(const float4*)(brow + kt + kb * 16 + g16 * 4);
      st[kb][0] = st[kb][0] * scale + bv.x;
      st[kb][1] = st[kb][1] * scale + bv.y;
      st[kb][2] = st[kb][2] * scale + bv.z;
      st[kb][3] = st[kb][3] * scale + bv.w;
    }
    float tm = st[0][0];
#pragma unroll
    for (int kb = 0; kb < 4; ++kb)
#pragma unroll
      for (int qq = 0; qq < 4; ++qq) tm = fmaxf(tm, st[kb][qq]);
    tm = fmaxf(tm, __shfl_xor(tm, 16, 64));
    tm = fmaxf(tm, __shfl_xor(tm, 32, 64));
    const float mn = fmaxf(m, tm);
    const float corr = __expf(m - mn);
    m = mn;
    lsum *= corr;
#pragma unroll
    for (int ct = 0; ct < 2; ++ct) {
      accp[ct][0] *= corr; accp[ct][1] *= corr;
      accp[ct][2] *= corr; accp[ct][3] *= corr;
    }
#pragma unroll
    for (int kb = 0; kb < 4; ++kb)
#pragma unroll
      for (int qq = 0; qq < 4; ++qq) {
        const float e = __expf(st[kb][qq] - mn);
        st[kb][qq] = e;
        lsum += e;
      }
    const int src0 = lane16 + ((l & 16) << 1);
    const int src1 = src0 + 16;
    const bool hi = (l & 32) != 0;
#pragma unroll
    for (int kk = 0; kk < 2; ++kk) {
      float lo4[4], hi4[4];
#pragma unroll
      for (int qq = 0; qq < 4; ++qq) {
        const float a0 = __shfl(st[kk * 2][qq], src0, 64);
        const float a1 = __shfl(st[kk * 2][qq], src1, 64);
        const float b0 = __shfl(st[kk * 2 + 1][qq], src0, 64);
        const float b1 = __shfl(st[kk * 2 + 1][qq], src1, 64);
        lo4[qq] = hi ? b0 : a0;
        hi4[qq] = hi ? b1 : a1;
      }
      uint4 pu;
      pu.x = pk2(lo4[0], lo4[1]); pu.y = pk2(lo4[2], lo4[3]);
      pu.z = pk2(hi4[0], hi4[1]); pu.w = pk2(hi4[2], hi4[3]);
      bf16x8 pf;
      __builtin_memcpy(&pf, &pu, 16);
#pragma unroll
      for (int ct = 0; ct < 2; ++ct) {
        const bf16x8 vf = *(const bf16x8*)&Vt[ct * 16 + lane16][kk * 32 + g16 * 8];
        accp[ct] = __builtin_amdgcn_mfma_f32_16x16x32_bf16(vf, pf, accp[ct], 0, 0, 0);
      }
    }
    __syncthreads();
  }
  lsum += __shfl_xor(lsum, 16, 64);
  lsum += __shfl_xor(lsum, 32, 64);
  const float inv = 1.0f / lsum;
#pragma unroll
  for (int ct = 0; ct < 2; ++ct) {
    float4 o4;
    o4.x = accp[ct][0] * inv; o4.y = accp[ct][1] * inv;
    o4.z = accp[ct][2] * inv; o4.w = accp[ct][3] * inv;
    *(float4*)(o + (size_t)q * SEQ_D + h * 32 + ct * 16 + g16 * 4) = o4;
  }
}

// ---------------- gate: ob = bf16(o * sigmoid(g)) --------------------------
__global__ __launch_bounds__(256) void gate_b_kernel(
    const float* __restrict__ o, const float* __restrict__ g,
    ushort_t* __restrict__ ob) {
  const int i = blockIdx.x * 256 + threadIdx.x;
  float4 ov = ((const float4*)o)[i];
  float4 gv = ((const float4*)g)[i];
  ov.x *= 1.0f / (1.0f + __expf(-gv.x));
  ov.y *= 1.0f / (1.0f + __expf(-gv.y));
  ov.z *= 1.0f / (1.0f + __expf(-gv.z));
  ov.w *= 1.0f / (1.0f + __expf(-gv.w));
  uint2 pkd; pkd.x = pk2(ov.x, ov.y); pkd.y = pk2(ov.z, ov.w);
  ((uint2*)ob)[i] = pkd;
}

// ---------------- in-wave butterfly: C-layout packed -> A/B-frag -----------
// pk[8]: uint2 per cb = 4 bf16 at cols cb*16 + g16*4 + q (own g16).
// returns frag kk: vals at k = kk*32 + g16*8 + j, j=0..7.
template <int KK>
__device__ inline bf16x8 bfly(const uint2* pk, int lane16, int g16) {
  const int sl_lo = lane16 + (((g16 * 2) & 3) << 4);
  const int sl_hi = lane16 + (((g16 * 2 + 1) & 3) << 4);
  const int hiSel = g16 >> 1;
  const unsigned a0x = __shfl((int)pk[2 * KK].x, sl_lo, 64);
  const unsigned a0y = __shfl((int)pk[2 * KK].y, sl_lo, 64);
  const unsigned a1x = __shfl((int)pk[2 * KK + 1].x, sl_lo, 64);
  const unsigned a1y = __shfl((int)pk[2 * KK + 1].y, sl_lo, 64);
  const unsigned b0x = __shfl((int)pk[2 * KK].x, sl_hi, 64);
  const unsigned b0y = __shfl((int)pk[2 * KK].y, sl_hi, 64);
  const unsigned b1x = __shfl((int)pk[2 * KK + 1].x, sl_hi, 64);
  const unsigned b1y = __shfl((int)pk[2 * KK + 1].y, sl_hi, 64);
  uint4 u;
  u.x = hiSel ? a1x : a0x;
  u.y = hiSel ? a1y : a0y;
  u.z = hiSel ? b1x : b0x;
  u.w = hiSel ? b1y : b0y;
  bf16x8 r;
  __builtin_memcpy(&r, &u, 16);
  return r;
}

// ---------------- fused SequenceToPair + pair MLP (64-row tiles) -----------
// wave w owns rows w*16..w*16+15 (all 128 cols). LDS: one 32KB W buffer.
__global__ __launch_bounds__(256, 3) void pairfuse64_kernel(
    const float* __restrict__ spb, const ushort_t* __restrict__ Wspob,
    const float* __restrict__ bspo, const float* __restrict__ pairw,
    const float* __restrict__ lng, const float* __restrict__ lnb,
    const ushort_t* __restrict__ Wp1b, const float* __restrict__ bp1,
    const ushort_t* __restrict__ Wp2b, const float* __restrict__ bp2,
    float* __restrict__ pout) {
  __shared__ __align__(16) char Wbuf[32768];  // 128 rows x 256B, swizzled
  const int tid = threadIdx.x;
  const int l = tid & 63, w = tid >> 6;
  const int lane16 = l & 15, g16 = l >> 4;
  const size_t r0 = (size_t)blockIdx.x * 64;
  const int i_idx = (int)(r0 >> 9), j0 = (int)(r0 & 511);
  const int prow = w * 16 + lane16;            // local row 0..63
  const size_t grow = r0 + prow;               // global p-row

  // ---- stage Wspo (128x128 bf16) ----
#pragma unroll
  for (int u = 0; u < 8; ++u) {
    const int slot = u * 256 + tid;
    const int row = slot >> 4, sl = slot & 15;
    bf16x8 v = *(const bf16x8*)(Wspob + (size_t)row * 128 + sl * 8);
    *(bf16x8*)(Wbuf + SWZ(row, sl * 16)) = v;
  }

  // ---- build X A-frags in registers: X = [qh*kh | qh-kh] ----
  bf16x8 xf[4];
  {
    const float* qrow = spb + (size_t)(j0 + prow) * 128;
    const float* krow = spb + (size_t)i_idx * 128 + 64;
#pragma unroll
    for (int kk = 0; kk < 4; ++kk) {
      const int c = ((kk & 1) << 5) + g16 * 8;
      const float4 q0 = *(const float4*)(qrow + c);
      const float4 q1 = *(const float4*)(qrow + c + 4);
      const float4 k0 = *(const float4*)(krow + c);
      const float4 k1 = *(const float4*)(krow + c + 4);
      uint4 u;
      if (kk < 2) {
        u.x = pk2(q0.x * k0.x, q0.y * k0.y);
        u.y = pk2(q0.z * k0.z, q0.w * k0.w);
        u.z = pk2(q1.x * k1.x, q1.y * k1.y);
        u.w = pk2(q1.z * k1.z, q1.w * k1.w);
      } else {
        u.x = pk2(q0.x - k0.x, q0.y - k0.y);
        u.y = pk2(q0.z - k0.z, q0.w - k0.w);
        u.z = pk2(q1.x - k1.x, q1.y - k1.y);
        u.w = pk2(q1.z - k1.z, q1.w - k1.w);
      }
      __builtin_memcpy(&xf[kk], &u, 16);
    }
  }
  __syncthreads();

  // ---- GEMM0: acc[cb] = X @ Wspo^T ----
  const f32x4 fz = {0.f, 0.f, 0.f, 0.f};
  f32x4 acc[8];
#pragma unroll
  for (int cb = 0; cb < 8; ++cb) acc[cb] = fz;
#pragma unroll
  for (int kk = 0; kk < 4; ++kk) {
#pragma unroll
    for (int cb = 0; cb < 8; ++cb) {
      const bf16x8 wf = *(const bf16x8*)(
          Wbuf + SWZ(cb * 16 + lane16, kk * 64 + g16 * 16));
      acc[cb] = __builtin_amdgcn_mfma_f32_16x16x32_bf16(wf, xf[kk], acc[cb], 0, 0, 0);
    }
  }

  // ---- P = acc + bspo + pair; LN stats in-wave ----
  uint2 Ppk[8];
  float s = 0.f, s2 = 0.f;
#pragma unroll
  for (int cb = 0; cb < 8; ++cb) {
    const int col0 = cb * 16 + g16 * 4;
    const float4 bs = *(const float4*)(bspo + col0);
    const float4 pw = *(const float4*)(pairw + grow * 128 + col0);
    acc[cb][0] += bs.x + pw.x; acc[cb][1] += bs.y + pw.y;
    acc[cb][2] += bs.z + pw.z; acc[cb][3] += bs.w + pw.w;
    s += acc[cb][0] + acc[cb][1] + acc[cb][2] + acc[cb][3];
    s2 += acc[cb][0] * acc[cb][0] + acc[cb][1] * acc[cb][1] +
          acc[cb][2] * acc[cb][2] + acc[cb][3] * acc[cb][3];
    Ppk[cb].x = pk2(acc[cb][0], acc[cb][1]);
    Ppk[cb].y = pk2(acc[cb][2], acc[cb][3]);
  }
  s += __shfl_xor(s, 16, 64);  s += __shfl_xor(s, 32, 64);
  s2 += __shfl_xor(s2, 16, 64); s2 += __shfl_xor(s2, 32, 64);
  const float mean = s * (1.0f / 128.0f);
  const float rstd = rsqrtf(s2 * (1.0f / 128.0f) - mean * mean + 1e-5f);

  // ---- pn = LN(P) packed, then butterfly -> A-frags ----
  uint2 pnpk[8];
#pragma unroll
  for (int cb = 0; cb < 8; ++cb) {
    const int col0 = cb * 16 + g16 * 4;
    const float4 gv = *(const float4*)(lng + col0);
    const float4 bv = *(const float4*)(lnb + col0);
    const float n0 = (acc[cb][0] - mean) * rstd * gv.x + bv.x;
    const float n1 = (acc[cb][1] - mean) * rstd * gv.y + bv.y;
    const float n2 = (acc[cb][2] - mean) * rstd * gv.z + bv.z;
    const float n3 = (acc[cb][3] - mean) * rstd * gv.w + bv.w;
    pnpk[cb].x = pk2(n0, n1); pnpk[cb].y = pk2(n2, n3);
  }
  bf16x8 pnf[4];
  pnf[0] = bfly<0>(pnpk, lane16, g16);
  pnf[1] = bfly<1>(pnpk, lane16, g16);
  pnf[2] = bfly<2>(pnpk, lane16, g16);
  pnf[3] = bfly<3>(pnpk, lane16, g16);

  // ---- MLP: 4 chunks of 128 hidden ----
  f32x4 acc2[8];
#pragma unroll
  for (int cb = 0; cb < 8; ++cb) acc2[cb] = fz;

  for (int ch = 0; ch < 4; ++ch) {
    __syncthreads();  // all waves done reading Wbuf
    // stage W1 chunk: Wp1b[ch*128 + row][0:128]
#pragma unroll
    for (int u = 0; u < 8; ++u) {
      const int slot = u * 256 + tid;
      const int row = slot >> 4, sl = slot & 15;
      bf16x8 v = *(const bf16x8*)(Wp1b + (size_t)(ch * 128 + row) * 128 + sl * 8);
      *(bf16x8*)(Wbuf + SWZ(row, sl * 16)) = v;
    }
    __syncthreads();
    // GEMM1: hacc[cb1] = pn @ W1c^T  (16 rows x 128 hidden per wave)
    f32x4 hacc[8];
#pragma unroll
    for (int cb = 0; cb < 8; ++cb) hacc[cb] = fz;
#pragma unroll
    for (int kk = 0; kk < 4; ++kk) {
#pragma unroll
      for (int cb = 0; cb < 8; ++cb) {
        const bf16x8 w1f = *(const bf16x8*)(
            Wbuf + SWZ(cb * 16 + lane16, kk * 64 + g16 * 16));
        hacc[cb] = __builtin_amdgcn_mfma_f32_16x16x32_bf16(w1f, pnf[kk], hacc[cb], 0, 0, 0);
      }
    }
    // bias + relu + pack
    uint2 hpk[8];
#pragma unroll
    for (int cb = 0; cb < 8; ++cb) {
      const int hcol = ch * 128 + cb * 16 + g16 * 4;
      const float4 bi = *(const float4*)(bp1 + hcol);
      const float h0 = fmaxf(hacc[cb][0] + bi.x, 0.f);
      const float h1 = fmaxf(hacc[cb][1] + bi.y, 0.f);
      const float h2 = fmaxf(hacc[cb][2] + bi.z, 0.f);
      const float h3 = fmaxf(hacc[cb][3] + bi.w, 0.f);
      hpk[cb].x = pk2(h0, h1); hpk[cb].y = pk2(h2, h3);
    }
    bf16x8 hf[4];
    hf[0] = bfly<0>(hpk, lane16, g16);
    hf[1] = bfly<1>(hpk, lane16, g16);
    hf[2] = bfly<2>(hpk, lane16, g16);
    hf[3] = bfly<3>(hpk, lane16, g16);
    __syncthreads();  // GEMM1 LDS reads done
    // stage W2 chunk: Wp2b[m][ch*128 : +128]
#pragma unroll
    for (int u = 0; u < 8; ++u) {
      const int slot = u * 256 + tid;
      const int row = slot >> 4, sl = slot & 15;
      bf16x8 v = *(const bf16x8*)(Wp2b + (size_t)row * 512 + ch * 128 + sl * 8);
      *(bf16x8*)(Wbuf + SWZ(row, sl * 16)) = v;
    }
    __syncthreads();
    // GEMM2: acc2[cb2] += H @ W2c^T
#pragma unroll
    for (int kk = 0; kk < 4; ++kk) {
#pragma unroll
      for (int cb = 0; cb < 8; ++cb) {
        const bf16x8 w2f = *(const bf16x8*)(
            Wbuf + SWZ(cb * 16 + lane16, kk * 64 + g16 * 16));
        acc2[cb] = __builtin_amdgcn_mfma_f32_16x16x32_bf16(w2f, hf[kk], acc2[cb], 0, 0, 0);
      }
    }
  }

  // ---- epilogue: out = P + acc2 + bp2 (direct full-line float4 stores) ----
#pragma unroll
  for (int cb = 0; cb < 8; ++cb) {
    const int col0 = cb * 16 + g16 * 4;
    const float4 b2 = *(const float4*)(bp2 + col0);
    float4 o4;
    o4.x = acc2[cb][0] + b2.x + bfl(Ppk[cb].x);
    o4.y = acc2[cb][1] + b2.y + bfh(Ppk[cb].x);
    o4.z = acc2[cb][2] + b2.z + bfl(Ppk[cb].y);
    o4.w = acc2[cb][3] + b2.w + bfh(Ppk[cb].y);
    *(float4*)(pout + grow * 128 + col0) = o4;
  }
}

// ---------------------------------------------------------------------------
extern "C" void kernel_launch(void* const* d_in, const int* in_sizes, int n_in,
                              void* d_out, int out_size, void* d_ws,
                              size_t ws_size, hipStream_t stream) {
  (void)in_sizes; (void)n_in; (void)out_size; (void)ws_size;
  const float* seq      = (const float*)d_in[0];
  const float* pair     = (const float*)d_in[1];
  const float* ln_p2s_g = (const float*)d_in[2];
  const float* ln_p2s_b = (const float*)d_in[3];
  const float* W_p2s    = (const float*)d_in[4];
  const float* ln1_g    = (const float*)d_in[5];
  const float* ln1_b    = (const float*)d_in[6];
  const float* Wqkv     = (const float*)d_in[7];
  const float* Wo       = (const float*)d_in[8];
  const float* bo       = (const float*)d_in[9];
  const float* Wg       = (const float*)d_in[10];
  const float* bg       = (const float*)d_in[11];
  const float* ln_s_g   = (const float*)d_in[12];
  const float* ln_s_b   = (const float*)d_in[13];
  const float* Wm1      = (const float*)d_in[14];
  const float* bm1      = (const float*)d_in[15];
  const float* Wm2      = (const float*)d_in[16];
  const float* bm2      = (const float*)d_in[17];
  const float* ln_sp_g  = (const float*)d_in[18];
  const float* ln_sp_b  = (const float*)d_in[19];
  const float* Wsp      = (const float*)d_in[20];
  const float* bsp      = (const float*)d_in[21];
  const float* Wspo     = (const float*)d_in[22];
  const float* bspo     = (const float*)d_in[23];
  const float* ln_mp_g  = (const float*)d_in[24];
  const float* ln_mp_b  = (const float*)d_in[25];
  const float* Wp1      = (const float*)d_in[26];
  const float* bp1      = (const float*)d_in[27];
  const float* Wp2      = (const float*)d_in[28];
  const float* bp2      = (const float*)d_in[29];

  float* out_s = (float*)d_out;            // 512*1024
  float* out_p = out_s + 512 * 1024;       // 512*512*128

  float* ws = (float*)d_ws;
  ushort_t* y_b = (ushort_t*)ws;                       // 524288 ush
  ushort_t* t_b = (ushort_t*)(ws + 262144);            // 1572864 ush
  float* g   = ws + 1048576;                           // 524288 f
  float* o   = g + 524288;                             // 524288 f
  float* s1  = o + 524288;                             // 524288 f
  ushort_t* ob  = (ushort_t*)(s1 + 524288);            // 524288 ush
  ushort_t* h1b = (ushort_t*)(s1 + 524288 + 262144);   // 2097152 ush
  float* spb = s1 + 524288 + 262144 + 1048576;         // 65536 f
  ushort_t* wspo_b = (ushort_t*)(spb + 65536);         // 16384 ush
  ushort_t* wp1_b  = (ushort_t*)(spb + 65536 + 8192);  // 65536 ush
  ushort_t* wp2_b  = (ushort_t*)(spb + 65536 + 40960); // 65536 ush

  float* biasT = out_p;                                // 8388608 f
  ushort_t* wq_b  = (ushort_t*)(out_p + 8388608);      // 3145728 ush
  ushort_t* wg_b  = wq_b + 3145728;
  ushort_t* wo_b  = wg_b + 1048576;
  ushort_t* wm1_b = wo_b + 1048576;
  ushort_t* wm2_b = wm1_b + 4194304;
  ushort_t* wsp_b = wm2_b + 4194304;

  cvt9_kernel<<<6792, 256, 0, stream>>>(Wqkv, wq_b, Wg, wg_b, Wo, wo_b,
                                        Wm1, wm1_b, Wm2, wm2_b, Wsp, wsp_b,
                                        Wspo, wspo_b, Wp1, wp1_b, Wp2, wp2_b);
  ln1024b_kernel<<<512, 256, 0, stream>>>(seq, ln1_g, ln1_b, y_b);
  gemm_mfma_kernel<0, 0, 0, 1><<<dim3(24, 8), 256, 0, stream>>>(
      y_b, wq_b, nullptr, nullptr, nullptr, t_b, 512, 3072, 1024);
  gemm_mfma_kernel<1, 0, 0, 0><<<dim3(8, 8), 256, 0, stream>>>(
      y_b, wg_b, bg, nullptr, g, nullptr, 512, 1024, 1024);
  p2s_mfma_kernel<<<2048, 256, 0, stream>>>(pair, ln_p2s_g, ln_p2s_b, W_p2s,
                                            biasT);
  attn_kernel<<<dim3(8, 32), 256, 0, stream>>>(t_b, biasT, o);
  gate_b_kernel<<<512, 256, 0, stream>>>(o, g, ob);
  gemm_mfma_kernel<1, 0, 1, 0><<<dim3(8, 8), 256, 0, stream>>>(
      ob, wo_b, bo, seq, s1, nullptr, 512, 1024, 1024);
  ln1024b_kernel<<<512, 256, 0, stream>>>(s1, ln_s_g, ln_s_b, y_b);
  gemm_mfma_kernel<1, 1, 0, 1><<<dim3(32, 8), 256, 0, stream>>>(
      y_b, wm1_b, bm1, nullptr, nullptr, h1b, 512, 4096, 1024);
  gemm_mfma_kernel<1, 0, 1, 0><<<dim3(8, 8), 256, 0, stream>>>(
      h1b, wm2_b, bm2, s1, out_s, nullptr, 512, 1024, 4096);
  ln1024b_kernel<<<512, 256, 0, stream>>>(out_s, ln_sp_g, ln_sp_b, y_b);
  gemm_mfma_kernel<1, 0, 0, 0><<<dim3(1, 8), 256, 0, stream>>>(
      y_b, wsp_b, bsp, nullptr, spb, nullptr, 512, 128, 1024);
  pairfuse64_kernel<<<4096, 256, 0, stream>>>(spb, wspo_b, bspo, pair,
                                              ln_mp_g, ln_mp_b, wp1_b, bp1,
                                              wp2_b, bp2, out_p);
}

// Round 8
// 500.214 us; speedup vs baseline: 7.8426x; 1.1052x over previous
//
#include <hip/hip_runtime.h>
#include <hip/hip_bf16.h>
#include <cstddef>

// ---------------------------------------------------------------------------
// TriangularSelfAttentionBlock R7: pairfuse64 with rb=2 register blocking
// (halves LDS W-fragment reads per MFMA). Rest identical to R6.
// L=512, SEQ_D=1024, PAIR_D=128, H=32, HW=32, INNER=64
// ---------------------------------------------------------------------------

#define L 512
#define SEQ_D 1024
#define PAIR_D 128
#define NH 32
#define HW 32

typedef short bf16x8 __attribute__((ext_vector_type(8)));
typedef float f32x4 __attribute__((ext_vector_type(4)));
typedef unsigned short ushort_t;

__device__ inline float wred_sum(float v) {
#pragma unroll
  for (int off = 32; off; off >>= 1) v += __shfl_xor(v, off, 64);
  return v;
}
// f32 -> bf16 (RNE), packed pair (a low, b high)
__device__ inline unsigned pk2(float a, float b) {
  unsigned ua = __float_as_uint(a), ub = __float_as_uint(b);
  ua = (ua + 0x7fffu + ((ua >> 16) & 1u)) >> 16;
  ub = (ub + 0x7fffu + ((ub >> 16) & 1u)) >> 16;
  return ua | (ub << 16);
}
__device__ inline float bfl(unsigned u) { return __uint_as_float(u << 16); }
__device__ inline float bfh(unsigned u) { return __uint_as_float(u & 0xffff0000u); }

// swizzled byte offset for [row][256B] LDS tiles
#define SWZ(row, kb) ((((row)) << 8) + ((kb) ^ (((row)&7) << 4)))
// swizzled byte offset for [row][128B] LDS tiles
#define SWZ64(row, kb) ((((row)) << 7) + ((kb) ^ (((row)&7) << 4)))

// ---------------- fused f32->bf16 weight conversion (9 tensors) ------------
__global__ __launch_bounds__(256) void cvt9_kernel(
    const float* __restrict__ s0, ushort_t* __restrict__ d0,
    const float* __restrict__ s1, ushort_t* __restrict__ d1,
    const float* __restrict__ s2, ushort_t* __restrict__ d2,
    const float* __restrict__ s3, ushort_t* __restrict__ d3,
    const float* __restrict__ s4, ushort_t* __restrict__ d4,
    const float* __restrict__ s5, ushort_t* __restrict__ d5,
    const float* __restrict__ s6, ushort_t* __restrict__ d6,
    const float* __restrict__ s7, ushort_t* __restrict__ d7,
    const float* __restrict__ s8, ushort_t* __restrict__ d8) {
  const int b = blockIdx.x;
  const float* s; ushort_t* d; int base;
  if (b < 1536)      { s = s0; d = d0; base = b; }
  else if (b < 2048) { s = s1; d = d1; base = b - 1536; }
  else if (b < 2560) { s = s2; d = d2; base = b - 2048; }
  else if (b < 4608) { s = s3; d = d3; base = b - 2560; }
  else if (b < 6656) { s = s4; d = d4; base = b - 4608; }
  else if (b < 6720) { s = s5; d = d5; base = b - 6656; }
  else if (b < 6728) { s = s6; d = d6; base = b - 6720; }
  else if (b < 6760) { s = s7; d = d7; base = b - 6728; }
  else               { s = s8; d = d8; base = b - 6760; }
  const int i = base * 256 + threadIdx.x;
  float4 a = ((const float4*)s)[2 * i], c = ((const float4*)s)[2 * i + 1];
  uint4 w;
  w.x = pk2(a.x, a.y); w.y = pk2(a.z, a.w);
  w.z = pk2(c.x, c.y); w.w = pk2(c.z, c.w);
  ((uint4*)d)[i] = w;
}

// ---------------- LayerNorm 1024 -> bf16 out -------------------------------
__global__ __launch_bounds__(256) void ln1024b_kernel(
    const float* __restrict__ in, const float* __restrict__ g,
    const float* __restrict__ b, ushort_t* __restrict__ out) {
  const int row = blockIdx.x;
  const int tid = threadIdx.x;
  float4 v = ((const float4*)(in + (size_t)row * SEQ_D))[tid];
  float s = v.x + v.y + v.z + v.w;
  float s2 = v.x * v.x + v.y * v.y + v.z * v.z + v.w * v.w;
  __shared__ float red[8];
  const int lane = tid & 63, wid = tid >> 6;
  s = wred_sum(s);
  s2 = wred_sum(s2);
  if (lane == 0) { red[wid] = s; red[4 + wid] = s2; }
  __syncthreads();
  s = red[0] + red[1] + red[2] + red[3];
  s2 = red[4] + red[5] + red[6] + red[7];
  const float mean = s * (1.0f / SEQ_D);
  const float var = s2 * (1.0f / SEQ_D) - mean * mean;
  const float rstd = rsqrtf(var + 1e-5f);
  float4 gv = ((const float4*)g)[tid];
  float4 bv = ((const float4*)b)[tid];
  const float o0 = (v.x - mean) * rstd * gv.x + bv.x;
  const float o1 = (v.y - mean) * rstd * gv.y + bv.y;
  const float o2 = (v.z - mean) * rstd * gv.z + bv.z;
  const float o3 = (v.w - mean) * rstd * gv.w + bv.w;
  uint2 pkd; pkd.x = pk2(o0, o1); pkd.y = pk2(o2, o3);
  ((uint2*)(out + (size_t)row * SEQ_D))[tid] = pkd;
}

// ---------------- MFMA GEMM: C[M][N] = A[M][K](bf16) @ B[N][K]^T(bf16) -----
template <int BIAS, int RELU, int RES, int OBF16>
__global__ __launch_bounds__(256, 2) void gemm_mfma_kernel(
    const ushort_t* __restrict__ A, const ushort_t* __restrict__ B,
    const float* __restrict__ bias, const float* __restrict__ res,
    float* __restrict__ C, ushort_t* __restrict__ Cb, int M, int N, int K) {
  __shared__ __align__(16) char smem[24576];
  char* Ab = smem;
  char* Bb = smem + 8192;
  const int tid = threadIdx.x;
  const int l = tid & 63, w = tid >> 6;
  const int wr = w >> 1, wc = w & 1;
  const int lane16 = l & 15, g16 = l >> 4;
  const int bm = blockIdx.y * 64, bn = blockIdx.x * 128;
  const f32x4 fz = {0.f, 0.f, 0.f, 0.f};
  f32x4 acc[4][2];
#pragma unroll
  for (int i = 0; i < 4; ++i)
#pragma unroll
    for (int j = 0; j < 2; ++j) acc[i][j] = fz;

  for (int k0 = 0; k0 < K; k0 += 64) {
    __syncthreads();
#pragma unroll
    for (int u = 0; u < 2; ++u) {
      const int slot = u * 256 + tid;
      const int row = slot >> 3, sl = slot & 7;
      bf16x8 v = *(const bf16x8*)(A + (size_t)(bm + row) * K + k0 + sl * 8);
      *(bf16x8*)(Ab + SWZ64(row, sl * 16)) = v;
    }
#pragma unroll
    for (int u = 0; u < 4; ++u) {
      const int slot = u * 256 + tid;
      const int row = slot >> 3, sl = slot & 7;
      bf16x8 v = *(const bf16x8*)(B + (size_t)(bn + row) * K + k0 + sl * 8);
      *(bf16x8*)(Bb + SWZ64(row, sl * 16)) = v;
    }
    __syncthreads();
#pragma unroll
    for (int kk = 0; kk < 2; ++kk) {
      const int kb = kk * 64 + g16 * 16;
      bf16x8 af[2], bf[4];
#pragma unroll
      for (int rb = 0; rb < 2; ++rb) {
        const int row = wr * 32 + rb * 16 + lane16;
        af[rb] = *(const bf16x8*)(Ab + SWZ64(row, kb));
      }
#pragma unroll
      for (int cb = 0; cb < 4; ++cb) {
        const int row = wc * 64 + cb * 16 + lane16;
        bf[cb] = *(const bf16x8*)(Bb + SWZ64(row, kb));
      }
#pragma unroll
      for (int cb = 0; cb < 4; ++cb)
#pragma unroll
        for (int rb = 0; rb < 2; ++rb)
          acc[cb][rb] = __builtin_amdgcn_mfma_f32_16x16x32_bf16(
              bf[cb], af[rb], acc[cb][rb], 0, 0, 0);
    }
  }
#pragma unroll
  for (int cb = 0; cb < 4; ++cb) {
    const int col0 = bn + wc * 64 + cb * 16 + g16 * 4;
    float4 bi = make_float4(0.f, 0.f, 0.f, 0.f);
    if (BIAS) bi = *(const float4*)(bias + col0);
#pragma unroll
    for (int rb = 0; rb < 2; ++rb) {
      const int row = bm + wr * 32 + rb * 16 + lane16;
      f32x4 v = acc[cb][rb];
      v[0] += bi.x; v[1] += bi.y; v[2] += bi.z; v[3] += bi.w;
      if (RELU) {
        v[0] = fmaxf(v[0], 0.f); v[1] = fmaxf(v[1], 0.f);
        v[2] = fmaxf(v[2], 0.f); v[3] = fmaxf(v[3], 0.f);
      }
      if (RES) {
        const float4 r4 = *(const float4*)(res + (size_t)row * N + col0);
        v[0] += r4.x; v[1] += r4.y; v[2] += r4.z; v[3] += r4.w;
      }
      if (OBF16) {
        uint2 pkd; pkd.x = pk2(v[0], v[1]); pkd.y = pk2(v[2], v[3]);
        *(uint2*)(Cb + (size_t)row * N + col0) = pkd;
      } else {
        float4 o4; o4.x = v[0]; o4.y = v[1]; o4.z = v[2]; o4.w = v[3];
        *(float4*)(C + (size_t)row * N + col0) = o4;
      }
    }
  }
}

// ---------------- PairToSequence via MFMA ----------------------------------
__global__ __launch_bounds__(256) void p2s_mfma_kernel(
    const float* __restrict__ pair, const float* __restrict__ g,
    const float* __restrict__ b, const float* __restrict__ W,
    float* __restrict__ biasT) {
  __shared__ __align__(16) char pnb[32768];
  __shared__ __align__(16) char wls[8192];
  const int tid = threadIdx.x;
  const int l = tid & 63, w = tid >> 6;
  const int lane16 = l & 15, g16 = l >> 4;
  const size_t r0 = (size_t)blockIdx.x * 128;
  const int i_idx = (int)(r0 >> 9), j0 = (int)(r0 & 511);
#pragma unroll
  for (int u = 0; u < 2; ++u) {
    const int slot = u * 256 + tid;
    const int row = slot >> 4, sl = slot & 15;
    const float4 v0 = *(const float4*)(W + (size_t)row * 128 + sl * 8);
    const float4 v1 = *(const float4*)(W + (size_t)row * 128 + sl * 8 + 4);
    uint4 wv; wv.x = pk2(v0.x, v0.y); wv.y = pk2(v0.z, v0.w);
    wv.z = pk2(v1.x, v1.y); wv.w = pk2(v1.z, v1.w);
    *(uint4*)(wls + SWZ(row, sl * 16)) = wv;
  }
  {
    const int l32 = tid & 31, rg = tid >> 5;
    const float4 gv = *(const float4*)(g + l32 * 4);
    const float4 bv = *(const float4*)(b + l32 * 4);
#pragma unroll
    for (int it = 0; it < 16; ++it) {
      const int r = it * 8 + rg;
      const float4 v = *(const float4*)(pair + (r0 + r) * 128 + l32 * 4);
      float s = v.x + v.y + v.z + v.w;
      float s2 = v.x * v.x + v.y * v.y + v.z * v.z + v.w * v.w;
#pragma unroll
      for (int off = 1; off < 32; off <<= 1) {
        s += __shfl_xor(s, off, 64);
        s2 += __shfl_xor(s2, off, 64);
      }
      const float mean = s * (1.0f / 128.0f);
      const float rstd = rsqrtf(s2 * (1.0f / 128.0f) - mean * mean + 1e-5f);
      const float n0 = (v.x - mean) * rstd * gv.x + bv.x;
      const float n1 = (v.y - mean) * rstd * gv.y + bv.y;
      const float n2 = (v.z - mean) * rstd * gv.z + bv.z;
      const float n3 = (v.w - mean) * rstd * gv.w + bv.w;
      uint2 pkd; pkd.x = pk2(n0, n1); pkd.y = pk2(n2, n3);
      *(uint2*)(pnb + SWZ(r, l32 * 8)) = pkd;
    }
  }
  __syncthreads();
  const f32x4 fz = {0.f, 0.f, 0.f, 0.f};
  f32x4 a2[2][2];
#pragma unroll
  for (int i = 0; i < 2; ++i)
#pragma unroll
    for (int j = 0; j < 2; ++j) a2[i][j] = fz;
#pragma unroll
  for (int kk = 0; kk < 4; ++kk) {
    bf16x8 wf[2], pf[2];
#pragma unroll
    for (int hb = 0; hb < 2; ++hb)
      wf[hb] = *(const bf16x8*)(wls + SWZ(hb * 16 + lane16, kk * 64 + g16 * 16));
#pragma unroll
    for (int rb = 0; rb < 2; ++rb)
      pf[rb] = *(const bf16x8*)(pnb + SWZ(w * 32 + rb * 16 + lane16, kk * 64 + g16 * 16));
#pragma unroll
    for (int hb = 0; hb < 2; ++hb)
#pragma unroll
      for (int rb = 0; rb < 2; ++rb)
        a2[hb][rb] = __builtin_amdgcn_mfma_f32_16x16x32_bf16(
            wf[hb], pf[rb], a2[hb][rb], 0, 0, 0);
  }
#pragma unroll
  for (int hb = 0; hb < 2; ++hb)
#pragma unroll
    for (int rb = 0; rb < 2; ++rb) {
      const int j = j0 + w * 32 + rb * 16 + lane16;
#pragma unroll
      for (int qq = 0; qq < 4; ++qq) {
        const int hh = hb * 16 + g16 * 4 + qq;
        biasT[((size_t)hh * 512 + i_idx) * 512 + j] = a2[hb][rb][qq];
      }
    }
}

// ---------------- fused attention: softmax(scale*QK^T + bias) @ V ----------
__global__ __launch_bounds__(256) void attn_kernel(
    const ushort_t* __restrict__ tb, const float* __restrict__ biasT,
    float* __restrict__ o) {
  __shared__ __align__(16) ushort_t Vt[32][80];
  const int tid = threadIdx.x;
  const int l = tid & 63, wq = tid >> 6;
  const int lane16 = l & 15, g16 = l >> 4;
  const int h = blockIdx.y;
  const int q = blockIdx.x * 64 + wq * 16 + lane16;
  const float scale = 0.17677669529663689f;
  const bf16x8 qf = *(const bf16x8*)(tb + (size_t)q * 3072 + h * 96 + g16 * 8);
  const float* brow = biasT + ((size_t)h * 512 + q) * 512;
  float m = -3e38f, lsum = 0.f;
  const f32x4 fz = {0.f, 0.f, 0.f, 0.f};
  f32x4 accp[2] = {fz, fz};
  for (int kt = 0; kt < 512; kt += 64) {
    {
      const int kr = tid >> 2, cc = tid & 3;
      bf16x8 vv = *(const bf16x8*)(tb + (size_t)(kt + kr) * 3072 + h * 96 + 64 + cc * 8);
#pragma unroll
      for (int u = 0; u < 8; ++u) Vt[cc * 8 + u][kr] = (ushort_t)vv[u];
    }
    __syncthreads();
    f32x4 st[4];
#pragma unroll
    for (int kb = 0; kb < 4; ++kb) {
      const bf16x8 kf = *(const bf16x8*)(
          tb + (size_t)(kt + kb * 16 + lane16) * 3072 + h * 96 + 32 + g16 * 8);
      st[kb] = __builtin_amdgcn_mfma_f32_16x16x32_bf16(kf, qf, fz, 0, 0, 0);
      const float4 bv = *(const float4*)(brow + kt + kb * 16 + g16 * 4);
      st[kb][0] = st[kb][0] * scale + bv.x;
      st[kb][1] = st[kb][1] * scale + bv.y;
      st[kb][2] = st[kb][2] * scale + bv.z;
      st[kb][3] = st[kb][3] * scale + bv.w;
    }
    float tm = st[0][0];
#pragma unroll
    for (int kb = 0; kb < 4; ++kb)
#pragma unroll
      for (int qq = 0; qq < 4; ++qq) tm = fmaxf(tm, st[kb][qq]);
    tm = fmaxf(tm, __shfl_xor(tm, 16, 64));
    tm = fmaxf(tm, __shfl_xor(tm, 32, 64));
    const float mn = fmaxf(m, tm);
    const float corr = __expf(m - mn);
    m = mn;
    lsum *= corr;
#pragma unroll
    for (int ct = 0; ct < 2; ++ct) {
      accp[ct][0] *= corr; accp[ct][1] *= corr;
      accp[ct][2] *= corr; accp[ct][3] *= corr;
    }
#pragma unroll
    for (int kb = 0; kb < 4; ++kb)
#pragma unroll
      for (int qq = 0; qq < 4; ++qq) {
        const float e = __expf(st[kb][qq] - mn);
        st[kb][qq] = e;
        lsum += e;
      }
    const int src0 = lane16 + ((l & 16) << 1);
    const int src1 = src0 + 16;
    const bool hi = (l & 32) != 0;
#pragma unroll
    for (int kk = 0; kk < 2; ++kk) {
      float lo4[4], hi4[4];
#pragma unroll
      for (int qq = 0; qq < 4; ++qq) {
        const float a0 = __shfl(st[kk * 2][qq], src0, 64);
        const float a1 = __shfl(st[kk * 2][qq], src1, 64);
        const float b0 = __shfl(st[kk * 2 + 1][qq], src0, 64);
        const float b1 = __shfl(st[kk * 2 + 1][qq], src1, 64);
        lo4[qq] = hi ? b0 : a0;
        hi4[qq] = hi ? b1 : a1;
      }
      uint4 pu;
      pu.x = pk2(lo4[0], lo4[1]); pu.y = pk2(lo4[2], lo4[3]);
      pu.z = pk2(hi4[0], hi4[1]); pu.w = pk2(hi4[2], hi4[3]);
      bf16x8 pf;
      __builtin_memcpy(&pf, &pu, 16);
#pragma unroll
      for (int ct = 0; ct < 2; ++ct) {
        const bf16x8 vf = *(const bf16x8*)&Vt[ct * 16 + lane16][kk * 32 + g16 * 8];
        accp[ct] = __builtin_amdgcn_mfma_f32_16x16x32_bf16(vf, pf, accp[ct], 0, 0, 0);
      }
    }
    __syncthreads();
  }
  lsum += __shfl_xor(lsum, 16, 64);
  lsum += __shfl_xor(lsum, 32, 64);
  const float inv = 1.0f / lsum;
#pragma unroll
  for (int ct = 0; ct < 2; ++ct) {
    float4 o4;
    o4.x = accp[ct][0] * inv; o4.y = accp[ct][1] * inv;
    o4.z = accp[ct][2] * inv; o4.w = accp[ct][3] * inv;
    *(float4*)(o + (size_t)q * SEQ_D + h * 32 + ct * 16 + g16 * 4) = o4;
  }
}

// ---------------- gate: ob = bf16(o * sigmoid(g)) --------------------------
__global__ __launch_bounds__(256) void gate_b_kernel(
    const float* __restrict__ o, const float* __restrict__ g,
    ushort_t* __restrict__ ob) {
  const int i = blockIdx.x * 256 + threadIdx.x;
  float4 ov = ((const float4*)o)[i];
  float4 gv = ((const float4*)g)[i];
  ov.x *= 1.0f / (1.0f + __expf(-gv.x));
  ov.y *= 1.0f / (1.0f + __expf(-gv.y));
  ov.z *= 1.0f / (1.0f + __expf(-gv.z));
  ov.w *= 1.0f / (1.0f + __expf(-gv.w));
  uint2 pkd; pkd.x = pk2(ov.x, ov.y); pkd.y = pk2(ov.z, ov.w);
  ((uint2*)ob)[i] = pkd;
}

// ---------------- in-wave butterfly: C-layout packed pair -> A/B-frag ------
// pkA = cols cb=2k (4 bf16 at col 2k*16+g16*4), pkB = cb=2k+1.
// returns frag: vals at k-col = k*32 + g16*8 + j, j=0..7.
__device__ inline bf16x8 bfly2(uint2 pkA, uint2 pkB, int lane16, int g16) {
  const int sl_lo = lane16 + (((g16 * 2) & 3) << 4);
  const int sl_hi = lane16 + (((g16 * 2 + 1) & 3) << 4);
  const int hiSel = g16 >> 1;
  const unsigned a0x = __shfl((int)pkA.x, sl_lo, 64);
  const unsigned a0y = __shfl((int)pkA.y, sl_lo, 64);
  const unsigned a1x = __shfl((int)pkB.x, sl_lo, 64);
  const unsigned a1y = __shfl((int)pkB.y, sl_lo, 64);
  const unsigned b0x = __shfl((int)pkA.x, sl_hi, 64);
  const unsigned b0y = __shfl((int)pkA.y, sl_hi, 64);
  const unsigned b1x = __shfl((int)pkB.x, sl_hi, 64);
  const unsigned b1y = __shfl((int)pkB.y, sl_hi, 64);
  uint4 u;
  u.x = hiSel ? a1x : a0x;
  u.y = hiSel ? a1y : a0y;
  u.z = hiSel ? b1x : b0x;
  u.w = hiSel ? b1y : b0y;
  bf16x8 r;
  __builtin_memcpy(&r, &u, 16);
  return r;
}

// ---------------- fused SequenceToPair + pair MLP (rb=2) -------------------
// 128-row tile; wave w owns rows w*32..w*32+31 (2 x 16-row frag sets).
// Each LDS W-fragment read feeds 2 MFMAs.
__global__ __launch_bounds__(256, 2) void pairfuse64_kernel(
    const float* __restrict__ spb, const ushort_t* __restrict__ Wspob,
    const float* __restrict__ bspo, const float* __restrict__ pairw,
    const float* __restrict__ lng, const float* __restrict__ lnb,
    const ushort_t* __restrict__ Wp1b, const float* __restrict__ bp1,
    const ushort_t* __restrict__ Wp2b, const float* __restrict__ bp2,
    float* __restrict__ pout) {
  __shared__ __align__(16) char Wbuf[32768];  // 128 rows x 256B, swizzled
  const int tid = threadIdx.x;
  const int l = tid & 63, w = tid >> 6;
  const int lane16 = l & 15, g16 = l >> 4;
  const size_t r0 = (size_t)blockIdx.x * 128;
  const int i_idx = (int)(r0 >> 9), j0 = (int)(r0 & 511);
  // rows owned by this thread: grow[rb] = r0 + w*32 + rb*16 + lane16
  size_t grow[2];
  grow[0] = r0 + w * 32 + lane16;
  grow[1] = grow[0] + 16;

  // ---- stage Wspo (128x128 bf16) ----
#pragma unroll
  for (int u = 0; u < 8; ++u) {
    const int slot = u * 256 + tid;
    const int row = slot >> 4, sl = slot & 15;
    bf16x8 v = *(const bf16x8*)(Wspob + (size_t)row * 128 + sl * 8);
    *(bf16x8*)(Wbuf + SWZ(row, sl * 16)) = v;
  }

  // ---- build X A-frags in registers: X = [qh*kh | qh-kh] ----
  bf16x8 xf[2][4];
  {
    const float* krow = spb + (size_t)i_idx * 128 + 64;
#pragma unroll
    for (int rb = 0; rb < 2; ++rb) {
      const float* qrow = spb + (size_t)(j0 + w * 32 + rb * 16 + lane16) * 128;
#pragma unroll
      for (int kk = 0; kk < 4; ++kk) {
        const int c = ((kk & 1) << 5) + g16 * 8;
        const float4 q0 = *(const float4*)(qrow + c);
        const float4 q1 = *(const float4*)(qrow + c + 4);
        const float4 k0 = *(const float4*)(krow + c);
        const float4 k1 = *(const float4*)(krow + c + 4);
        uint4 u;
        if (kk < 2) {
          u.x = pk2(q0.x * k0.x, q0.y * k0.y);
          u.y = pk2(q0.z * k0.z, q0.w * k0.w);
          u.z = pk2(q1.x * k1.x, q1.y * k1.y);
          u.w = pk2(q1.z * k1.z, q1.w * k1.w);
        } else {
          u.x = pk2(q0.x - k0.x, q0.y - k0.y);
          u.y = pk2(q0.z - k0.z, q0.w - k0.w);
          u.z = pk2(q1.x - k1.x, q1.y - k1.y);
          u.w = pk2(q1.z - k1.z, q1.w - k1.w);
        }
        __builtin_memcpy(&xf[rb][kk], &u, 16);
      }
    }
  }
  __syncthreads();

  // ---- GEMM0: acc[rb][cb] = X @ Wspo^T (W-frag read once, 2 MFMAs) ----
  const f32x4 fz = {0.f, 0.f, 0.f, 0.f};
  f32x4 acc[2][8];
#pragma unroll
  for (int rb = 0; rb < 2; ++rb)
#pragma unroll
    for (int cb = 0; cb < 8; ++cb) acc[rb][cb] = fz;
#pragma unroll
  for (int cb = 0; cb < 8; ++cb) {
#pragma unroll
    for (int kk = 0; kk < 4; ++kk) {
      const bf16x8 wf = *(const bf16x8*)(
          Wbuf + SWZ(cb * 16 + lane16, kk * 64 + g16 * 16));
      acc[0][cb] = __builtin_amdgcn_mfma_f32_16x16x32_bf16(wf, xf[0][kk], acc[0][cb], 0, 0, 0);
      acc[1][cb] = __builtin_amdgcn_mfma_f32_16x16x32_bf16(wf, xf[1][kk], acc[1][cb], 0, 0, 0);
    }
  }

  // ---- P = acc + bspo + pair; LN stats in-wave (per rb) ----
  uint2 Ppk[2][8];
  bf16x8 pnf[2][4];
#pragma unroll
  for (int rb = 0; rb < 2; ++rb) {
    float s = 0.f, s2 = 0.f;
#pragma unroll
    for (int cb = 0; cb < 8; ++cb) {
      const int col0 = cb * 16 + g16 * 4;
      const float4 bs = *(const float4*)(bspo + col0);
      const float4 pw = *(const float4*)(pairw + grow[rb] * 128 + col0);
      acc[rb][cb][0] += bs.x + pw.x; acc[rb][cb][1] += bs.y + pw.y;
      acc[rb][cb][2] += bs.z + pw.z; acc[rb][cb][3] += bs.w + pw.w;
      s += acc[rb][cb][0] + acc[rb][cb][1] + acc[rb][cb][2] + acc[rb][cb][3];
      s2 += acc[rb][cb][0] * acc[rb][cb][0] + acc[rb][cb][1] * acc[rb][cb][1] +
            acc[rb][cb][2] * acc[rb][cb][2] + acc[rb][cb][3] * acc[rb][cb][3];
      Ppk[rb][cb].x = pk2(acc[rb][cb][0], acc[rb][cb][1]);
      Ppk[rb][cb].y = pk2(acc[rb][cb][2], acc[rb][cb][3]);
    }
    s += __shfl_xor(s, 16, 64);  s += __shfl_xor(s, 32, 64);
    s2 += __shfl_xor(s2, 16, 64); s2 += __shfl_xor(s2, 32, 64);
    const float mean = s * (1.0f / 128.0f);
    const float rstd = rsqrtf(s2 * (1.0f / 128.0f) - mean * mean + 1e-5f);
    uint2 pnpk[8];
#pragma unroll
    for (int cb = 0; cb < 8; ++cb) {
      const int col0 = cb * 16 + g16 * 4;
      const float4 gv = *(const float4*)(lng + col0);
      const float4 bv = *(const float4*)(lnb + col0);
      const float n0 = (acc[rb][cb][0] - mean) * rstd * gv.x + bv.x;
      const float n1 = (acc[rb][cb][1] - mean) * rstd * gv.y + bv.y;
      const float n2 = (acc[rb][cb][2] - mean) * rstd * gv.z + bv.z;
      const float n3 = (acc[rb][cb][3] - mean) * rstd * gv.w + bv.w;
      pnpk[cb].x = pk2(n0, n1); pnpk[cb].y = pk2(n2, n3);
    }
#pragma unroll
    for (int fk = 0; fk < 4; ++fk)
      pnf[rb][fk] = bfly2(pnpk[2 * fk], pnpk[2 * fk + 1], lane16, g16);
  }

  // ---- MLP: 4 chunks of 128 hidden ----
  f32x4 acc2[2][8];
#pragma unroll
  for (int rb = 0; rb < 2; ++rb)
#pragma unroll
    for (int cb = 0; cb < 8; ++cb) acc2[rb][cb] = fz;

  for (int ch = 0; ch < 4; ++ch) {
    __syncthreads();  // all waves done reading Wbuf
#pragma unroll
    for (int u = 0; u < 8; ++u) {
      const int slot = u * 256 + tid;
      const int row = slot >> 4, sl = slot & 15;
      bf16x8 v = *(const bf16x8*)(Wp1b + (size_t)(ch * 128 + row) * 128 + sl * 8);
      *(bf16x8*)(Wbuf + SWZ(row, sl * 16)) = v;
    }
    __syncthreads();
    // GEMM1 pipelined per output k-frag pair (keeps hacc transient)
    bf16x8 hf[2][4];
#pragma unroll
    for (int fk = 0; fk < 4; ++fk) {
      uint2 hpk[2][2];
#pragma unroll
      for (int cbl = 0; cbl < 2; ++cbl) {
        const int cb = fk * 2 + cbl;
        f32x4 hacc[2] = {fz, fz};
#pragma unroll
        for (int kk = 0; kk < 4; ++kk) {
          const bf16x8 w1f = *(const bf16x8*)(
              Wbuf + SWZ(cb * 16 + lane16, kk * 64 + g16 * 16));
          hacc[0] = __builtin_amdgcn_mfma_f32_16x16x32_bf16(w1f, pnf[0][kk], hacc[0], 0, 0, 0);
          hacc[1] = __builtin_amdgcn_mfma_f32_16x16x32_bf16(w1f, pnf[1][kk], hacc[1], 0, 0, 0);
        }
        const int hcol = ch * 128 + cb * 16 + g16 * 4;
        const float4 bi = *(const float4*)(bp1 + hcol);
#pragma unroll
        for (int rb = 0; rb < 2; ++rb) {
          const float h0 = fmaxf(hacc[rb][0] + bi.x, 0.f);
          const float h1 = fmaxf(hacc[rb][1] + bi.y, 0.f);
          const float h2 = fmaxf(hacc[rb][2] + bi.z, 0.f);
          const float h3 = fmaxf(hacc[rb][3] + bi.w, 0.f);
          hpk[rb][cbl].x = pk2(h0, h1); hpk[rb][cbl].y = pk2(h2, h3);
        }
      }
      hf[0][fk] = bfly2(hpk[0][0], hpk[0][1], lane16, g16);
      hf[1][fk] = bfly2(hpk[1][0], hpk[1][1], lane16, g16);
    }
    __syncthreads();  // GEMM1 LDS reads done
#pragma unroll
    for (int u = 0; u < 8; ++u) {
      const int slot = u * 256 + tid;
      const int row = slot >> 4, sl = slot & 15;
      bf16x8 v = *(const bf16x8*)(Wp2b + (size_t)row * 512 + ch * 128 + sl * 8);
      *(bf16x8*)(Wbuf + SWZ(row, sl * 16)) = v;
    }
    __syncthreads();
    // GEMM2: acc2 += H @ W2c^T (W-frag read once, 2 MFMAs)
#pragma unroll
    for (int cb = 0; cb < 8; ++cb) {
#pragma unroll
      for (int kk = 0; kk < 4; ++kk) {
        const bf16x8 w2f = *(const bf16x8*)(
            Wbuf + SWZ(cb * 16 + lane16, kk * 64 + g16 * 16));
        acc2[0][cb] = __builtin_amdgcn_mfma_f32_16x16x32_bf16(w2f, hf[0][kk], acc2[0][cb], 0, 0, 0);
        acc2[1][cb] = __builtin_amdgcn_mfma_f32_16x16x32_bf16(w2f, hf[1][kk], acc2[1][cb], 0, 0, 0);
      }
    }
  }

  // ---- epilogue: out = P + acc2 + bp2 ----
#pragma unroll
  for (int rb = 0; rb < 2; ++rb) {
#pragma unroll
    for (int cb = 0; cb < 8; ++cb) {
      const int col0 = cb * 16 + g16 * 4;
      const float4 b2 = *(const float4*)(bp2 + col0);
      float4 o4;
      o4.x = acc2[rb][cb][0] + b2.x + bfl(Ppk[rb][cb].x);
      o4.y = acc2[rb][cb][1] + b2.y + bfh(Ppk[rb][cb].x);
      o4.z = acc2[rb][cb][2] + b2.z + bfl(Ppk[rb][cb].y);
      o4.w = acc2[rb][cb][3] + b2.w + bfh(Ppk[rb][cb].y);
      *(float4*)(pout + grow[rb] * 128 + col0) = o4;
    }
  }
}

// ---------------------------------------------------------------------------
extern "C" void kernel_launch(void* const* d_in, const int* in_sizes, int n_in,
                              void* d_out, int out_size, void* d_ws,
                              size_t ws_size, hipStream_t stream) {
  (void)in_sizes; (void)n_in; (void)out_size; (void)ws_size;
  const float* seq      = (const float*)d_in[0];
  const float* pair     = (const float*)d_in[1];
  const float* ln_p2s_g = (const float*)d_in[2];
  const float* ln_p2s_b = (const float*)d_in[3];
  const float* W_p2s    = (const float*)d_in[4];
  const float* ln1_g    = (const float*)d_in[5];
  const float* ln1_b    = (const float*)d_in[6];
  const float* Wqkv     = (const float*)d_in[7];
  const float* Wo       = (const float*)d_in[8];
  const float* bo       = (const float*)d_in[9];
  const float* Wg       = (const float*)d_in[10];
  const float* bg       = (const float*)d_in[11];
  const float* ln_s_g   = (const float*)d_in[12];
  const float* ln_s_b   = (const float*)d_in[13];
  const float* Wm1      = (const float*)d_in[14];
  const float* bm1      = (const float*)d_in[15];
  const float* Wm2      = (const float*)d_in[16];
  const float* bm2      = (const float*)d_in[17];
  const float* ln_sp_g  = (const float*)d_in[18];
  const float* ln_sp_b  = (const float*)d_in[19];
  const float* Wsp      = (const float*)d_in[20];
  const float* bsp      = (const float*)d_in[21];
  const float* Wspo     = (const float*)d_in[22];
  const float* bspo     = (const float*)d_in[23];
  const float* ln_mp_g  = (const float*)d_in[24];
  const float* ln_mp_b  = (const float*)d_in[25];
  const float* Wp1      = (const float*)d_in[26];
  const float* bp1      = (const float*)d_in[27];
  const float* Wp2      = (const float*)d_in[28];
  const float* bp2      = (const float*)d_in[29];

  float* out_s = (float*)d_out;            // 512*1024
  float* out_p = out_s + 512 * 1024;       // 512*512*128

  float* ws = (float*)d_ws;
  ushort_t* y_b = (ushort_t*)ws;                       // 524288 ush
  ushort_t* t_b = (ushort_t*)(ws + 262144);            // 1572864 ush
  float* g   = ws + 1048576;                           // 524288 f
  float* o   = g + 524288;                             // 524288 f
  float* s1  = o + 524288;                             // 524288 f
  ushort_t* ob  = (ushort_t*)(s1 + 524288);            // 524288 ush
  ushort_t* h1b = (ushort_t*)(s1 + 524288 + 262144);   // 2097152 ush
  float* spb = s1 + 524288 + 262144 + 1048576;         // 65536 f
  ushort_t* wspo_b = (ushort_t*)(spb + 65536);         // 16384 ush
  ushort_t* wp1_b  = (ushort_t*)(spb + 65536 + 8192);  // 65536 ush
  ushort_t* wp2_b  = (ushort_t*)(spb + 65536 + 40960); // 65536 ush

  float* biasT = out_p;                                // 8388608 f
  ushort_t* wq_b  = (ushort_t*)(out_p + 8388608);      // 3145728 ush
  ushort_t* wg_b  = wq_b + 3145728;
  ushort_t* wo_b  = wg_b + 1048576;
  ushort_t* wm1_b = wo_b + 1048576;
  ushort_t* wm2_b = wm1_b + 4194304;
  ushort_t* wsp_b = wm2_b + 4194304;

  cvt9_kernel<<<6792, 256, 0, stream>>>(Wqkv, wq_b, Wg, wg_b, Wo, wo_b,
                                        Wm1, wm1_b, Wm2, wm2_b, Wsp, wsp_b,
                                        Wspo, wspo_b, Wp1, wp1_b, Wp2, wp2_b);
  ln1024b_kernel<<<512, 256, 0, stream>>>(seq, ln1_g, ln1_b, y_b);
  gemm_mfma_kernel<0, 0, 0, 1><<<dim3(24, 8), 256, 0, stream>>>(
      y_b, wq_b, nullptr, nullptr, nullptr, t_b, 512, 3072, 1024);
  gemm_mfma_kernel<1, 0, 0, 0><<<dim3(8, 8), 256, 0, stream>>>(
      y_b, wg_b, bg, nullptr, g, nullptr, 512, 1024, 1024);
  p2s_mfma_kernel<<<2048, 256, 0, stream>>>(pair, ln_p2s_g, ln_p2s_b, W_p2s,
                                            biasT);
  attn_kernel<<<dim3(8, 32), 256, 0, stream>>>(t_b, biasT, o);
  gate_b_kernel<<<512, 256, 0, stream>>>(o, g, ob);
  gemm_mfma_kernel<1, 0, 1, 0><<<dim3(8, 8), 256, 0, stream>>>(
      ob, wo_b, bo, seq, s1, nullptr, 512, 1024, 1024);
  ln1024b_kernel<<<512, 256, 0, stream>>>(s1, ln_s_g, ln_s_b, y_b);
  gemm_mfma_kernel<1, 1, 0, 1><<<dim3(32, 8), 256, 0, stream>>>(
      y_b, wm1_b, bm1, nullptr, nullptr, h1b, 512, 4096, 1024);
  gemm_mfma_kernel<1, 0, 1, 0><<<dim3(8, 8), 256, 0, stream>>>(
      h1b, wm2_b, bm2, s1, out_s, nullptr, 512, 1024, 4096);
  ln1024b_kernel<<<512, 256, 0, stream>>>(out_s, ln_sp_g, ln_sp_b, y_b);
  gemm_mfma_kernel<1, 0, 0, 0><<<dim3(1, 8), 256, 0, stream>>>(
      y_b, wsp_b, bsp, nullptr, spb, nullptr, 512, 128, 1024);
  pairfuse64_kernel<<<2048, 256, 0, stream>>>(spb, wspo_b, bspo, pair,
                                              ln_mp_g, ln_mp_b, wp1_b, bp1,
                                              wp2_b, bp2, out_p);
}